// Round 6
// baseline (631.916 us; speedup 1.0000x reference)
//
#include <hip/hip_runtime.h>
#include <hip/hip_fp16.h>

typedef _Float16 half8 __attribute__((ext_vector_type(8)));
typedef _Float16 half4v __attribute__((ext_vector_type(4)));
typedef _Float16 half2v __attribute__((ext_vector_type(2)));
typedef float f32x4 __attribute__((ext_vector_type(4)));

static constexpr int B_ = 8, T_ = 64, N_ = 256;
static constexpr int F0 = 12, F1 = 64, F2 = 32;
static constexpr int BT_ = B_ * T_;

__device__ inline float tanh_fast(float x) {
    x = fminf(20.f, fmaxf(-20.f, x));
    float e = __expf(2.f * x);
    return (e - 1.f) / (e + 1.f);
}

// ---------------- K0: S (BT,256,256) f32 -> S^T hi/lo fp16 planes ----------
__global__ void k_transpose_s(const float* __restrict__ S,
                              _Float16* __restrict__ STh, _Float16* __restrict__ STl) {
    int bt = blockIdx.x;
    int n0 = blockIdx.y * 64;
    const float* s = S + (size_t)bt * N_ * N_;
    _Float16* sth = STh + (size_t)bt * N_ * N_;
    _Float16* stl = STl + (size_t)bt * N_ * N_;
    __shared__ float tile[64][65];
    int tx = threadIdx.x & 15;
    int ty = threadIdx.x >> 4;
    for (int tm = 0; tm < N_; tm += 64) {
        #pragma unroll
        for (int r = ty; r < 64; r += 32) {
            float4 v = *(const float4*)(s + (size_t)(tm + r) * N_ + n0 + tx * 4);
            tile[r][tx * 4 + 0] = v.x;
            tile[r][tx * 4 + 1] = v.y;
            tile[r][tx * 4 + 2] = v.z;
            tile[r][tx * 4 + 3] = v.w;
        }
        __syncthreads();
        #pragma unroll
        for (int rr = ty; rr < 64; rr += 32) {
            half4v h, l;
            #pragma unroll
            for (int c = 0; c < 4; ++c) {
                float v = tile[tx * 4 + c][rr];
                _Float16 hh = (_Float16)v;
                h[c] = hh;
                l[c] = (_Float16)(v - (float)hh);
            }
            size_t o = (size_t)(n0 + rr) * N_ + tm + tx * 4;
            *(half4v*)(sth + o) = h;
            *(half4v*)(stl + o) = l;
        }
        __syncthreads();
    }
}

// ---------------- K1: U1(b,t) = x(b,t-1) @ S(b,t); grid (BT,2), wave=32 cols
__global__ void k_chain1x(const float* __restrict__ x,
                          const _Float16* __restrict__ STh, const _Float16* __restrict__ STl,
                          _Float16* __restrict__ Oh, _Float16* __restrict__ Ol) {
    int bt = blockIdx.x;
    int t = bt & (T_ - 1);
    int wave = threadIdx.x >> 6;
    int lane = threadIdx.x & 63;
    int l15 = lane & 15;
    int lk = lane >> 4;
    int n0 = blockIdx.y * 128 + wave * 32;

    f32x4 acc[2];
    #pragma unroll
    for (int j = 0; j < 2; ++j) acc[j] = (f32x4){0.f, 0.f, 0.f, 0.f};

    if (t > 0) {
        const float* A = x + (size_t)(bt - 1) * F0 * N_;
        const _Float16* B_h = STh + (size_t)bt * N_ * N_;
        const _Float16* B_l = STl + (size_t)bt * N_ * N_;
        #pragma unroll
        for (int kk = 0; kk < 8; ++kk) {
            int kof = kk * 32 + lk * 8;
            half8 ah = {}, al = {};
            if (l15 < F0) {
                const float* ar = A + (size_t)l15 * N_ + kof;
                float4 v0 = *(const float4*)(ar);
                float4 v1 = *(const float4*)(ar + 4);
                float vv[8] = {v0.x, v0.y, v0.z, v0.w, v1.x, v1.y, v1.z, v1.w};
                #pragma unroll
                for (int c = 0; c < 8; ++c) {
                    _Float16 hh = (_Float16)vv[c];
                    ah[c] = hh;
                    al[c] = (_Float16)(vv[c] - (float)hh);
                }
            }
            #pragma unroll
            for (int j = 0; j < 2; ++j) {
                half8 bh = *(const half8*)(B_h + (size_t)(n0 + j * 16 + l15) * N_ + kof);
                half8 bl = *(const half8*)(B_l + (size_t)(n0 + j * 16 + l15) * N_ + kof);
                acc[j] = __builtin_amdgcn_mfma_f32_16x16x32_f16(ah, bh, acc[j], 0, 0, 0);
                acc[j] = __builtin_amdgcn_mfma_f32_16x16x32_f16(al, bh, acc[j], 0, 0, 0);
                acc[j] = __builtin_amdgcn_mfma_f32_16x16x32_f16(ah, bl, acc[j], 0, 0, 0);
            }
        }
    }
    _Float16* O_h = Oh + (size_t)bt * 16 * N_;
    _Float16* O_l = Ol + (size_t)bt * 16 * N_;
    #pragma unroll
    for (int j = 0; j < 2; ++j)
        #pragma unroll
        for (int r = 0; r < 4; ++r) {
            float v = acc[j][r];
            _Float16 h = (_Float16)v;
            size_t idx = (size_t)(lk * 4 + r) * N_ + n0 + j * 16 + l15;
            O_h[idx] = h;
            O_l[idx] = (_Float16)(v - (float)h);
        }
}

// ---------------- K2: V1 = U1(t-1)@S(t); y1 = tanh(b1 + W1 ⋅ [x,U1,V1]) ----
// grid (BT,2): block covers 128 cols. MFMA: 4 waves x 32 cols. Combine: 2
// threads per col (f-halves of 64).
__global__ void k_layer1b(const _Float16* __restrict__ U1h, const _Float16* __restrict__ U1l,
                          const _Float16* __restrict__ STh, const _Float16* __restrict__ STl,
                          const float* __restrict__ x,
                          const float* __restrict__ W1,  // (64,3,12)
                          const float* __restrict__ b1,
                          _Float16* __restrict__ Y1h, _Float16* __restrict__ Y1l) {
    __shared__ float v1s[16][132];
    int bt = blockIdx.x;
    int t = bt & (T_ - 1);
    int c0 = blockIdx.y * 128;
    int wave = threadIdx.x >> 6;
    int lane = threadIdx.x & 63;
    int l15 = lane & 15;
    int lk = lane >> 4;
    int n0 = c0 + wave * 32;

    f32x4 acc[2];
    #pragma unroll
    for (int j = 0; j < 2; ++j) acc[j] = (f32x4){0.f, 0.f, 0.f, 0.f};

    if (t > 0) {
        const _Float16* A_h = U1h + (size_t)(bt - 1) * 16 * N_;
        const _Float16* A_l = U1l + (size_t)(bt - 1) * 16 * N_;
        const _Float16* B_h = STh + (size_t)bt * N_ * N_;
        const _Float16* B_l = STl + (size_t)bt * N_ * N_;
        #pragma unroll
        for (int kk = 0; kk < 8; ++kk) {
            int kof = kk * 32 + lk * 8;
            half8 ah = *(const half8*)(A_h + (size_t)l15 * N_ + kof);
            half8 al = *(const half8*)(A_l + (size_t)l15 * N_ + kof);
            #pragma unroll
            for (int j = 0; j < 2; ++j) {
                half8 bh = *(const half8*)(B_h + (size_t)(n0 + j * 16 + l15) * N_ + kof);
                half8 bl = *(const half8*)(B_l + (size_t)(n0 + j * 16 + l15) * N_ + kof);
                acc[j] = __builtin_amdgcn_mfma_f32_16x16x32_f16(ah, bh, acc[j], 0, 0, 0);
                acc[j] = __builtin_amdgcn_mfma_f32_16x16x32_f16(al, bh, acc[j], 0, 0, 0);
                acc[j] = __builtin_amdgcn_mfma_f32_16x16x32_f16(ah, bl, acc[j], 0, 0, 0);
            }
        }
    }
    #pragma unroll
    for (int j = 0; j < 2; ++j)
        #pragma unroll
        for (int r = 0; r < 4; ++r)
            v1s[lk * 4 + r][wave * 32 + j * 16 + l15] = acc[j][r];
    __syncthreads();

    // combine: 2 threads per column (f-halves)
    int col = threadIdx.x & 127;
    int fh = threadIdx.x >> 7;   // 0/1 -> f in [fh*32, fh*32+32)
    int n = c0 + col;
    const float* xc = x + (size_t)bt * F0 * N_;
    const _Float16* u1hc = U1h + (size_t)bt * 16 * N_;
    const _Float16* u1lc = U1l + (size_t)bt * 16 * N_;
    float z0[F0], z1[F0], z2[F0];
    #pragma unroll
    for (int g = 0; g < F0; ++g) {
        z0[g] = xc[(size_t)g * N_ + n];
        z1[g] = (float)u1hc[(size_t)g * N_ + n] + (float)u1lc[(size_t)g * N_ + n];
        z2[g] = v1s[g][col];
    }
    _Float16* yh = Y1h + (size_t)bt * F1 * N_;
    _Float16* yl = Y1l + (size_t)bt * F1 * N_;
    #pragma unroll
    for (int ff = 0; ff < 32; ++ff) {
        int f = fh * 32 + ff;
        float a2 = b1[f];
        const float* w = W1 + f * 36;
        #pragma unroll
        for (int g = 0; g < F0; ++g)
            a2 += w[g] * z0[g] + w[12 + g] * z1[g] + w[24 + g] * z2[g];
        float yv = tanh_fast(a2);
        _Float16 h = (_Float16)yv;
        yh[(size_t)f * N_ + n] = h;
        yl[(size_t)f * N_ + n] = (_Float16)(yv - (float)h);
    }
}

// ---------------- K3: U2(b,t) = Y1(b,t-1) @ S(b,t); grid (BT,2), wave=32 cols
template <int MT>
__global__ void k_chain(const _Float16* __restrict__ Ah, const _Float16* __restrict__ Al,
                        const _Float16* __restrict__ STh, const _Float16* __restrict__ STl,
                        _Float16* __restrict__ Oh, _Float16* __restrict__ Ol) {
    constexpr int M = 16 * MT;
    int bt = blockIdx.x;
    int t = bt & (T_ - 1);
    int wave = threadIdx.x >> 6;
    int lane = threadIdx.x & 63;
    int l15 = lane & 15;
    int lk = lane >> 4;
    int n0 = blockIdx.y * 128 + wave * 32;

    f32x4 acc[MT][2];
    #pragma unroll
    for (int i = 0; i < MT; ++i)
        #pragma unroll
        for (int j = 0; j < 2; ++j)
            acc[i][j] = (f32x4){0.f, 0.f, 0.f, 0.f};

    if (t > 0) {
        const _Float16* A_h = Ah + (size_t)(bt - 1) * M * N_;
        const _Float16* A_l = Al + (size_t)(bt - 1) * M * N_;
        const _Float16* B_h = STh + (size_t)bt * N_ * N_;
        const _Float16* B_l = STl + (size_t)bt * N_ * N_;
        #pragma unroll
        for (int kk = 0; kk < 8; ++kk) {
            int kof = kk * 32 + lk * 8;
            half8 ah[MT], al[MT];
            #pragma unroll
            for (int i = 0; i < MT; ++i) {
                ah[i] = *(const half8*)(A_h + (size_t)(i * 16 + l15) * N_ + kof);
                al[i] = *(const half8*)(A_l + (size_t)(i * 16 + l15) * N_ + kof);
            }
            #pragma unroll
            for (int j = 0; j < 2; ++j) {
                half8 bh = *(const half8*)(B_h + (size_t)(n0 + j * 16 + l15) * N_ + kof);
                half8 bl = *(const half8*)(B_l + (size_t)(n0 + j * 16 + l15) * N_ + kof);
                #pragma unroll
                for (int i = 0; i < MT; ++i) {
                    acc[i][j] = __builtin_amdgcn_mfma_f32_16x16x32_f16(ah[i], bh, acc[i][j], 0, 0, 0);
                    acc[i][j] = __builtin_amdgcn_mfma_f32_16x16x32_f16(al[i], bh, acc[i][j], 0, 0, 0);
                    acc[i][j] = __builtin_amdgcn_mfma_f32_16x16x32_f16(ah[i], bl, acc[i][j], 0, 0, 0);
                }
            }
        }
    }
    _Float16* O_h = Oh + (size_t)bt * M * N_;
    _Float16* O_l = Ol + (size_t)bt * M * N_;
    #pragma unroll
    for (int i = 0; i < MT; ++i)
        #pragma unroll
        for (int j = 0; j < 2; ++j)
            #pragma unroll
            for (int r = 0; r < 4; ++r) {
                float v = acc[i][j][r];
                _Float16 h = (_Float16)v;
                size_t idx = (size_t)(i * 16 + lk * 4 + r) * N_ + n0 + j * 16 + l15;
                O_h[idx] = h;
                O_l[idx] = (_Float16)(v - (float)h);
            }
}

// ---------------- K4: V2(b,t) = U2(b,t-1) @ S(b,t), f32 out; grid (BT,2) ----
__global__ void k_chainV2f(const _Float16* __restrict__ Ah, const _Float16* __restrict__ Al,
                           const _Float16* __restrict__ STh, const _Float16* __restrict__ STl,
                           float* __restrict__ O) {
    int bt = blockIdx.x;
    int t = bt & (T_ - 1);
    int wave = threadIdx.x >> 6;
    int lane = threadIdx.x & 63;
    int l15 = lane & 15;
    int lk = lane >> 4;
    int n0 = blockIdx.y * 128 + wave * 32;

    f32x4 acc[4][2];
    #pragma unroll
    for (int i = 0; i < 4; ++i)
        #pragma unroll
        for (int j = 0; j < 2; ++j)
            acc[i][j] = (f32x4){0.f, 0.f, 0.f, 0.f};

    if (t > 0) {
        const _Float16* A_h = Ah + (size_t)(bt - 1) * 64 * N_;
        const _Float16* A_l = Al + (size_t)(bt - 1) * 64 * N_;
        const _Float16* B_h = STh + (size_t)bt * N_ * N_;
        const _Float16* B_l = STl + (size_t)bt * N_ * N_;
        #pragma unroll
        for (int kk = 0; kk < 8; ++kk) {
            int kof = kk * 32 + lk * 8;
            half8 ah[4], al[4];
            #pragma unroll
            for (int i = 0; i < 4; ++i) {
                ah[i] = *(const half8*)(A_h + (size_t)(i * 16 + l15) * N_ + kof);
                al[i] = *(const half8*)(A_l + (size_t)(i * 16 + l15) * N_ + kof);
            }
            #pragma unroll
            for (int j = 0; j < 2; ++j) {
                half8 bh = *(const half8*)(B_h + (size_t)(n0 + j * 16 + l15) * N_ + kof);
                half8 bl = *(const half8*)(B_l + (size_t)(n0 + j * 16 + l15) * N_ + kof);
                #pragma unroll
                for (int i = 0; i < 4; ++i) {
                    acc[i][j] = __builtin_amdgcn_mfma_f32_16x16x32_f16(ah[i], bh, acc[i][j], 0, 0, 0);
                    acc[i][j] = __builtin_amdgcn_mfma_f32_16x16x32_f16(al[i], bh, acc[i][j], 0, 0, 0);
                    acc[i][j] = __builtin_amdgcn_mfma_f32_16x16x32_f16(ah[i], bl, acc[i][j], 0, 0, 0);
                }
            }
        }
    }
    float* Ob = O + (size_t)bt * 64 * N_;
    #pragma unroll
    for (int i = 0; i < 4; ++i)
        #pragma unroll
        for (int j = 0; j < 2; ++j)
            #pragma unroll
            for (int r = 0; r < 4; ++r)
                Ob[(size_t)(i * 16 + lk * 4 + r) * N_ + n0 + j * 16 + l15] = acc[i][j][r];
}

// ---------------- K5: combine + readout, wave-parallel ----------------------
// grid (BT,2) x 256. Wave = 16 col-pairs x 4 g-quarters; float2 math;
// butterfly shfl reduce; per-gq j-split readout.
__global__ __launch_bounds__(256, 4) void k_combine2(
    const _Float16* __restrict__ Y1h, const _Float16* __restrict__ Y1l,
    const _Float16* __restrict__ U2h, const _Float16* __restrict__ U2l,
    const float* __restrict__ V2,
    const float* __restrict__ W2, const float* __restrict__ b2,
    const float* __restrict__ A1, const float* __restrict__ c1,
    const float* __restrict__ A2, const float* __restrict__ c2,
    float* __restrict__ out) {
    __shared__ float lw[F2 * 192];     // 24 KB
    __shared__ float la1[32 * 33];     // 4.2 KB, padded
    int bt = blockIdx.x;
    int tid = threadIdx.x;
    for (int i = tid; i < F2 * 192; i += 256) lw[i] = W2[i];
    for (int i = tid; i < 32 * 32; i += 256) la1[(i >> 5) * 33 + (i & 31)] = A1[i];
    __syncthreads();

    int w = tid >> 6;
    int lane = tid & 63;
    int pr = lane & 15;      // col-pair within wave
    int gq = lane >> 4;      // g-quarter 0..3
    int n = blockIdx.y * 128 + w * 32 + pr * 2;

    const _Float16* yh = Y1h + (size_t)bt * 64 * N_;
    const _Float16* yl = Y1l + (size_t)bt * 64 * N_;
    const _Float16* uh = U2h + (size_t)bt * 64 * N_;
    const _Float16* ul = U2l + (size_t)bt * 64 * N_;
    const float*    vv = V2  + (size_t)bt * 64 * N_;

    float2 y2[F2];
    #pragma unroll
    for (int f = 0; f < F2; ++f) y2[f] = make_float2(0.f, 0.f);

    for (int i = 0; i < 16; ++i) {
        int g = gq * 16 + i;
        size_t o = (size_t)g * N_ + n;
        half2v a0 = *(const half2v*)(yh + o);
        half2v a1 = *(const half2v*)(yl + o);
        half2v b0 = *(const half2v*)(uh + o);
        half2v b1v = *(const half2v*)(ul + o);
        float2 zv = *(const float2*)(vv + o);
        float2 zy = make_float2((float)a0[0] + (float)a1[0], (float)a0[1] + (float)a1[1]);
        float2 zu = make_float2((float)b0[0] + (float)b1v[0], (float)b0[1] + (float)b1v[1]);
        const float* wrow = lw + g;
        #pragma unroll
        for (int f = 0; f < F2; ++f) {
            float wy = wrow[f * 192];
            float wu = wrow[f * 192 + 64];
            float wz = wrow[f * 192 + 128];
            y2[f].x += wy * zy.x + wu * zu.x + wz * zv.x;
            y2[f].y += wy * zy.y + wu * zu.y + wz * zv.y;
        }
    }
    // reduce over g-quarters (butterfly -> all lanes full)
    #pragma unroll
    for (int f = 0; f < F2; ++f) {
        y2[f].x += __shfl_xor(y2[f].x, 16, 64);
        y2[f].y += __shfl_xor(y2[f].y, 16, 64);
        y2[f].x += __shfl_xor(y2[f].x, 32, 64);
        y2[f].y += __shfl_xor(y2[f].y, 32, 64);
    }
    #pragma unroll
    for (int f = 0; f < F2; ++f) {
        float bb = b2[f];
        y2[f].x = tanh_fast(y2[f].x + bb);
        y2[f].y = tanh_fast(y2[f].y + bb);
    }
    // readout: each gq handles 8 of 32 j's, then butterfly-sum outputs
    float2 o0 = make_float2(0.f, 0.f), o1 = make_float2(0.f, 0.f);
    #pragma unroll
    for (int jj = 0; jj < 8; ++jj) {
        int j = gq * 8 + jj;
        float cj = c1[j];
        float2 s = make_float2(cj, cj);
        const float* a1r = la1 + j * 33;
        #pragma unroll
        for (int f = 0; f < F2; ++f) {
            float a = a1r[f];
            s.x += a * y2[f].x;
            s.y += a * y2[f].y;
        }
        float2 hj = make_float2(tanh_fast(s.x), tanh_fast(s.y));
        float a20 = A2[j], a21 = A2[32 + j];
        o0.x += a20 * hj.x; o0.y += a20 * hj.y;
        o1.x += a21 * hj.x; o1.y += a21 * hj.y;
    }
    o0.x += __shfl_xor(o0.x, 16, 64); o0.y += __shfl_xor(o0.y, 16, 64);
    o0.x += __shfl_xor(o0.x, 32, 64); o0.y += __shfl_xor(o0.y, 32, 64);
    o1.x += __shfl_xor(o1.x, 16, 64); o1.y += __shfl_xor(o1.y, 16, 64);
    o1.x += __shfl_xor(o1.x, 32, 64); o1.y += __shfl_xor(o1.y, 32, 64);
    if (gq == 0) {
        float c20 = c2[0], c21 = c2[1];
        *(float2*)(out + ((size_t)bt * 2 + 0) * N_ + n) = make_float2(o0.x + c20, o0.y + c20);
        *(float2*)(out + ((size_t)bt * 2 + 1) * N_ + n) = make_float2(o1.x + c21, o1.y + c21);
    }
}

extern "C" void kernel_launch(void* const* d_in, const int* in_sizes, int n_in,
                              void* d_out, int out_size, void* d_ws, size_t ws_size,
                              hipStream_t stream) {
    const float* x  = (const float*)d_in[0];
    const float* S  = (const float*)d_in[1];
    const float* W1 = (const float*)d_in[2];
    const float* b1 = (const float*)d_in[3];
    const float* W2 = (const float*)d_in[4];
    const float* b2 = (const float*)d_in[5];
    const float* A1 = (const float*)d_in[6];
    const float* c1 = (const float*)d_in[7];
    const float* A2 = (const float*)d_in[8];
    const float* c2 = (const float*)d_in[9];
    float* out = (float*)d_out;

    char* ws = (char*)d_ws;
    const size_t SZ_ST = (size_t)BT_ * N_ * N_ * 2;   // 67,108,864 per plane
    const size_t SZ_U1 = (size_t)BT_ * 16 * N_ * 2;   //  4,194,304 per plane
    const size_t SZ_Y1 = (size_t)BT_ * 64 * N_ * 2;   // 16,777,216 per plane
    const size_t SZ_V2 = (size_t)BT_ * 64 * N_ * 4;   // 33,554,432 (f32)
    size_t off = 0;
    _Float16* STh = (_Float16*)(ws + off); off += SZ_ST;
    _Float16* STl = (_Float16*)(ws + off); off += SZ_ST;
    _Float16* Y1h = (_Float16*)(ws + off); off += SZ_Y1;
    _Float16* Y1l = (_Float16*)(ws + off); off += SZ_Y1;
    _Float16* U2h = (_Float16*)(ws + off); off += SZ_Y1;
    _Float16* U2l = (_Float16*)(ws + off); off += SZ_Y1;
    float*    V2  = (float*)(ws + off);
    _Float16* U1h = (_Float16*)(ws + off); off += SZ_U1;
    _Float16* U1l = (_Float16*)(ws + off); off += SZ_U1;
    off = off - 2 * SZ_U1 + SZ_V2;
    if (ws_size < off) return;  // insufficient scratch -> clean failure

    k_transpose_s<<<dim3(BT_, 4), 512, 0, stream>>>(S, STh, STl);
    k_chain1x<<<dim3(BT_, 2), 256, 0, stream>>>(x, STh, STl, U1h, U1l);
    k_layer1b<<<dim3(BT_, 2), 256, 0, stream>>>(U1h, U1l, STh, STl, x, W1, b1, Y1h, Y1l);
    k_chain<4><<<dim3(BT_, 2), 256, 0, stream>>>(Y1h, Y1l, STh, STl, U2h, U2l);
    k_chainV2f<<<dim3(BT_, 2), 256, 0, stream>>>(U2h, U2l, STh, STl, V2);
    k_combine2<<<dim3(BT_, 2), 256, 0, stream>>>(Y1h, Y1l, U2h, U2l, V2,
                                                 W2, b2, A1, c1, A2, c2, out);
}

// Round 7
// 316.908 us; speedup vs baseline: 1.9940x; 1.9940x over previous
//
#include <hip/hip_runtime.h>
#include <hip/hip_fp16.h>

typedef _Float16 half8 __attribute__((ext_vector_type(8)));
typedef _Float16 half4v __attribute__((ext_vector_type(4)));
typedef float f32x4 __attribute__((ext_vector_type(4)));

static constexpr int B_ = 8, T_ = 64, N_ = 256;
static constexpr int F0 = 12, F1 = 64, F2 = 32;
static constexpr int BT_ = B_ * T_;

__device__ inline float tanh_fast(float x) {
    x = fminf(20.f, fmaxf(-20.f, x));
    float e = __expf(2.f * x);
    return (e - 1.f) / (e + 1.f);
}

// ---------------- K0: S (BT,256,256) f32 -> S^T hi/lo fp16 planes ----------
__global__ void k_transpose_s(const float* __restrict__ S,
                              _Float16* __restrict__ STh, _Float16* __restrict__ STl) {
    int bt = blockIdx.x;
    int n0 = blockIdx.y * 64;
    const float* s = S + (size_t)bt * N_ * N_;
    _Float16* sth = STh + (size_t)bt * N_ * N_;
    _Float16* stl = STl + (size_t)bt * N_ * N_;
    __shared__ float tile[64][65];
    int tx = threadIdx.x & 15;
    int ty = threadIdx.x >> 4;
    for (int tm = 0; tm < N_; tm += 64) {
        #pragma unroll
        for (int r = ty; r < 64; r += 32) {
            float4 v = *(const float4*)(s + (size_t)(tm + r) * N_ + n0 + tx * 4);
            tile[r][tx * 4 + 0] = v.x;
            tile[r][tx * 4 + 1] = v.y;
            tile[r][tx * 4 + 2] = v.z;
            tile[r][tx * 4 + 3] = v.w;
        }
        __syncthreads();
        #pragma unroll
        for (int rr = ty; rr < 64; rr += 32) {
            half4v h, l;
            #pragma unroll
            for (int c = 0; c < 4; ++c) {
                float v = tile[tx * 4 + c][rr];
                _Float16 hh = (_Float16)v;
                h[c] = hh;
                l[c] = (_Float16)(v - (float)hh);
            }
            size_t o = (size_t)(n0 + rr) * N_ + tm + tx * 4;
            *(half4v*)(sth + o) = h;
            *(half4v*)(stl + o) = l;
        }
        __syncthreads();
    }
}

// ---------------- K1: U1(b,t) = x(b,t-1) @ S(b,t); grid (BT,2), wave=32 cols
__global__ void k_chain1x(const float* __restrict__ x,
                          const _Float16* __restrict__ STh, const _Float16* __restrict__ STl,
                          _Float16* __restrict__ Oh, _Float16* __restrict__ Ol) {
    int bt = blockIdx.x;
    int t = bt & (T_ - 1);
    int wave = threadIdx.x >> 6;
    int lane = threadIdx.x & 63;
    int l15 = lane & 15;
    int lk = lane >> 4;
    int n0 = blockIdx.y * 128 + wave * 32;

    f32x4 acc[2];
    #pragma unroll
    for (int j = 0; j < 2; ++j) acc[j] = (f32x4){0.f, 0.f, 0.f, 0.f};

    if (t > 0) {
        const float* A = x + (size_t)(bt - 1) * F0 * N_;
        const _Float16* B_h = STh + (size_t)bt * N_ * N_;
        const _Float16* B_l = STl + (size_t)bt * N_ * N_;
        #pragma unroll
        for (int kk = 0; kk < 8; ++kk) {
            int kof = kk * 32 + lk * 8;
            half8 ah = {}, al = {};
            if (l15 < F0) {
                const float* ar = A + (size_t)l15 * N_ + kof;
                float4 v0 = *(const float4*)(ar);
                float4 v1 = *(const float4*)(ar + 4);
                float vv[8] = {v0.x, v0.y, v0.z, v0.w, v1.x, v1.y, v1.z, v1.w};
                #pragma unroll
                for (int c = 0; c < 8; ++c) {
                    _Float16 hh = (_Float16)vv[c];
                    ah[c] = hh;
                    al[c] = (_Float16)(vv[c] - (float)hh);
                }
            }
            #pragma unroll
            for (int j = 0; j < 2; ++j) {
                half8 bh = *(const half8*)(B_h + (size_t)(n0 + j * 16 + l15) * N_ + kof);
                half8 bl = *(const half8*)(B_l + (size_t)(n0 + j * 16 + l15) * N_ + kof);
                acc[j] = __builtin_amdgcn_mfma_f32_16x16x32_f16(ah, bh, acc[j], 0, 0, 0);
                acc[j] = __builtin_amdgcn_mfma_f32_16x16x32_f16(al, bh, acc[j], 0, 0, 0);
                acc[j] = __builtin_amdgcn_mfma_f32_16x16x32_f16(ah, bl, acc[j], 0, 0, 0);
            }
        }
    }
    _Float16* O_h = Oh + (size_t)bt * 16 * N_;
    _Float16* O_l = Ol + (size_t)bt * 16 * N_;
    #pragma unroll
    for (int j = 0; j < 2; ++j)
        #pragma unroll
        for (int r = 0; r < 4; ++r) {
            float v = acc[j][r];
            _Float16 h = (_Float16)v;
            size_t idx = (size_t)(lk * 4 + r) * N_ + n0 + j * 16 + l15;
            O_h[idx] = h;
            O_l[idx] = (_Float16)(v - (float)h);
        }
}

// ---------------- K2: V1 = U1(t-1)@S(t); y1 = tanh(b1 + W1 ⋅ [x,U1,V1]) ----
__global__ void k_layer1b(const _Float16* __restrict__ U1h, const _Float16* __restrict__ U1l,
                          const _Float16* __restrict__ STh, const _Float16* __restrict__ STl,
                          const float* __restrict__ x,
                          const float* __restrict__ W1,  // (64,3,12)
                          const float* __restrict__ b1,
                          _Float16* __restrict__ Y1h, _Float16* __restrict__ Y1l) {
    __shared__ float v1s[16][132];
    int bt = blockIdx.x;
    int t = bt & (T_ - 1);
    int c0 = blockIdx.y * 128;
    int wave = threadIdx.x >> 6;
    int lane = threadIdx.x & 63;
    int l15 = lane & 15;
    int lk = lane >> 4;
    int n0 = c0 + wave * 32;

    f32x4 acc[2];
    #pragma unroll
    for (int j = 0; j < 2; ++j) acc[j] = (f32x4){0.f, 0.f, 0.f, 0.f};

    if (t > 0) {
        const _Float16* A_h = U1h + (size_t)(bt - 1) * 16 * N_;
        const _Float16* A_l = U1l + (size_t)(bt - 1) * 16 * N_;
        const _Float16* B_h = STh + (size_t)bt * N_ * N_;
        const _Float16* B_l = STl + (size_t)bt * N_ * N_;
        #pragma unroll
        for (int kk = 0; kk < 8; ++kk) {
            int kof = kk * 32 + lk * 8;
            half8 ah = *(const half8*)(A_h + (size_t)l15 * N_ + kof);
            half8 al = *(const half8*)(A_l + (size_t)l15 * N_ + kof);
            #pragma unroll
            for (int j = 0; j < 2; ++j) {
                half8 bh = *(const half8*)(B_h + (size_t)(n0 + j * 16 + l15) * N_ + kof);
                half8 bl = *(const half8*)(B_l + (size_t)(n0 + j * 16 + l15) * N_ + kof);
                acc[j] = __builtin_amdgcn_mfma_f32_16x16x32_f16(ah, bh, acc[j], 0, 0, 0);
                acc[j] = __builtin_amdgcn_mfma_f32_16x16x32_f16(al, bh, acc[j], 0, 0, 0);
                acc[j] = __builtin_amdgcn_mfma_f32_16x16x32_f16(ah, bl, acc[j], 0, 0, 0);
            }
        }
    }
    #pragma unroll
    for (int j = 0; j < 2; ++j)
        #pragma unroll
        for (int r = 0; r < 4; ++r)
            v1s[lk * 4 + r][wave * 32 + j * 16 + l15] = acc[j][r];
    __syncthreads();

    int col = threadIdx.x & 127;
    int fh = threadIdx.x >> 7;
    int n = c0 + col;
    const float* xc = x + (size_t)bt * F0 * N_;
    const _Float16* u1hc = U1h + (size_t)bt * 16 * N_;
    const _Float16* u1lc = U1l + (size_t)bt * 16 * N_;
    float z0[F0], z1[F0], z2[F0];
    #pragma unroll
    for (int g = 0; g < F0; ++g) {
        z0[g] = xc[(size_t)g * N_ + n];
        z1[g] = (float)u1hc[(size_t)g * N_ + n] + (float)u1lc[(size_t)g * N_ + n];
        z2[g] = v1s[g][col];
    }
    _Float16* yh = Y1h + (size_t)bt * F1 * N_;
    _Float16* yl = Y1l + (size_t)bt * F1 * N_;
    #pragma unroll
    for (int ff = 0; ff < 32; ++ff) {
        int f = fh * 32 + ff;
        float a2 = b1[f];
        const float* w = W1 + f * 36;
        #pragma unroll
        for (int g = 0; g < F0; ++g)
            a2 += w[g] * z0[g] + w[12 + g] * z1[g] + w[24 + g] * z2[g];
        float yv = tanh_fast(a2);
        _Float16 h = (_Float16)yv;
        yh[(size_t)f * N_ + n] = h;
        yl[(size_t)f * N_ + n] = (_Float16)(yv - (float)h);
    }
}

// ---------------- K3: U2(b,t) = Y1(b,t-1) @ S(b,t); grid (BT,2), wave=32 cols
template <int MT>
__global__ void k_chain(const _Float16* __restrict__ Ah, const _Float16* __restrict__ Al,
                        const _Float16* __restrict__ STh, const _Float16* __restrict__ STl,
                        _Float16* __restrict__ Oh, _Float16* __restrict__ Ol) {
    constexpr int M = 16 * MT;
    int bt = blockIdx.x;
    int t = bt & (T_ - 1);
    int wave = threadIdx.x >> 6;
    int lane = threadIdx.x & 63;
    int l15 = lane & 15;
    int lk = lane >> 4;
    int n0 = blockIdx.y * 128 + wave * 32;

    f32x4 acc[MT][2];
    #pragma unroll
    for (int i = 0; i < MT; ++i)
        #pragma unroll
        for (int j = 0; j < 2; ++j)
            acc[i][j] = (f32x4){0.f, 0.f, 0.f, 0.f};

    if (t > 0) {
        const _Float16* A_h = Ah + (size_t)(bt - 1) * M * N_;
        const _Float16* A_l = Al + (size_t)(bt - 1) * M * N_;
        const _Float16* B_h = STh + (size_t)bt * N_ * N_;
        const _Float16* B_l = STl + (size_t)bt * N_ * N_;
        #pragma unroll
        for (int kk = 0; kk < 8; ++kk) {
            int kof = kk * 32 + lk * 8;
            half8 ah[MT], al[MT];
            #pragma unroll
            for (int i = 0; i < MT; ++i) {
                ah[i] = *(const half8*)(A_h + (size_t)(i * 16 + l15) * N_ + kof);
                al[i] = *(const half8*)(A_l + (size_t)(i * 16 + l15) * N_ + kof);
            }
            #pragma unroll
            for (int j = 0; j < 2; ++j) {
                half8 bh = *(const half8*)(B_h + (size_t)(n0 + j * 16 + l15) * N_ + kof);
                half8 bl = *(const half8*)(B_l + (size_t)(n0 + j * 16 + l15) * N_ + kof);
                #pragma unroll
                for (int i = 0; i < MT; ++i) {
                    acc[i][j] = __builtin_amdgcn_mfma_f32_16x16x32_f16(ah[i], bh, acc[i][j], 0, 0, 0);
                    acc[i][j] = __builtin_amdgcn_mfma_f32_16x16x32_f16(al[i], bh, acc[i][j], 0, 0, 0);
                    acc[i][j] = __builtin_amdgcn_mfma_f32_16x16x32_f16(ah[i], bl, acc[i][j], 0, 0, 0);
                }
            }
        }
    }
    _Float16* O_h = Oh + (size_t)bt * M * N_;
    _Float16* O_l = Ol + (size_t)bt * M * N_;
    #pragma unroll
    for (int i = 0; i < MT; ++i)
        #pragma unroll
        for (int j = 0; j < 2; ++j)
            #pragma unroll
            for (int r = 0; r < 4; ++r) {
                float v = acc[i][j][r];
                _Float16 h = (_Float16)v;
                size_t idx = (size_t)(i * 16 + lk * 4 + r) * N_ + n0 + j * 16 + l15;
                O_h[idx] = h;
                O_l[idx] = (_Float16)(v - (float)h);
            }
}

// ---------------- K4: V2(b,t) = U2(b,t-1) @ S(b,t), f32 out; grid (BT,2) ----
__global__ void k_chainV2f(const _Float16* __restrict__ Ah, const _Float16* __restrict__ Al,
                           const _Float16* __restrict__ STh, const _Float16* __restrict__ STl,
                           float* __restrict__ O) {
    int bt = blockIdx.x;
    int t = bt & (T_ - 1);
    int wave = threadIdx.x >> 6;
    int lane = threadIdx.x & 63;
    int l15 = lane & 15;
    int lk = lane >> 4;
    int n0 = blockIdx.y * 128 + wave * 32;

    f32x4 acc[4][2];
    #pragma unroll
    for (int i = 0; i < 4; ++i)
        #pragma unroll
        for (int j = 0; j < 2; ++j)
            acc[i][j] = (f32x4){0.f, 0.f, 0.f, 0.f};

    if (t > 0) {
        const _Float16* A_h = Ah + (size_t)(bt - 1) * 64 * N_;
        const _Float16* A_l = Al + (size_t)(bt - 1) * 64 * N_;
        const _Float16* B_h = STh + (size_t)bt * N_ * N_;
        const _Float16* B_l = STl + (size_t)bt * N_ * N_;
        #pragma unroll
        for (int kk = 0; kk < 8; ++kk) {
            int kof = kk * 32 + lk * 8;
            half8 ah[4], al[4];
            #pragma unroll
            for (int i = 0; i < 4; ++i) {
                ah[i] = *(const half8*)(A_h + (size_t)(i * 16 + l15) * N_ + kof);
                al[i] = *(const half8*)(A_l + (size_t)(i * 16 + l15) * N_ + kof);
            }
            #pragma unroll
            for (int j = 0; j < 2; ++j) {
                half8 bh = *(const half8*)(B_h + (size_t)(n0 + j * 16 + l15) * N_ + kof);
                half8 bl = *(const half8*)(B_l + (size_t)(n0 + j * 16 + l15) * N_ + kof);
                #pragma unroll
                for (int i = 0; i < 4; ++i) {
                    acc[i][j] = __builtin_amdgcn_mfma_f32_16x16x32_f16(ah[i], bh, acc[i][j], 0, 0, 0);
                    acc[i][j] = __builtin_amdgcn_mfma_f32_16x16x32_f16(al[i], bh, acc[i][j], 0, 0, 0);
                    acc[i][j] = __builtin_amdgcn_mfma_f32_16x16x32_f16(ah[i], bl, acc[i][j], 0, 0, 0);
                }
            }
        }
    }
    float* Ob = O + (size_t)bt * 64 * N_;
    #pragma unroll
    for (int i = 0; i < 4; ++i)
        #pragma unroll
        for (int j = 0; j < 2; ++j)
            #pragma unroll
            for (int r = 0; r < 4; ++r)
                Ob[(size_t)(i * 16 + lk * 4 + r) * N_ + n0 + j * 16 + l15] = acc[i][j][r];
}

// ---------------- K5: combine + readout, f-half split -----------------------
// grid (BT,2) x 256. tid = fh*128 + col. Per-thread y2[16] (f-subset, full g).
// Exchange tanh'd y2 halves via LDS (reuse W2 buffer), full readout per thread.
__global__ void k_combine2(
    const _Float16* __restrict__ Y1h, const _Float16* __restrict__ Y1l,
    const _Float16* __restrict__ U2h, const _Float16* __restrict__ U2l,
    const float* __restrict__ V2,
    const float* __restrict__ W2, const float* __restrict__ b2,
    const float* __restrict__ A1, const float* __restrict__ c1,
    const float* __restrict__ A2, const float* __restrict__ c2,
    float* __restrict__ out) {
    __shared__ float lw[F2 * 192];     // 24 KB; reused as y2 exchange [32][132]
    __shared__ float la1[32 * 33];     // 4.2 KB, padded
    int bt = blockIdx.x;
    int tid = threadIdx.x;
    for (int i = tid; i < F2 * 192; i += 256) lw[i] = W2[i];
    for (int i = tid; i < 32 * 32; i += 256) la1[(i >> 5) * 33 + (i & 31)] = A1[i];
    __syncthreads();

    int col = tid & 127;
    int fh = tid >> 7;            // wave-uniform (waves 0-1: fh=0, waves 2-3: fh=1)
    int n = blockIdx.y * 128 + col;

    const _Float16* yh = Y1h + (size_t)bt * 64 * N_;
    const _Float16* yl = Y1l + (size_t)bt * 64 * N_;
    const _Float16* uh = U2h + (size_t)bt * 64 * N_;
    const _Float16* ul = U2l + (size_t)bt * 64 * N_;
    const float*    vv = V2  + (size_t)bt * 64 * N_;

    float y2[16];
    #pragma unroll
    for (int ff = 0; ff < 16; ++ff) y2[ff] = 0.f;

    const float* wbase = lw + fh * 16 * 192;
    for (int g = 0; g < 64; ++g) {
        size_t o = (size_t)g * N_ + n;
        float zy = (float)yh[o] + (float)yl[o];
        float zu = (float)uh[o] + (float)ul[o];
        float zv = vv[o];
        const float* wrow = wbase + g;
        #pragma unroll
        for (int ff = 0; ff < 16; ++ff)
            y2[ff] += wrow[ff * 192] * zy + wrow[ff * 192 + 64] * zu + wrow[ff * 192 + 128] * zv;
    }
    #pragma unroll
    for (int ff = 0; ff < 16; ++ff)
        y2[ff] = tanh_fast(y2[ff] + b2[fh * 16 + ff]);

    // exchange halves through LDS (overwrite lw after all g-loops done)
    __syncthreads();
    float* ly = lw;               // [32][132]
    #pragma unroll
    for (int ff = 0; ff < 16; ++ff)
        ly[(fh * 16 + ff) * 132 + col] = y2[ff];
    __syncthreads();

    float y2f[32];
    #pragma unroll
    for (int f = 0; f < 32; ++f) y2f[f] = ly[f * 132 + col];

    float o = 0.f;
    #pragma unroll
    for (int j = 0; j < 32; ++j) {
        const float* a1r = la1 + j * 33;
        float s = c1[j];
        #pragma unroll
        for (int f = 0; f < 32; ++f) s += a1r[f] * y2f[f];
        o += A2[fh * 32 + j] * tanh_fast(s);
    }
    out[((size_t)bt * 2 + fh) * N_ + n] = o + c2[fh];
}

extern "C" void kernel_launch(void* const* d_in, const int* in_sizes, int n_in,
                              void* d_out, int out_size, void* d_ws, size_t ws_size,
                              hipStream_t stream) {
    const float* x  = (const float*)d_in[0];
    const float* S  = (const float*)d_in[1];
    const float* W1 = (const float*)d_in[2];
    const float* b1 = (const float*)d_in[3];
    const float* W2 = (const float*)d_in[4];
    const float* b2 = (const float*)d_in[5];
    const float* A1 = (const float*)d_in[6];
    const float* c1 = (const float*)d_in[7];
    const float* A2 = (const float*)d_in[8];
    const float* c2 = (const float*)d_in[9];
    float* out = (float*)d_out;

    char* ws = (char*)d_ws;
    const size_t SZ_ST = (size_t)BT_ * N_ * N_ * 2;   // 67,108,864 per plane
    const size_t SZ_U1 = (size_t)BT_ * 16 * N_ * 2;   //  4,194,304 per plane
    const size_t SZ_Y1 = (size_t)BT_ * 64 * N_ * 2;   // 16,777,216 per plane
    const size_t SZ_V2 = (size_t)BT_ * 64 * N_ * 4;   // 33,554,432 (f32)
    size_t off = 0;
    _Float16* STh = (_Float16*)(ws + off); off += SZ_ST;
    _Float16* STl = (_Float16*)(ws + off); off += SZ_ST;
    _Float16* Y1h = (_Float16*)(ws + off); off += SZ_Y1;
    _Float16* Y1l = (_Float16*)(ws + off); off += SZ_Y1;
    _Float16* U2h = (_Float16*)(ws + off); off += SZ_Y1;
    _Float16* U2l = (_Float16*)(ws + off); off += SZ_Y1;
    float*    V2  = (float*)(ws + off);
    _Float16* U1h = (_Float16*)(ws + off); off += SZ_U1;
    _Float16* U1l = (_Float16*)(ws + off); off += SZ_U1;
    off = off - 2 * SZ_U1 + SZ_V2;
    if (ws_size < off) return;  // insufficient scratch -> clean failure

    k_transpose_s<<<dim3(BT_, 4), 512, 0, stream>>>(S, STh, STl);
    k_chain1x<<<dim3(BT_, 2), 256, 0, stream>>>(x, STh, STl, U1h, U1l);
    k_layer1b<<<dim3(BT_, 2), 256, 0, stream>>>(U1h, U1l, STh, STl, x, W1, b1, Y1h, Y1l);
    k_chain<4><<<dim3(BT_, 2), 256, 0, stream>>>(Y1h, Y1l, STh, STl, U2h, U2l);
    k_chainV2f<<<dim3(BT_, 2), 256, 0, stream>>>(U2h, U2l, STh, STl, V2);
    k_combine2<<<dim3(BT_, 2), 256, 0, stream>>>(Y1h, Y1l, U2h, U2l, V2,
                                                 W2, b2, A1, c1, A2, c2, out);
}

// Round 8
// 288.185 us; speedup vs baseline: 2.1927x; 1.0997x over previous
//
#include <hip/hip_runtime.h>
#include <hip/hip_fp16.h>

typedef _Float16 half8 __attribute__((ext_vector_type(8)));
typedef _Float16 half4v __attribute__((ext_vector_type(4)));
typedef float f32x4 __attribute__((ext_vector_type(4)));

static constexpr int B_ = 8, T_ = 64, N_ = 256;
static constexpr int F0 = 12, F1 = 64, F2 = 32;
static constexpr int BT_ = B_ * T_;

__device__ inline float tanh_fast(float x) {
    x = fminf(20.f, fmaxf(-20.f, x));
    float e = __expf(2.f * x);
    return (e - 1.f) / (e + 1.f);
}

// ---------------- K0: S (BT,256,256) f32 -> S^T hi/lo fp16 planes ----------
__global__ void k_transpose_s(const float* __restrict__ S,
                              _Float16* __restrict__ STh, _Float16* __restrict__ STl) {
    int bt = blockIdx.x;
    int n0 = blockIdx.y * 64;
    const float* s = S + (size_t)bt * N_ * N_;
    _Float16* sth = STh + (size_t)bt * N_ * N_;
    _Float16* stl = STl + (size_t)bt * N_ * N_;
    __shared__ float tile[64][65];
    int tx = threadIdx.x & 15;
    int ty = threadIdx.x >> 4;
    for (int tm = 0; tm < N_; tm += 64) {
        #pragma unroll
        for (int r = ty; r < 64; r += 32) {
            float4 v = *(const float4*)(s + (size_t)(tm + r) * N_ + n0 + tx * 4);
            tile[r][tx * 4 + 0] = v.x;
            tile[r][tx * 4 + 1] = v.y;
            tile[r][tx * 4 + 2] = v.z;
            tile[r][tx * 4 + 3] = v.w;
        }
        __syncthreads();
        #pragma unroll
        for (int rr = ty; rr < 64; rr += 32) {
            half4v h, l;
            #pragma unroll
            for (int c = 0; c < 4; ++c) {
                float v = tile[tx * 4 + c][rr];
                _Float16 hh = (_Float16)v;
                h[c] = hh;
                l[c] = (_Float16)(v - (float)hh);
            }
            size_t o = (size_t)(n0 + rr) * N_ + tm + tx * 4;
            *(half4v*)(sth + o) = h;
            *(half4v*)(stl + o) = l;
        }
        __syncthreads();
    }
}

// ---------------- K1: U1(b,t) = x(b,t-1) @ S(b,t); grid (BT,2), wave=32 cols
__global__ void k_chain1x(const float* __restrict__ x,
                          const _Float16* __restrict__ STh, const _Float16* __restrict__ STl,
                          _Float16* __restrict__ Oh, _Float16* __restrict__ Ol) {
    int bt = blockIdx.x;
    int t = bt & (T_ - 1);
    int wave = threadIdx.x >> 6;
    int lane = threadIdx.x & 63;
    int l15 = lane & 15;
    int lk = lane >> 4;
    int n0 = blockIdx.y * 128 + wave * 32;

    f32x4 acc[2];
    #pragma unroll
    for (int j = 0; j < 2; ++j) acc[j] = (f32x4){0.f, 0.f, 0.f, 0.f};

    if (t > 0) {
        const float* A = x + (size_t)(bt - 1) * F0 * N_;
        const _Float16* B_h = STh + (size_t)bt * N_ * N_;
        const _Float16* B_l = STl + (size_t)bt * N_ * N_;
        #pragma unroll
        for (int kk = 0; kk < 8; ++kk) {
            int kof = kk * 32 + lk * 8;
            half8 ah = {}, al = {};
            if (l15 < F0) {
                const float* ar = A + (size_t)l15 * N_ + kof;
                float4 v0 = *(const float4*)(ar);
                float4 v1 = *(const float4*)(ar + 4);
                float vv[8] = {v0.x, v0.y, v0.z, v0.w, v1.x, v1.y, v1.z, v1.w};
                #pragma unroll
                for (int c = 0; c < 8; ++c) {
                    _Float16 hh = (_Float16)vv[c];
                    ah[c] = hh;
                    al[c] = (_Float16)(vv[c] - (float)hh);
                }
            }
            #pragma unroll
            for (int j = 0; j < 2; ++j) {
                half8 bh = *(const half8*)(B_h + (size_t)(n0 + j * 16 + l15) * N_ + kof);
                half8 bl = *(const half8*)(B_l + (size_t)(n0 + j * 16 + l15) * N_ + kof);
                acc[j] = __builtin_amdgcn_mfma_f32_16x16x32_f16(ah, bh, acc[j], 0, 0, 0);
                acc[j] = __builtin_amdgcn_mfma_f32_16x16x32_f16(al, bh, acc[j], 0, 0, 0);
                acc[j] = __builtin_amdgcn_mfma_f32_16x16x32_f16(ah, bl, acc[j], 0, 0, 0);
            }
        }
    }
    _Float16* O_h = Oh + (size_t)bt * 16 * N_;
    _Float16* O_l = Ol + (size_t)bt * 16 * N_;
    #pragma unroll
    for (int j = 0; j < 2; ++j)
        #pragma unroll
        for (int r = 0; r < 4; ++r) {
            float v = acc[j][r];
            _Float16 h = (_Float16)v;
            size_t idx = (size_t)(lk * 4 + r) * N_ + n0 + j * 16 + l15;
            O_h[idx] = h;
            O_l[idx] = (_Float16)(v - (float)h);
        }
}

// ---------------- K2: V1 = U1(t-1)@S(t); y1 = tanh(b1 + W1 ⋅ [x,U1,V1]) ----
// Writes Y1 TRANSPOSED: Y1T[col][g] hi/lo (B-operand layout for k_proj).
__global__ void k_layer1b(const _Float16* __restrict__ U1h, const _Float16* __restrict__ U1l,
                          const _Float16* __restrict__ STh, const _Float16* __restrict__ STl,
                          const float* __restrict__ x,
                          const float* __restrict__ W1,  // (64,3,12)
                          const float* __restrict__ b1,
                          _Float16* __restrict__ Y1Th, _Float16* __restrict__ Y1Tl) {
    __shared__ float v1s[16][132];
    int bt = blockIdx.x;
    int t = bt & (T_ - 1);
    int c0 = blockIdx.y * 128;
    int wave = threadIdx.x >> 6;
    int lane = threadIdx.x & 63;
    int l15 = lane & 15;
    int lk = lane >> 4;
    int n0 = c0 + wave * 32;

    f32x4 acc[2];
    #pragma unroll
    for (int j = 0; j < 2; ++j) acc[j] = (f32x4){0.f, 0.f, 0.f, 0.f};

    if (t > 0) {
        const _Float16* A_h = U1h + (size_t)(bt - 1) * 16 * N_;
        const _Float16* A_l = U1l + (size_t)(bt - 1) * 16 * N_;
        const _Float16* B_h = STh + (size_t)bt * N_ * N_;
        const _Float16* B_l = STl + (size_t)bt * N_ * N_;
        #pragma unroll
        for (int kk = 0; kk < 8; ++kk) {
            int kof = kk * 32 + lk * 8;
            half8 ah = *(const half8*)(A_h + (size_t)l15 * N_ + kof);
            half8 al = *(const half8*)(A_l + (size_t)l15 * N_ + kof);
            #pragma unroll
            for (int j = 0; j < 2; ++j) {
                half8 bh = *(const half8*)(B_h + (size_t)(n0 + j * 16 + l15) * N_ + kof);
                half8 bl = *(const half8*)(B_l + (size_t)(n0 + j * 16 + l15) * N_ + kof);
                acc[j] = __builtin_amdgcn_mfma_f32_16x16x32_f16(ah, bh, acc[j], 0, 0, 0);
                acc[j] = __builtin_amdgcn_mfma_f32_16x16x32_f16(al, bh, acc[j], 0, 0, 0);
                acc[j] = __builtin_amdgcn_mfma_f32_16x16x32_f16(ah, bl, acc[j], 0, 0, 0);
            }
        }
    }
    #pragma unroll
    for (int j = 0; j < 2; ++j)
        #pragma unroll
        for (int r = 0; r < 4; ++r)
            v1s[lk * 4 + r][wave * 32 + j * 16 + l15] = acc[j][r];
    __syncthreads();

    int col = threadIdx.x & 127;
    int fh = threadIdx.x >> 7;
    int n = c0 + col;
    const float* xc = x + (size_t)bt * F0 * N_;
    const _Float16* u1hc = U1h + (size_t)bt * 16 * N_;
    const _Float16* u1lc = U1l + (size_t)bt * 16 * N_;
    float z0[F0], z1[F0], z2[F0];
    #pragma unroll
    for (int g = 0; g < F0; ++g) {
        z0[g] = xc[(size_t)g * N_ + n];
        z1[g] = (float)u1hc[(size_t)g * N_ + n] + (float)u1lc[(size_t)g * N_ + n];
        z2[g] = v1s[g][col];
    }
    half8 hbuf[4], lbuf[4];
    #pragma unroll
    for (int ff = 0; ff < 32; ++ff) {
        int f = fh * 32 + ff;
        float a2 = b1[f];
        const float* w = W1 + f * 36;
        #pragma unroll
        for (int g = 0; g < F0; ++g)
            a2 += w[g] * z0[g] + w[12 + g] * z1[g] + w[24 + g] * z2[g];
        float yv = tanh_fast(a2);
        _Float16 h = (_Float16)yv;
        hbuf[ff >> 3][ff & 7] = h;
        lbuf[ff >> 3][ff & 7] = (_Float16)(yv - (float)h);
    }
    size_t to = ((size_t)bt * N_ + n) * 64 + fh * 32;
    #pragma unroll
    for (int q = 0; q < 4; ++q) {
        *(half8*)(Y1Th + to + q * 8) = hbuf[q];
        *(half8*)(Y1Tl + to + q * 8) = lbuf[q];
    }
}

// ---------------- K3: projections G=W2v@Y1, H=W2u@Y1, Y2a=W2y@Y1 ------------
// grid (BT), 256 thr. A = Wcat (96x64) hi/lo staged in LDS; B = Y1T[col][g].
__global__ void k_proj(const _Float16* __restrict__ Y1Th, const _Float16* __restrict__ Y1Tl,
                       const float* __restrict__ W2,
                       _Float16* __restrict__ Gh, _Float16* __restrict__ Gl,
                       float* __restrict__ Hf, float* __restrict__ Y2a) {
    __shared__ _Float16 wh[96 * 72], wl[96 * 72];
    int bt = blockIdx.x;
    int tid = threadIdx.x;
    for (int i = tid; i < 96 * 64; i += 256) {
        int r = i >> 6, g = i & 63;
        int f, off;
        if (r < 32)      { f = r;      off = 128; }   // W2v -> G
        else if (r < 64) { f = r - 32; off = 64;  }   // W2u -> H
        else             { f = r - 64; off = 0;   }   // W2y -> Y2a
        float v = W2[f * 192 + off + g];
        _Float16 hh = (_Float16)v;
        wh[r * 72 + g] = hh;
        wl[r * 72 + g] = (_Float16)(v - (float)hh);
    }
    __syncthreads();

    int wv = tid >> 6, lane = tid & 63, l15 = lane & 15, lk = lane >> 4;
    int n0 = wv * 64;
    f32x4 acc[6][4];
    #pragma unroll
    for (int i = 0; i < 6; ++i)
        #pragma unroll
        for (int j = 0; j < 4; ++j) acc[i][j] = (f32x4){0.f, 0.f, 0.f, 0.f};

    const _Float16* Bh = Y1Th + (size_t)bt * N_ * 64;
    const _Float16* Bl = Y1Tl + (size_t)bt * N_ * 64;
    #pragma unroll
    for (int kk = 0; kk < 2; ++kk) {
        int kof = kk * 32 + lk * 8;
        half8 bh[4], bl[4];
        #pragma unroll
        for (int j = 0; j < 4; ++j) {
            bh[j] = *(const half8*)(Bh + (size_t)(n0 + j * 16 + l15) * 64 + kof);
            bl[j] = *(const half8*)(Bl + (size_t)(n0 + j * 16 + l15) * 64 + kof);
        }
        #pragma unroll
        for (int i = 0; i < 6; ++i) {
            half8 ah = *(const half8*)(wh + (i * 16 + l15) * 72 + kof);
            half8 al = *(const half8*)(wl + (i * 16 + l15) * 72 + kof);
            #pragma unroll
            for (int j = 0; j < 4; ++j) {
                acc[i][j] = __builtin_amdgcn_mfma_f32_16x16x32_f16(ah, bh[j], acc[i][j], 0, 0, 0);
                acc[i][j] = __builtin_amdgcn_mfma_f32_16x16x32_f16(al, bh[j], acc[i][j], 0, 0, 0);
                acc[i][j] = __builtin_amdgcn_mfma_f32_16x16x32_f16(ah, bl[j], acc[i][j], 0, 0, 0);
            }
        }
    }
    #pragma unroll
    for (int i = 0; i < 6; ++i)
        #pragma unroll
        for (int j = 0; j < 4; ++j)
            #pragma unroll
            for (int r = 0; r < 4; ++r) {
                int row = i * 16 + lk * 4 + r;   // 0..95
                int col = n0 + j * 16 + l15;
                float v = acc[i][j][r];
                if (row < 32) {
                    _Float16 hh = (_Float16)v;
                    size_t o = ((size_t)bt * 32 + row) * N_ + col;
                    Gh[o] = hh;
                    Gl[o] = (_Float16)(v - (float)hh);
                } else if (row < 64) {
                    Hf[((size_t)bt * 32 + row - 32) * N_ + col] = v;
                } else {
                    Y2a[((size_t)bt * 32 + row - 64) * N_ + col] = v;
                }
            }
}

// ---------------- K4: R(b,t) = H(b,t) + G(b,t-1)@S(b,t), hi/lo out ----------
__global__ void k_chainR(const _Float16* __restrict__ Gh, const _Float16* __restrict__ Gl,
                         const _Float16* __restrict__ STh, const _Float16* __restrict__ STl,
                         const float* __restrict__ Hf,
                         _Float16* __restrict__ Rh, _Float16* __restrict__ Rl) {
    int bt = blockIdx.x;
    int t = bt & (T_ - 1);
    int wave = threadIdx.x >> 6;
    int lane = threadIdx.x & 63;
    int l15 = lane & 15;
    int lk = lane >> 4;
    int n0 = blockIdx.y * 128 + wave * 32;

    f32x4 acc[2][2];
    #pragma unroll
    for (int i = 0; i < 2; ++i)
        #pragma unroll
        for (int j = 0; j < 2; ++j) acc[i][j] = (f32x4){0.f, 0.f, 0.f, 0.f};

    if (t > 0) {
        const _Float16* A_h = Gh + (size_t)(bt - 1) * 32 * N_;
        const _Float16* A_l = Gl + (size_t)(bt - 1) * 32 * N_;
        const _Float16* B_h = STh + (size_t)bt * N_ * N_;
        const _Float16* B_l = STl + (size_t)bt * N_ * N_;
        #pragma unroll
        for (int kk = 0; kk < 8; ++kk) {
            int kof = kk * 32 + lk * 8;
            half8 ah[2], al[2];
            #pragma unroll
            for (int i = 0; i < 2; ++i) {
                ah[i] = *(const half8*)(A_h + (size_t)(i * 16 + l15) * N_ + kof);
                al[i] = *(const half8*)(A_l + (size_t)(i * 16 + l15) * N_ + kof);
            }
            #pragma unroll
            for (int j = 0; j < 2; ++j) {
                half8 bh = *(const half8*)(B_h + (size_t)(n0 + j * 16 + l15) * N_ + kof);
                half8 bl = *(const half8*)(B_l + (size_t)(n0 + j * 16 + l15) * N_ + kof);
                #pragma unroll
                for (int i = 0; i < 2; ++i) {
                    acc[i][j] = __builtin_amdgcn_mfma_f32_16x16x32_f16(ah[i], bh, acc[i][j], 0, 0, 0);
                    acc[i][j] = __builtin_amdgcn_mfma_f32_16x16x32_f16(al[i], bh, acc[i][j], 0, 0, 0);
                    acc[i][j] = __builtin_amdgcn_mfma_f32_16x16x32_f16(ah[i], bl, acc[i][j], 0, 0, 0);
                }
            }
        }
    }
    const float* Hb = Hf + (size_t)bt * 32 * N_;
    _Float16* R_h = Rh + (size_t)bt * 32 * N_;
    _Float16* R_l = Rl + (size_t)bt * 32 * N_;
    #pragma unroll
    for (int i = 0; i < 2; ++i)
        #pragma unroll
        for (int j = 0; j < 2; ++j)
            #pragma unroll
            for (int r = 0; r < 4; ++r) {
                size_t idx = (size_t)(i * 16 + lk * 4 + r) * N_ + n0 + j * 16 + l15;
                float v = acc[i][j][r] + Hb[idx];
                _Float16 h = (_Float16)v;
                R_h[idx] = h;
                R_l[idx] = (_Float16)(v - (float)h);
            }
}

// ---------------- K5: y2 = tanh(b2 + Y2a + R(t-1)@S(t)); readout -> out -----
__global__ void k_chainY2(const _Float16* __restrict__ Rh, const _Float16* __restrict__ Rl,
                          const _Float16* __restrict__ STh, const _Float16* __restrict__ STl,
                          const float* __restrict__ Y2a, const float* __restrict__ b2,
                          const float* __restrict__ A1, const float* __restrict__ c1,
                          const float* __restrict__ A2, const float* __restrict__ c2,
                          float* __restrict__ out) {
    __shared__ float y2s[32 * 133];   // 17 KB, pad 133 -> conflict-free
    __shared__ float la1[32 * 33];
    int bt = blockIdx.x;
    int t = bt & (T_ - 1);
    int tid = threadIdx.x;
    for (int i = tid; i < 32 * 32; i += 256) la1[(i >> 5) * 33 + (i & 31)] = A1[i];

    int wave = tid >> 6;
    int lane = tid & 63;
    int l15 = lane & 15;
    int lk = lane >> 4;
    int n0 = blockIdx.y * 128 + wave * 32;

    f32x4 acc[2][2];
    #pragma unroll
    for (int i = 0; i < 2; ++i)
        #pragma unroll
        for (int j = 0; j < 2; ++j) acc[i][j] = (f32x4){0.f, 0.f, 0.f, 0.f};

    if (t > 0) {
        const _Float16* A_h = Rh + (size_t)(bt - 1) * 32 * N_;
        const _Float16* A_l = Rl + (size_t)(bt - 1) * 32 * N_;
        const _Float16* B_h = STh + (size_t)bt * N_ * N_;
        const _Float16* B_l = STl + (size_t)bt * N_ * N_;
        #pragma unroll
        for (int kk = 0; kk < 8; ++kk) {
            int kof = kk * 32 + lk * 8;
            half8 ah[2], al[2];
            #pragma unroll
            for (int i = 0; i < 2; ++i) {
                ah[i] = *(const half8*)(A_h + (size_t)(i * 16 + l15) * N_ + kof);
                al[i] = *(const half8*)(A_l + (size_t)(i * 16 + l15) * N_ + kof);
            }
            #pragma unroll
            for (int j = 0; j < 2; ++j) {
                half8 bh = *(const half8*)(B_h + (size_t)(n0 + j * 16 + l15) * N_ + kof);
                half8 bl = *(const half8*)(B_l + (size_t)(n0 + j * 16 + l15) * N_ + kof);
                #pragma unroll
                for (int i = 0; i < 2; ++i) {
                    acc[i][j] = __builtin_amdgcn_mfma_f32_16x16x32_f16(ah[i], bh, acc[i][j], 0, 0, 0);
                    acc[i][j] = __builtin_amdgcn_mfma_f32_16x16x32_f16(al[i], bh, acc[i][j], 0, 0, 0);
                    acc[i][j] = __builtin_amdgcn_mfma_f32_16x16x32_f16(ah[i], bl, acc[i][j], 0, 0, 0);
                }
            }
        }
    }
    const float* Ya = Y2a + (size_t)bt * 32 * N_;
    int colb0 = wave * 32;
    #pragma unroll
    for (int i = 0; i < 2; ++i)
        #pragma unroll
        for (int j = 0; j < 2; ++j)
            #pragma unroll
            for (int r = 0; r < 4; ++r) {
                int row = i * 16 + lk * 4 + r;
                int colb = colb0 + j * 16 + l15;
                int n = blockIdx.y * 128 + colb;
                y2s[row * 133 + colb] = acc[i][j][r] + Ya[(size_t)row * N_ + n] + b2[row];
            }
    __syncthreads();

    if (tid < 128) {
        int colb = tid;
        int n = blockIdx.y * 128 + colb;
        float y2v[32];
        #pragma unroll
        for (int f = 0; f < 32; ++f) y2v[f] = tanh_fast(y2s[f * 133 + colb]);
        float o0 = 0.f, o1 = 0.f;
        #pragma unroll
        for (int j = 0; j < 32; ++j) {
            const float* a1r = la1 + j * 33;
            float s = c1[j];
            #pragma unroll
            for (int f = 0; f < 32; ++f) s += a1r[f] * y2v[f];
            float hj = tanh_fast(s);
            o0 += A2[j] * hj;
            o1 += A2[32 + j] * hj;
        }
        out[((size_t)bt * 2 + 0) * N_ + n] = o0 + c2[0];
        out[((size_t)bt * 2 + 1) * N_ + n] = o1 + c2[1];
    }
}

extern "C" void kernel_launch(void* const* d_in, const int* in_sizes, int n_in,
                              void* d_out, int out_size, void* d_ws, size_t ws_size,
                              hipStream_t stream) {
    const float* x  = (const float*)d_in[0];
    const float* S  = (const float*)d_in[1];
    const float* W1 = (const float*)d_in[2];
    const float* b1 = (const float*)d_in[3];
    const float* W2 = (const float*)d_in[4];
    const float* b2 = (const float*)d_in[5];
    const float* A1 = (const float*)d_in[6];
    const float* c1 = (const float*)d_in[7];
    const float* A2 = (const float*)d_in[8];
    const float* c2 = (const float*)d_in[9];
    float* out = (float*)d_out;

    char* ws = (char*)d_ws;
    const size_t SZ_ST  = (size_t)BT_ * N_ * N_ * 2;   // 67,108,864 per plane
    const size_t SZ_Y1T = (size_t)BT_ * N_ * 64 * 2;   // 16,777,216 per plane
    const size_t SZ_G   = (size_t)BT_ * 32 * N_ * 2;   //  8,388,608 per plane
    const size_t SZ_H   = (size_t)BT_ * 32 * N_ * 4;   // 16,777,216 (f32)
    size_t off = 0;
    _Float16* STh  = (_Float16*)(ws + off); off += SZ_ST;
    _Float16* STl  = (_Float16*)(ws + off); off += SZ_ST;
    _Float16* Y1Th = (_Float16*)(ws + off); off += SZ_Y1T;
    _Float16* Y1Tl = (_Float16*)(ws + off); off += SZ_Y1T;
    _Float16* Gh   = (_Float16*)(ws + off); off += SZ_G;
    _Float16* Gl   = (_Float16*)(ws + off); off += SZ_G;
    float*    Hf   = (float*)(ws + off); off += SZ_H;
    float*    Y2a  = (float*)(ws + off); off += SZ_H;
    // R region; U1 (dead after k_layer1b) overlays the front of each plane.
    _Float16* Rh   = (_Float16*)(ws + off); off += SZ_G;
    _Float16* Rl   = (_Float16*)(ws + off); off += SZ_G;
    _Float16* U1h  = Rh;
    _Float16* U1l  = Rl;
    if (ws_size < off) return;  // insufficient scratch -> clean failure

    k_transpose_s<<<dim3(BT_, 4), 512, 0, stream>>>(S, STh, STl);
    k_chain1x<<<dim3(BT_, 2), 256, 0, stream>>>(x, STh, STl, U1h, U1l);
    k_layer1b<<<dim3(BT_, 2), 256, 0, stream>>>(U1h, U1l, STh, STl, x, W1, b1, Y1Th, Y1Tl);
    k_proj<<<BT_, 256, 0, stream>>>(Y1Th, Y1Tl, W2, Gh, Gl, Hf, Y2a);
    k_chainR<<<dim3(BT_, 2), 256, 0, stream>>>(Gh, Gl, STh, STl, Hf, Rh, Rl);
    k_chainY2<<<dim3(BT_, 2), 256, 0, stream>>>(Rh, Rl, STh, STl, Y2a, b2,
                                                A1, c1, A2, c2, out);
}

// Round 9
// 261.292 us; speedup vs baseline: 2.4184x; 1.1029x over previous
//
#include <hip/hip_runtime.h>
#include <hip/hip_fp16.h>

typedef _Float16 half8 __attribute__((ext_vector_type(8)));
typedef _Float16 half4v __attribute__((ext_vector_type(4)));
typedef float f32x4 __attribute__((ext_vector_type(4)));

static constexpr int B_ = 8, T_ = 64, N_ = 256;
static constexpr int F0 = 12, F1 = 64, F2 = 32;
static constexpr int BT_ = B_ * T_;

__device__ inline float tanh_fast(float x) {
    x = fminf(20.f, fmaxf(-20.f, x));
    float e = __expf(2.f * x);
    return (e - 1.f) / (e + 1.f);
}

// ---------------- K0: S (BT,256,256) f32 -> S^T hi/lo fp16 planes ----------
__global__ void k_transpose_s(const float* __restrict__ S,
                              _Float16* __restrict__ STh, _Float16* __restrict__ STl) {
    int bt = blockIdx.x;
    int n0 = blockIdx.y * 64;
    const float* s = S + (size_t)bt * N_ * N_;
    _Float16* sth = STh + (size_t)bt * N_ * N_;
    _Float16* stl = STl + (size_t)bt * N_ * N_;
    __shared__ float tile[64][65];
    int tx = threadIdx.x & 15;
    int ty = threadIdx.x >> 4;
    for (int tm = 0; tm < N_; tm += 64) {
        #pragma unroll
        for (int r = ty; r < 64; r += 32) {
            float4 v = *(const float4*)(s + (size_t)(tm + r) * N_ + n0 + tx * 4);
            tile[r][tx * 4 + 0] = v.x;
            tile[r][tx * 4 + 1] = v.y;
            tile[r][tx * 4 + 2] = v.z;
            tile[r][tx * 4 + 3] = v.w;
        }
        __syncthreads();
        #pragma unroll
        for (int rr = ty; rr < 64; rr += 32) {
            half4v h, l;
            #pragma unroll
            for (int c = 0; c < 4; ++c) {
                float v = tile[tx * 4 + c][rr];
                _Float16 hh = (_Float16)v;
                h[c] = hh;
                l[c] = (_Float16)(v - (float)hh);
            }
            size_t o = (size_t)(n0 + rr) * N_ + tm + tx * 4;
            *(half4v*)(sth + o) = h;
            *(half4v*)(stl + o) = l;
        }
        __syncthreads();
    }
}

// ---------------- K0b: x -> xT[bt][n][16] hi/lo (rows 12..15 zero) ----------
__global__ void k_transpose_x(const float* __restrict__ x,
                              _Float16* __restrict__ XTh, _Float16* __restrict__ XTl) {
    int bt = blockIdx.x;
    int n = threadIdx.x;
    const float* xc = x + (size_t)bt * F0 * N_;
    half8 hb[2] = {}, lb[2] = {};
    #pragma unroll
    for (int g = 0; g < F0; ++g) {
        float v = xc[(size_t)g * N_ + n];
        _Float16 hh = (_Float16)v;
        hb[g >> 3][g & 7] = hh;
        lb[g >> 3][g & 7] = (_Float16)(v - (float)hh);
    }
    size_t o = ((size_t)bt * N_ + n) * 16;
    *(half8*)(XTh + o) = hb[0];
    *(half8*)(XTh + o + 8) = hb[1];
    *(half8*)(XTl + o) = lb[0];
    *(half8*)(XTl + o + 8) = lb[1];
}

// ---------------- K1: U1(b,t) = x(b,t-1) @ S(b,t); grid (BT,2) --------------
// Writes U1 row-major (A-operand for chainV1) AND col-major U1T (for combine1).
__global__ void k_chain1x(const float* __restrict__ x,
                          const _Float16* __restrict__ STh, const _Float16* __restrict__ STl,
                          _Float16* __restrict__ Oh, _Float16* __restrict__ Ol,
                          _Float16* __restrict__ OTh, _Float16* __restrict__ OTl) {
    int bt = blockIdx.x;
    int t = bt & (T_ - 1);
    int wave = threadIdx.x >> 6;
    int lane = threadIdx.x & 63;
    int l15 = lane & 15;
    int lk = lane >> 4;
    int n0 = blockIdx.y * 128 + wave * 32;

    f32x4 acc[2];
    #pragma unroll
    for (int j = 0; j < 2; ++j) acc[j] = (f32x4){0.f, 0.f, 0.f, 0.f};

    if (t > 0) {
        const float* A = x + (size_t)(bt - 1) * F0 * N_;
        const _Float16* B_h = STh + (size_t)bt * N_ * N_;
        const _Float16* B_l = STl + (size_t)bt * N_ * N_;
        #pragma unroll
        for (int kk = 0; kk < 8; ++kk) {
            int kof = kk * 32 + lk * 8;
            half8 ah = {}, al = {};
            if (l15 < F0) {
                const float* ar = A + (size_t)l15 * N_ + kof;
                float4 v0 = *(const float4*)(ar);
                float4 v1 = *(const float4*)(ar + 4);
                float vv[8] = {v0.x, v0.y, v0.z, v0.w, v1.x, v1.y, v1.z, v1.w};
                #pragma unroll
                for (int c = 0; c < 8; ++c) {
                    _Float16 hh = (_Float16)vv[c];
                    ah[c] = hh;
                    al[c] = (_Float16)(vv[c] - (float)hh);
                }
            }
            #pragma unroll
            for (int j = 0; j < 2; ++j) {
                half8 bh = *(const half8*)(B_h + (size_t)(n0 + j * 16 + l15) * N_ + kof);
                half8 bl = *(const half8*)(B_l + (size_t)(n0 + j * 16 + l15) * N_ + kof);
                acc[j] = __builtin_amdgcn_mfma_f32_16x16x32_f16(ah, bh, acc[j], 0, 0, 0);
                acc[j] = __builtin_amdgcn_mfma_f32_16x16x32_f16(al, bh, acc[j], 0, 0, 0);
                acc[j] = __builtin_amdgcn_mfma_f32_16x16x32_f16(ah, bl, acc[j], 0, 0, 0);
            }
        }
    }
    _Float16* O_h = Oh + (size_t)bt * 16 * N_;
    _Float16* O_l = Ol + (size_t)bt * 16 * N_;
    #pragma unroll
    for (int j = 0; j < 2; ++j) {
        half4v th, tl;
        #pragma unroll
        for (int r = 0; r < 4; ++r) {
            float v = acc[j][r];
            _Float16 h = (_Float16)v;
            size_t idx = (size_t)(lk * 4 + r) * N_ + n0 + j * 16 + l15;
            O_h[idx] = h;
            O_l[idx] = (_Float16)(v - (float)h);
            th[r] = h;
            tl[r] = (_Float16)(v - (float)h);
        }
        size_t to = ((size_t)bt * N_ + n0 + j * 16 + l15) * 16 + lk * 4;
        *(half4v*)(OTh + to) = th;
        *(half4v*)(OTl + to) = tl;
    }
}

// ---------------- K2: V1(b,t) = U1(b,t-1) @ S(b,t) -> col-major hi/lo -------
__global__ void k_chainV1(const _Float16* __restrict__ Ah, const _Float16* __restrict__ Al,
                          const _Float16* __restrict__ STh, const _Float16* __restrict__ STl,
                          _Float16* __restrict__ OTh, _Float16* __restrict__ OTl) {
    int bt = blockIdx.x;
    int t = bt & (T_ - 1);
    int wave = threadIdx.x >> 6;
    int lane = threadIdx.x & 63;
    int l15 = lane & 15;
    int lk = lane >> 4;
    int n0 = blockIdx.y * 128 + wave * 32;

    f32x4 acc[2];
    #pragma unroll
    for (int j = 0; j < 2; ++j) acc[j] = (f32x4){0.f, 0.f, 0.f, 0.f};

    if (t > 0) {
        const _Float16* A_h = Ah + (size_t)(bt - 1) * 16 * N_;
        const _Float16* A_l = Al + (size_t)(bt - 1) * 16 * N_;
        const _Float16* B_h = STh + (size_t)bt * N_ * N_;
        const _Float16* B_l = STl + (size_t)bt * N_ * N_;
        #pragma unroll
        for (int kk = 0; kk < 8; ++kk) {
            int kof = kk * 32 + lk * 8;
            half8 ah = *(const half8*)(A_h + (size_t)l15 * N_ + kof);
            half8 al = *(const half8*)(A_l + (size_t)l15 * N_ + kof);
            #pragma unroll
            for (int j = 0; j < 2; ++j) {
                half8 bh = *(const half8*)(B_h + (size_t)(n0 + j * 16 + l15) * N_ + kof);
                half8 bl = *(const half8*)(B_l + (size_t)(n0 + j * 16 + l15) * N_ + kof);
                acc[j] = __builtin_amdgcn_mfma_f32_16x16x32_f16(ah, bh, acc[j], 0, 0, 0);
                acc[j] = __builtin_amdgcn_mfma_f32_16x16x32_f16(al, bh, acc[j], 0, 0, 0);
                acc[j] = __builtin_amdgcn_mfma_f32_16x16x32_f16(ah, bl, acc[j], 0, 0, 0);
            }
        }
    }
    #pragma unroll
    for (int j = 0; j < 2; ++j) {
        half4v th, tl;
        #pragma unroll
        for (int r = 0; r < 4; ++r) {
            float v = acc[j][r];
            _Float16 h = (_Float16)v;
            th[r] = h;
            tl[r] = (_Float16)(v - (float)h);
        }
        size_t to = ((size_t)bt * N_ + n0 + j * 16 + l15) * 16 + lk * 4;
        *(half4v*)(OTh + to) = th;
        *(half4v*)(OTl + to) = tl;
    }
}

// ---------------- K3: y1 = tanh(W1cat @ Zcat + b1) -> Y1T hi/lo -------------
// Zcat^T[col] = [xT(16) | U1T(16) | V1T(16) | 0(16)]; W1cat (64x64) in LDS.
__global__ void k_combine1(const _Float16* __restrict__ XTh, const _Float16* __restrict__ XTl,
                           const _Float16* __restrict__ U1Th, const _Float16* __restrict__ U1Tl,
                           const _Float16* __restrict__ V1Th, const _Float16* __restrict__ V1Tl,
                           const float* __restrict__ W1, const float* __restrict__ b1,
                           _Float16* __restrict__ Y1Th, _Float16* __restrict__ Y1Tl) {
    __shared__ _Float16 wh[64 * 72], wl[64 * 72];
    int bt = blockIdx.x;
    int tid = threadIdx.x;
    for (int i = tid; i < 64 * 72; i += 256) {
        int f = i / 72, k = i % 72;
        float v = 0.f;
        if (k < 12) v = W1[f * 36 + k];
        else if (k >= 16 && k < 28) v = W1[f * 36 + 12 + (k - 16)];
        else if (k >= 32 && k < 44) v = W1[f * 36 + 24 + (k - 32)];
        _Float16 hh = (_Float16)v;
        wh[i] = hh;
        wl[i] = (_Float16)(v - (float)hh);
    }
    __syncthreads();

    int wv = tid >> 6, lane = tid & 63, l15 = lane & 15, lk = lane >> 4;
    int n0 = wv * 64;
    f32x4 acc[4][4];
    #pragma unroll
    for (int i = 0; i < 4; ++i)
        #pragma unroll
        for (int j = 0; j < 4; ++j) acc[i][j] = (f32x4){0.f, 0.f, 0.f, 0.f};

    #pragma unroll
    for (int kk = 0; kk < 2; ++kk) {
        half8 bh[4], bl[4];
        #pragma unroll
        for (int j = 0; j < 4; ++j) {
            size_t base16 = ((size_t)bt * N_ + n0 + j * 16 + l15) * 16;
            if (kk == 0) {
                if (lk < 2) {
                    bh[j] = *(const half8*)(XTh + base16 + lk * 8);
                    bl[j] = *(const half8*)(XTl + base16 + lk * 8);
                } else {
                    bh[j] = *(const half8*)(U1Th + base16 + (lk - 2) * 8);
                    bl[j] = *(const half8*)(U1Tl + base16 + (lk - 2) * 8);
                }
            } else {
                if (lk < 2) {
                    bh[j] = *(const half8*)(V1Th + base16 + lk * 8);
                    bl[j] = *(const half8*)(V1Tl + base16 + lk * 8);
                } else {
                    bh[j] = half8{};
                    bl[j] = half8{};
                }
            }
        }
        #pragma unroll
        for (int i = 0; i < 4; ++i) {
            half8 ah = *(const half8*)(wh + (i * 16 + l15) * 72 + kk * 32 + lk * 8);
            half8 al = *(const half8*)(wl + (i * 16 + l15) * 72 + kk * 32 + lk * 8);
            #pragma unroll
            for (int j = 0; j < 4; ++j) {
                acc[i][j] = __builtin_amdgcn_mfma_f32_16x16x32_f16(ah, bh[j], acc[i][j], 0, 0, 0);
                acc[i][j] = __builtin_amdgcn_mfma_f32_16x16x32_f16(al, bh[j], acc[i][j], 0, 0, 0);
                acc[i][j] = __builtin_amdgcn_mfma_f32_16x16x32_f16(ah, bl[j], acc[i][j], 0, 0, 0);
            }
        }
    }
    #pragma unroll
    for (int i = 0; i < 4; ++i) {
        float bb[4];
        #pragma unroll
        for (int r = 0; r < 4; ++r) bb[r] = b1[i * 16 + lk * 4 + r];
        #pragma unroll
        for (int j = 0; j < 4; ++j) {
            half4v th, tl;
            #pragma unroll
            for (int r = 0; r < 4; ++r) {
                float yv = tanh_fast(acc[i][j][r] + bb[r]);
                _Float16 h = (_Float16)yv;
                th[r] = h;
                tl[r] = (_Float16)(yv - (float)h);
            }
            size_t to = ((size_t)bt * N_ + n0 + j * 16 + l15) * 64 + i * 16 + lk * 4;
            *(half4v*)(Y1Th + to) = th;
            *(half4v*)(Y1Tl + to) = tl;
        }
    }
}

// ---------------- K4: projections G=W2v@Y1, H=W2u@Y1, Y2a=W2y@Y1 ------------
__global__ void k_proj(const _Float16* __restrict__ Y1Th, const _Float16* __restrict__ Y1Tl,
                       const float* __restrict__ W2,
                       _Float16* __restrict__ Gh, _Float16* __restrict__ Gl,
                       float* __restrict__ Hf, float* __restrict__ Y2a) {
    __shared__ _Float16 wh[96 * 72], wl[96 * 72];
    int bt = blockIdx.x;
    int tid = threadIdx.x;
    for (int i = tid; i < 96 * 64; i += 256) {
        int r = i >> 6, g = i & 63;
        int f, off;
        if (r < 32)      { f = r;      off = 128; }   // W2v -> G
        else if (r < 64) { f = r - 32; off = 64;  }   // W2u -> H
        else             { f = r - 64; off = 0;   }   // W2y -> Y2a
        float v = W2[f * 192 + off + g];
        _Float16 hh = (_Float16)v;
        wh[r * 72 + g] = hh;
        wl[r * 72 + g] = (_Float16)(v - (float)hh);
    }
    __syncthreads();

    int wv = tid >> 6, lane = tid & 63, l15 = lane & 15, lk = lane >> 4;
    int n0 = wv * 64;
    f32x4 acc[6][4];
    #pragma unroll
    for (int i = 0; i < 6; ++i)
        #pragma unroll
        for (int j = 0; j < 4; ++j) acc[i][j] = (f32x4){0.f, 0.f, 0.f, 0.f};

    const _Float16* Bh = Y1Th + (size_t)bt * N_ * 64;
    const _Float16* Bl = Y1Tl + (size_t)bt * N_ * 64;
    #pragma unroll
    for (int kk = 0; kk < 2; ++kk) {
        int kof = kk * 32 + lk * 8;
        half8 bh[4], bl[4];
        #pragma unroll
        for (int j = 0; j < 4; ++j) {
            bh[j] = *(const half8*)(Bh + (size_t)(n0 + j * 16 + l15) * 64 + kof);
            bl[j] = *(const half8*)(Bl + (size_t)(n0 + j * 16 + l15) * 64 + kof);
        }
        #pragma unroll
        for (int i = 0; i < 6; ++i) {
            half8 ah = *(const half8*)(wh + (i * 16 + l15) * 72 + kof);
            half8 al = *(const half8*)(wl + (i * 16 + l15) * 72 + kof);
            #pragma unroll
            for (int j = 0; j < 4; ++j) {
                acc[i][j] = __builtin_amdgcn_mfma_f32_16x16x32_f16(ah, bh[j], acc[i][j], 0, 0, 0);
                acc[i][j] = __builtin_amdgcn_mfma_f32_16x16x32_f16(al, bh[j], acc[i][j], 0, 0, 0);
                acc[i][j] = __builtin_amdgcn_mfma_f32_16x16x32_f16(ah, bl[j], acc[i][j], 0, 0, 0);
            }
        }
    }
    #pragma unroll
    for (int i = 0; i < 6; ++i)
        #pragma unroll
        for (int j = 0; j < 4; ++j)
            #pragma unroll
            for (int r = 0; r < 4; ++r) {
                int row = i * 16 + lk * 4 + r;   // 0..95
                int col = n0 + j * 16 + l15;
                float v = acc[i][j][r];
                if (row < 32) {
                    _Float16 hh = (_Float16)v;
                    size_t o = ((size_t)bt * 32 + row) * N_ + col;
                    Gh[o] = hh;
                    Gl[o] = (_Float16)(v - (float)hh);
                } else if (row < 64) {
                    Hf[((size_t)bt * 32 + row - 32) * N_ + col] = v;
                } else {
                    Y2a[((size_t)bt * 32 + row - 64) * N_ + col] = v;
                }
            }
}

// ---------------- K5: R(b,t) = H(b,t) + G(b,t-1)@S(b,t), hi/lo out ----------
__global__ void k_chainR(const _Float16* __restrict__ Gh, const _Float16* __restrict__ Gl,
                         const _Float16* __restrict__ STh, const _Float16* __restrict__ STl,
                         const float* __restrict__ Hf,
                         _Float16* __restrict__ Rh, _Float16* __restrict__ Rl) {
    int bt = blockIdx.x;
    int t = bt & (T_ - 1);
    int wave = threadIdx.x >> 6;
    int lane = threadIdx.x & 63;
    int l15 = lane & 15;
    int lk = lane >> 4;
    int n0 = blockIdx.y * 128 + wave * 32;

    f32x4 acc[2][2];
    #pragma unroll
    for (int i = 0; i < 2; ++i)
        #pragma unroll
        for (int j = 0; j < 2; ++j) acc[i][j] = (f32x4){0.f, 0.f, 0.f, 0.f};

    if (t > 0) {
        const _Float16* A_h = Gh + (size_t)(bt - 1) * 32 * N_;
        const _Float16* A_l = Gl + (size_t)(bt - 1) * 32 * N_;
        const _Float16* B_h = STh + (size_t)bt * N_ * N_;
        const _Float16* B_l = STl + (size_t)bt * N_ * N_;
        #pragma unroll
        for (int kk = 0; kk < 8; ++kk) {
            int kof = kk * 32 + lk * 8;
            half8 ah[2], al[2];
            #pragma unroll
            for (int i = 0; i < 2; ++i) {
                ah[i] = *(const half8*)(A_h + (size_t)(i * 16 + l15) * N_ + kof);
                al[i] = *(const half8*)(A_l + (size_t)(i * 16 + l15) * N_ + kof);
            }
            #pragma unroll
            for (int j = 0; j < 2; ++j) {
                half8 bh = *(const half8*)(B_h + (size_t)(n0 + j * 16 + l15) * N_ + kof);
                half8 bl = *(const half8*)(B_l + (size_t)(n0 + j * 16 + l15) * N_ + kof);
                #pragma unroll
                for (int i = 0; i < 2; ++i) {
                    acc[i][j] = __builtin_amdgcn_mfma_f32_16x16x32_f16(ah[i], bh, acc[i][j], 0, 0, 0);
                    acc[i][j] = __builtin_amdgcn_mfma_f32_16x16x32_f16(al[i], bh, acc[i][j], 0, 0, 0);
                    acc[i][j] = __builtin_amdgcn_mfma_f32_16x16x32_f16(ah[i], bl, acc[i][j], 0, 0, 0);
                }
            }
        }
    }
    const float* Hb = Hf + (size_t)bt * 32 * N_;
    _Float16* R_h = Rh + (size_t)bt * 32 * N_;
    _Float16* R_l = Rl + (size_t)bt * 32 * N_;
    #pragma unroll
    for (int i = 0; i < 2; ++i)
        #pragma unroll
        for (int j = 0; j < 2; ++j)
            #pragma unroll
            for (int r = 0; r < 4; ++r) {
                size_t idx = (size_t)(i * 16 + lk * 4 + r) * N_ + n0 + j * 16 + l15;
                float v = acc[i][j][r] + Hb[idx];
                _Float16 h = (_Float16)v;
                R_h[idx] = h;
                R_l[idx] = (_Float16)(v - (float)h);
            }
}

// ---------------- K6: y2 = tanh(b2 + Y2a + R(t-1)@S(t)); readout -> out -----
__global__ void k_chainY2(const _Float16* __restrict__ Rh, const _Float16* __restrict__ Rl,
                          const _Float16* __restrict__ STh, const _Float16* __restrict__ STl,
                          const float* __restrict__ Y2a, const float* __restrict__ b2,
                          const float* __restrict__ A1, const float* __restrict__ c1,
                          const float* __restrict__ A2, const float* __restrict__ c2,
                          float* __restrict__ out) {
    __shared__ float y2s[32 * 133];   // 17 KB, pad 133 -> conflict-free
    __shared__ float la1[32 * 33];
    int bt = blockIdx.x;
    int t = bt & (T_ - 1);
    int tid = threadIdx.x;
    for (int i = tid; i < 32 * 32; i += 256) la1[(i >> 5) * 33 + (i & 31)] = A1[i];

    int wave = tid >> 6;
    int lane = tid & 63;
    int l15 = lane & 15;
    int lk = lane >> 4;
    int n0 = blockIdx.y * 128 + wave * 32;

    f32x4 acc[2][2];
    #pragma unroll
    for (int i = 0; i < 2; ++i)
        #pragma unroll
        for (int j = 0; j < 2; ++j) acc[i][j] = (f32x4){0.f, 0.f, 0.f, 0.f};

    if (t > 0) {
        const _Float16* A_h = Rh + (size_t)(bt - 1) * 32 * N_;
        const _Float16* A_l = Rl + (size_t)(bt - 1) * 32 * N_;
        const _Float16* B_h = STh + (size_t)bt * N_ * N_;
        const _Float16* B_l = STl + (size_t)bt * N_ * N_;
        #pragma unroll
        for (int kk = 0; kk < 8; ++kk) {
            int kof = kk * 32 + lk * 8;
            half8 ah[2], al[2];
            #pragma unroll
            for (int i = 0; i < 2; ++i) {
                ah[i] = *(const half8*)(A_h + (size_t)(i * 16 + l15) * N_ + kof);
                al[i] = *(const half8*)(A_l + (size_t)(i * 16 + l15) * N_ + kof);
            }
            #pragma unroll
            for (int j = 0; j < 2; ++j) {
                half8 bh = *(const half8*)(B_h + (size_t)(n0 + j * 16 + l15) * N_ + kof);
                half8 bl = *(const half8*)(B_l + (size_t)(n0 + j * 16 + l15) * N_ + kof);
                #pragma unroll
                for (int i = 0; i < 2; ++i) {
                    acc[i][j] = __builtin_amdgcn_mfma_f32_16x16x32_f16(ah[i], bh, acc[i][j], 0, 0, 0);
                    acc[i][j] = __builtin_amdgcn_mfma_f32_16x16x32_f16(al[i], bh, acc[i][j], 0, 0, 0);
                    acc[i][j] = __builtin_amdgcn_mfma_f32_16x16x32_f16(ah[i], bl, acc[i][j], 0, 0, 0);
                }
            }
        }
    }
    const float* Ya = Y2a + (size_t)bt * 32 * N_;
    int colb0 = wave * 32;
    #pragma unroll
    for (int i = 0; i < 2; ++i)
        #pragma unroll
        for (int j = 0; j < 2; ++j)
            #pragma unroll
            for (int r = 0; r < 4; ++r) {
                int row = i * 16 + lk * 4 + r;
                int colb = colb0 + j * 16 + l15;
                int n = blockIdx.y * 128 + colb;
                y2s[row * 133 + colb] = acc[i][j][r] + Ya[(size_t)row * N_ + n] + b2[row];
            }
    __syncthreads();

    if (tid < 128) {
        int colb = tid;
        int n = blockIdx.y * 128 + colb;
        float y2v[32];
        #pragma unroll
        for (int f = 0; f < 32; ++f) y2v[f] = tanh_fast(y2s[f * 133 + colb]);
        float o0 = 0.f, o1 = 0.f;
        #pragma unroll
        for (int j = 0; j < 32; ++j) {
            const float* a1r = la1 + j * 33;
            float s = c1[j];
            #pragma unroll
            for (int f = 0; f < 32; ++f) s += a1r[f] * y2v[f];
            float hj = tanh_fast(s);
            o0 += A2[j] * hj;
            o1 += A2[32 + j] * hj;
        }
        out[((size_t)bt * 2 + 0) * N_ + n] = o0 + c2[0];
        out[((size_t)bt * 2 + 1) * N_ + n] = o1 + c2[1];
    }
}

extern "C" void kernel_launch(void* const* d_in, const int* in_sizes, int n_in,
                              void* d_out, int out_size, void* d_ws, size_t ws_size,
                              hipStream_t stream) {
    const float* x  = (const float*)d_in[0];
    const float* S  = (const float*)d_in[1];
    const float* W1 = (const float*)d_in[2];
    const float* b1 = (const float*)d_in[3];
    const float* W2 = (const float*)d_in[4];
    const float* b2 = (const float*)d_in[5];
    const float* A1 = (const float*)d_in[6];
    const float* c1 = (const float*)d_in[7];
    const float* A2 = (const float*)d_in[8];
    const float* c2 = (const float*)d_in[9];
    float* out = (float*)d_out;

    char* ws = (char*)d_ws;
    const size_t SZ_ST  = (size_t)BT_ * N_ * N_ * 2;   // 67,108,864 per plane
    const size_t SZ_Y1T = (size_t)BT_ * N_ * 64 * 2;   // 16,777,216 per plane
    const size_t SZ_G   = (size_t)BT_ * 32 * N_ * 2;   //  8,388,608 per plane
    const size_t SZ_H   = (size_t)BT_ * 32 * N_ * 4;   // 16,777,216 (f32)
    const size_t SZ_T16 = (size_t)BT_ * N_ * 16 * 2;   //  4,194,304 (16-row plane)
    size_t off = 0;
    _Float16* STh  = (_Float16*)(ws + off); off += SZ_ST;
    _Float16* STl  = (_Float16*)(ws + off); off += SZ_ST;
    _Float16* Y1Th = (_Float16*)(ws + off); off += SZ_Y1T;
    _Float16* Y1Tl = (_Float16*)(ws + off); off += SZ_Y1T;
    _Float16* Gh   = (_Float16*)(ws + off); off += SZ_G;
    _Float16* Gl   = (_Float16*)(ws + off); off += SZ_G;
    float*    Hf   = (float*)(ws + off); off += SZ_H;
    float*    Y2a  = (float*)(ws + off); off += SZ_H;
    _Float16* Rh   = (_Float16*)(ws + off); off += SZ_G;
    _Float16* Rl   = (_Float16*)(ws + off); off += SZ_G;
    if (ws_size < off) return;  // insufficient scratch -> clean failure

    // overlays (lifetime-disjoint):
    //   XT  (written K0b, read K3)  lives in Hf  region (Hf written later by k_proj)
    //   U1T (written K1,  read K3)  lives in Y2a region first half
    //   V1T (written K2,  read K3)  lives in Y2a region second half
    //   U1 row-major (written K1, read K2) lives in R region (R written by k_chainR)
    _Float16* XTh  = (_Float16*)Hf;
    _Float16* XTl  = XTh + SZ_T16 / 2;
    _Float16* U1Th = (_Float16*)Y2a;
    _Float16* U1Tl = U1Th + SZ_T16 / 2;
    _Float16* V1Th = U1Tl + SZ_T16 / 2;
    _Float16* V1Tl = V1Th + SZ_T16 / 2;
    _Float16* U1h  = Rh;
    _Float16* U1l  = Rl;

    k_transpose_s<<<dim3(BT_, 4), 512, 0, stream>>>(S, STh, STl);
    k_transpose_x<<<BT_, 256, 0, stream>>>(x, XTh, XTl);
    k_chain1x<<<dim3(BT_, 2), 256, 0, stream>>>(x, STh, STl, U1h, U1l, U1Th, U1Tl);
    k_chainV1<<<dim3(BT_, 2), 256, 0, stream>>>(U1h, U1l, STh, STl, V1Th, V1Tl);
    k_combine1<<<BT_, 256, 0, stream>>>(XTh, XTl, U1Th, U1Tl, V1Th, V1Tl, W1, b1, Y1Th, Y1Tl);
    k_proj<<<BT_, 256, 0, stream>>>(Y1Th, Y1Tl, W2, Gh, Gl, Hf, Y2a);
    k_chainR<<<dim3(BT_, 2), 256, 0, stream>>>(Gh, Gl, STh, STl, Hf, Rh, Rl);
    k_chainY2<<<dim3(BT_, 2), 256, 0, stream>>>(Rh, Rl, STh, STl, Y2a, b2,
                                                A1, c1, A2, c2, out);
}

// Round 10
// 259.718 us; speedup vs baseline: 2.4331x; 1.0061x over previous
//
#include <hip/hip_runtime.h>
#include <hip/hip_fp16.h>

typedef _Float16 half8 __attribute__((ext_vector_type(8)));
typedef _Float16 half4v __attribute__((ext_vector_type(4)));
typedef float f32x4 __attribute__((ext_vector_type(4)));

static constexpr int B_ = 8, T_ = 64, N_ = 256;
static constexpr int F0 = 12, F1 = 64, F2 = 32;
static constexpr int BT_ = B_ * T_;

__device__ inline float tanh_fast(float x) {
    x = fminf(20.f, fmaxf(-20.f, x));
    float e = __expf(2.f * x);
    return (e - 1.f) / (e + 1.f);
}

// ---------------- K0: S (BT,256,256) f32 -> S^T hi/lo fp16 planes ----------
// grid (BT,4): block owns 64 output rows (n), loops over 2 m-tiles of 128.
// Load: float4 coalesced; store: half8 -> 256B-contiguous rows per plane.
__global__ __launch_bounds__(512) void k_transpose_s(const float* __restrict__ S,
                              _Float16* __restrict__ STh, _Float16* __restrict__ STl) {
    __shared__ float tile[128][65];
    int bt = blockIdx.x;
    int n0 = blockIdx.y * 64;
    const float* s = S + (size_t)bt * N_ * N_;
    _Float16* sth = STh + (size_t)bt * N_ * N_;
    _Float16* stl = STl + (size_t)bt * N_ * N_;
    int q = threadIdx.x & 15;        // n-quad (4 cols)
    int r0 = threadIdx.x >> 4;       // 0..31
    for (int m0 = 0; m0 < N_; m0 += 128) {
        #pragma unroll
        for (int rr = r0; rr < 128; rr += 32) {
            float4 v = *(const float4*)(s + (size_t)(m0 + rr) * N_ + n0 + q * 4);
            tile[rr][q * 4 + 0] = v.x;
            tile[rr][q * 4 + 1] = v.y;
            tile[rr][q * 4 + 2] = v.z;
            tile[rr][q * 4 + 3] = v.w;
        }
        __syncthreads();
        // store: ST[n0+nn][m0 + mg*8 ..] ; 16 lanes x 16B = 256B per row-plane
        #pragma unroll
        for (int nn = r0; nn < 64; nn += 32) {
            half8 h, l;
            #pragma unroll
            for (int e = 0; e < 8; ++e) {
                float v = tile[q * 8 + e][nn];
                _Float16 hh = (_Float16)v;
                h[e] = hh;
                l[e] = (_Float16)(v - (float)hh);
            }
            size_t o = (size_t)(n0 + nn) * N_ + m0 + q * 8;
            *(half8*)(sth + o) = h;
            *(half8*)(stl + o) = l;
        }
        __syncthreads();
    }
}

// ---------------- K0b: x -> xT[bt][n][16] hi/lo (rows 12..15 zero) ----------
__global__ void k_transpose_x(const float* __restrict__ x,
                              _Float16* __restrict__ XTh, _Float16* __restrict__ XTl) {
    int bt = blockIdx.x;
    int n = threadIdx.x;
    const float* xc = x + (size_t)bt * F0 * N_;
    half8 hb[2] = {}, lb[2] = {};
    #pragma unroll
    for (int g = 0; g < F0; ++g) {
        float v = xc[(size_t)g * N_ + n];
        _Float16 hh = (_Float16)v;
        hb[g >> 3][g & 7] = hh;
        lb[g >> 3][g & 7] = (_Float16)(v - (float)hh);
    }
    size_t o = ((size_t)bt * N_ + n) * 16;
    *(half8*)(XTh + o) = hb[0];
    *(half8*)(XTh + o + 8) = hb[1];
    *(half8*)(XTl + o) = lb[0];
    *(half8*)(XTl + o + 8) = lb[1];
}

// ---------------- K1: U1(b,t) = x(b,t-1) @ S(b,t); grid (BT,2) --------------
// Writes U1 row-major (A-operand for chainV1) AND col-major U1T (for combine1).
__global__ void k_chain1x(const float* __restrict__ x,
                          const _Float16* __restrict__ STh, const _Float16* __restrict__ STl,
                          _Float16* __restrict__ Oh, _Float16* __restrict__ Ol,
                          _Float16* __restrict__ OTh, _Float16* __restrict__ OTl) {
    int bt = blockIdx.x;
    int t = bt & (T_ - 1);
    int wave = threadIdx.x >> 6;
    int lane = threadIdx.x & 63;
    int l15 = lane & 15;
    int lk = lane >> 4;
    int n0 = blockIdx.y * 128 + wave * 32;

    f32x4 acc[2];
    #pragma unroll
    for (int j = 0; j < 2; ++j) acc[j] = (f32x4){0.f, 0.f, 0.f, 0.f};

    if (t > 0) {
        const float* A = x + (size_t)(bt - 1) * F0 * N_;
        const _Float16* B_h = STh + (size_t)bt * N_ * N_;
        const _Float16* B_l = STl + (size_t)bt * N_ * N_;
        #pragma unroll
        for (int kk = 0; kk < 8; ++kk) {
            int kof = kk * 32 + lk * 8;
            half8 ah = {}, al = {};
            if (l15 < F0) {
                const float* ar = A + (size_t)l15 * N_ + kof;
                float4 v0 = *(const float4*)(ar);
                float4 v1 = *(const float4*)(ar + 4);
                float vv[8] = {v0.x, v0.y, v0.z, v0.w, v1.x, v1.y, v1.z, v1.w};
                #pragma unroll
                for (int c = 0; c < 8; ++c) {
                    _Float16 hh = (_Float16)vv[c];
                    ah[c] = hh;
                    al[c] = (_Float16)(vv[c] - (float)hh);
                }
            }
            #pragma unroll
            for (int j = 0; j < 2; ++j) {
                half8 bh = *(const half8*)(B_h + (size_t)(n0 + j * 16 + l15) * N_ + kof);
                half8 bl = *(const half8*)(B_l + (size_t)(n0 + j * 16 + l15) * N_ + kof);
                acc[j] = __builtin_amdgcn_mfma_f32_16x16x32_f16(ah, bh, acc[j], 0, 0, 0);
                acc[j] = __builtin_amdgcn_mfma_f32_16x16x32_f16(al, bh, acc[j], 0, 0, 0);
                acc[j] = __builtin_amdgcn_mfma_f32_16x16x32_f16(ah, bl, acc[j], 0, 0, 0);
            }
        }
    }
    _Float16* O_h = Oh + (size_t)bt * 16 * N_;
    _Float16* O_l = Ol + (size_t)bt * 16 * N_;
    #pragma unroll
    for (int j = 0; j < 2; ++j) {
        half4v th, tl;
        #pragma unroll
        for (int r = 0; r < 4; ++r) {
            float v = acc[j][r];
            _Float16 h = (_Float16)v;
            size_t idx = (size_t)(lk * 4 + r) * N_ + n0 + j * 16 + l15;
            O_h[idx] = h;
            O_l[idx] = (_Float16)(v - (float)h);
            th[r] = h;
            tl[r] = (_Float16)(v - (float)h);
        }
        size_t to = ((size_t)bt * N_ + n0 + j * 16 + l15) * 16 + lk * 4;
        *(half4v*)(OTh + to) = th;
        *(half4v*)(OTl + to) = tl;
    }
}

// ---------------- K2: V1(b,t) = U1(b,t-1) @ S(b,t) -> col-major hi/lo -------
__global__ void k_chainV1(const _Float16* __restrict__ Ah, const _Float16* __restrict__ Al,
                          const _Float16* __restrict__ STh, const _Float16* __restrict__ STl,
                          _Float16* __restrict__ OTh, _Float16* __restrict__ OTl) {
    int bt = blockIdx.x;
    int t = bt & (T_ - 1);
    int wave = threadIdx.x >> 6;
    int lane = threadIdx.x & 63;
    int l15 = lane & 15;
    int lk = lane >> 4;
    int n0 = blockIdx.y * 128 + wave * 32;

    f32x4 acc[2];
    #pragma unroll
    for (int j = 0; j < 2; ++j) acc[j] = (f32x4){0.f, 0.f, 0.f, 0.f};

    if (t > 0) {
        const _Float16* A_h = Ah + (size_t)(bt - 1) * 16 * N_;
        const _Float16* A_l = Al + (size_t)(bt - 1) * 16 * N_;
        const _Float16* B_h = STh + (size_t)bt * N_ * N_;
        const _Float16* B_l = STl + (size_t)bt * N_ * N_;
        #pragma unroll
        for (int kk = 0; kk < 8; ++kk) {
            int kof = kk * 32 + lk * 8;
            half8 ah = *(const half8*)(A_h + (size_t)l15 * N_ + kof);
            half8 al = *(const half8*)(A_l + (size_t)l15 * N_ + kof);
            #pragma unroll
            for (int j = 0; j < 2; ++j) {
                half8 bh = *(const half8*)(B_h + (size_t)(n0 + j * 16 + l15) * N_ + kof);
                half8 bl = *(const half8*)(B_l + (size_t)(n0 + j * 16 + l15) * N_ + kof);
                acc[j] = __builtin_amdgcn_mfma_f32_16x16x32_f16(ah, bh, acc[j], 0, 0, 0);
                acc[j] = __builtin_amdgcn_mfma_f32_16x16x32_f16(al, bh, acc[j], 0, 0, 0);
                acc[j] = __builtin_amdgcn_mfma_f32_16x16x32_f16(ah, bl, acc[j], 0, 0, 0);
            }
        }
    }
    #pragma unroll
    for (int j = 0; j < 2; ++j) {
        half4v th, tl;
        #pragma unroll
        for (int r = 0; r < 4; ++r) {
            float v = acc[j][r];
            _Float16 h = (_Float16)v;
            th[r] = h;
            tl[r] = (_Float16)(v - (float)h);
        }
        size_t to = ((size_t)bt * N_ + n0 + j * 16 + l15) * 16 + lk * 4;
        *(half4v*)(OTh + to) = th;
        *(half4v*)(OTl + to) = tl;
    }
}

// ---------------- K3: y1 = tanh(W1cat @ Zcat + b1) -> Y1T hi/lo -------------
// Zcat^T[col] = [xT(16) | U1T(16) | V1T(16) | 0(16)]; W1cat (64x64) in LDS.
__global__ void k_combine1(const _Float16* __restrict__ XTh, const _Float16* __restrict__ XTl,
                           const _Float16* __restrict__ U1Th, const _Float16* __restrict__ U1Tl,
                           const _Float16* __restrict__ V1Th, const _Float16* __restrict__ V1Tl,
                           const float* __restrict__ W1, const float* __restrict__ b1,
                           _Float16* __restrict__ Y1Th, _Float16* __restrict__ Y1Tl) {
    __shared__ _Float16 wh[64 * 72], wl[64 * 72];
    int bt = blockIdx.x;
    int tid = threadIdx.x;
    for (int i = tid; i < 64 * 72; i += 256) {
        int f = i / 72, k = i % 72;
        float v = 0.f;
        if (k < 12) v = W1[f * 36 + k];
        else if (k >= 16 && k < 28) v = W1[f * 36 + 12 + (k - 16)];
        else if (k >= 32 && k < 44) v = W1[f * 36 + 24 + (k - 32)];
        _Float16 hh = (_Float16)v;
        wh[i] = hh;
        wl[i] = (_Float16)(v - (float)hh);
    }
    __syncthreads();

    int wv = tid >> 6, lane = tid & 63, l15 = lane & 15, lk = lane >> 4;
    int n0 = wv * 64;
    f32x4 acc[4][4];
    #pragma unroll
    for (int i = 0; i < 4; ++i)
        #pragma unroll
        for (int j = 0; j < 4; ++j) acc[i][j] = (f32x4){0.f, 0.f, 0.f, 0.f};

    #pragma unroll
    for (int kk = 0; kk < 2; ++kk) {
        half8 bh[4], bl[4];
        #pragma unroll
        for (int j = 0; j < 4; ++j) {
            size_t base16 = ((size_t)bt * N_ + n0 + j * 16 + l15) * 16;
            if (kk == 0) {
                if (lk < 2) {
                    bh[j] = *(const half8*)(XTh + base16 + lk * 8);
                    bl[j] = *(const half8*)(XTl + base16 + lk * 8);
                } else {
                    bh[j] = *(const half8*)(U1Th + base16 + (lk - 2) * 8);
                    bl[j] = *(const half8*)(U1Tl + base16 + (lk - 2) * 8);
                }
            } else {
                if (lk < 2) {
                    bh[j] = *(const half8*)(V1Th + base16 + lk * 8);
                    bl[j] = *(const half8*)(V1Tl + base16 + lk * 8);
                } else {
                    bh[j] = half8{};
                    bl[j] = half8{};
                }
            }
        }
        #pragma unroll
        for (int i = 0; i < 4; ++i) {
            half8 ah = *(const half8*)(wh + (i * 16 + l15) * 72 + kk * 32 + lk * 8);
            half8 al = *(const half8*)(wl + (i * 16 + l15) * 72 + kk * 32 + lk * 8);
            #pragma unroll
            for (int j = 0; j < 4; ++j) {
                acc[i][j] = __builtin_amdgcn_mfma_f32_16x16x32_f16(ah, bh[j], acc[i][j], 0, 0, 0);
                acc[i][j] = __builtin_amdgcn_mfma_f32_16x16x32_f16(al, bh[j], acc[i][j], 0, 0, 0);
                acc[i][j] = __builtin_amdgcn_mfma_f32_16x16x32_f16(ah, bl[j], acc[i][j], 0, 0, 0);
            }
        }
    }
    #pragma unroll
    for (int i = 0; i < 4; ++i) {
        float bb[4];
        #pragma unroll
        for (int r = 0; r < 4; ++r) bb[r] = b1[i * 16 + lk * 4 + r];
        #pragma unroll
        for (int j = 0; j < 4; ++j) {
            half4v th, tl;
            #pragma unroll
            for (int r = 0; r < 4; ++r) {
                float yv = tanh_fast(acc[i][j][r] + bb[r]);
                _Float16 h = (_Float16)yv;
                th[r] = h;
                tl[r] = (_Float16)(yv - (float)h);
            }
            size_t to = ((size_t)bt * N_ + n0 + j * 16 + l15) * 64 + i * 16 + lk * 4;
            *(half4v*)(Y1Th + to) = th;
            *(half4v*)(Y1Tl + to) = tl;
        }
    }
}

// ---------------- K4: projections G=W2v@Y1, H=W2u@Y1, Y2a=W2y@Y1 ------------
__global__ void k_proj(const _Float16* __restrict__ Y1Th, const _Float16* __restrict__ Y1Tl,
                       const float* __restrict__ W2,
                       _Float16* __restrict__ Gh, _Float16* __restrict__ Gl,
                       float* __restrict__ Hf, float* __restrict__ Y2a) {
    __shared__ _Float16 wh[96 * 72], wl[96 * 72];
    int bt = blockIdx.x;
    int tid = threadIdx.x;
    for (int i = tid; i < 96 * 64; i += 256) {
        int r = i >> 6, g = i & 63;
        int f, off;
        if (r < 32)      { f = r;      off = 128; }   // W2v -> G
        else if (r < 64) { f = r - 32; off = 64;  }   // W2u -> H
        else             { f = r - 64; off = 0;   }   // W2y -> Y2a
        float v = W2[f * 192 + off + g];
        _Float16 hh = (_Float16)v;
        wh[r * 72 + g] = hh;
        wl[r * 72 + g] = (_Float16)(v - (float)hh);
    }
    __syncthreads();

    int wv = tid >> 6, lane = tid & 63, l15 = lane & 15, lk = lane >> 4;
    int n0 = wv * 64;
    f32x4 acc[6][4];
    #pragma unroll
    for (int i = 0; i < 6; ++i)
        #pragma unroll
        for (int j = 0; j < 4; ++j) acc[i][j] = (f32x4){0.f, 0.f, 0.f, 0.f};

    const _Float16* Bh = Y1Th + (size_t)bt * N_ * 64;
    const _Float16* Bl = Y1Tl + (size_t)bt * N_ * 64;
    #pragma unroll
    for (int kk = 0; kk < 2; ++kk) {
        int kof = kk * 32 + lk * 8;
        half8 bh[4], bl[4];
        #pragma unroll
        for (int j = 0; j < 4; ++j) {
            bh[j] = *(const half8*)(Bh + (size_t)(n0 + j * 16 + l15) * 64 + kof);
            bl[j] = *(const half8*)(Bl + (size_t)(n0 + j * 16 + l15) * 64 + kof);
        }
        #pragma unroll
        for (int i = 0; i < 6; ++i) {
            half8 ah = *(const half8*)(wh + (i * 16 + l15) * 72 + kof);
            half8 al = *(const half8*)(wl + (i * 16 + l15) * 72 + kof);
            #pragma unroll
            for (int j = 0; j < 4; ++j) {
                acc[i][j] = __builtin_amdgcn_mfma_f32_16x16x32_f16(ah, bh[j], acc[i][j], 0, 0, 0);
                acc[i][j] = __builtin_amdgcn_mfma_f32_16x16x32_f16(al, bh[j], acc[i][j], 0, 0, 0);
                acc[i][j] = __builtin_amdgcn_mfma_f32_16x16x32_f16(ah, bl[j], acc[i][j], 0, 0, 0);
            }
        }
    }
    #pragma unroll
    for (int i = 0; i < 6; ++i)
        #pragma unroll
        for (int j = 0; j < 4; ++j)
            #pragma unroll
            for (int r = 0; r < 4; ++r) {
                int row = i * 16 + lk * 4 + r;   // 0..95
                int col = n0 + j * 16 + l15;
                float v = acc[i][j][r];
                if (row < 32) {
                    _Float16 hh = (_Float16)v;
                    size_t o = ((size_t)bt * 32 + row) * N_ + col;
                    Gh[o] = hh;
                    Gl[o] = (_Float16)(v - (float)hh);
                } else if (row < 64) {
                    Hf[((size_t)bt * 32 + row - 32) * N_ + col] = v;
                } else {
                    Y2a[((size_t)bt * 32 + row - 64) * N_ + col] = v;
                }
            }
}

// ---------------- K5: R(b,t) = H(b,t) + G(b,t-1)@S(b,t), hi/lo out ----------
__global__ void k_chainR(const _Float16* __restrict__ Gh, const _Float16* __restrict__ Gl,
                         const _Float16* __restrict__ STh, const _Float16* __restrict__ STl,
                         const float* __restrict__ Hf,
                         _Float16* __restrict__ Rh, _Float16* __restrict__ Rl) {
    int bt = blockIdx.x;
    int t = bt & (T_ - 1);
    int wave = threadIdx.x >> 6;
    int lane = threadIdx.x & 63;
    int l15 = lane & 15;
    int lk = lane >> 4;
    int n0 = blockIdx.y * 128 + wave * 32;

    f32x4 acc[2][2];
    #pragma unroll
    for (int i = 0; i < 2; ++i)
        #pragma unroll
        for (int j = 0; j < 2; ++j) acc[i][j] = (f32x4){0.f, 0.f, 0.f, 0.f};

    if (t > 0) {
        const _Float16* A_h = Gh + (size_t)(bt - 1) * 32 * N_;
        const _Float16* A_l = Gl + (size_t)(bt - 1) * 32 * N_;
        const _Float16* B_h = STh + (size_t)bt * N_ * N_;
        const _Float16* B_l = STl + (size_t)bt * N_ * N_;
        #pragma unroll
        for (int kk = 0; kk < 8; ++kk) {
            int kof = kk * 32 + lk * 8;
            half8 ah[2], al[2];
            #pragma unroll
            for (int i = 0; i < 2; ++i) {
                ah[i] = *(const half8*)(A_h + (size_t)(i * 16 + l15) * N_ + kof);
                al[i] = *(const half8*)(A_l + (size_t)(i * 16 + l15) * N_ + kof);
            }
            #pragma unroll
            for (int j = 0; j < 2; ++j) {
                half8 bh = *(const half8*)(B_h + (size_t)(n0 + j * 16 + l15) * N_ + kof);
                half8 bl = *(const half8*)(B_l + (size_t)(n0 + j * 16 + l15) * N_ + kof);
                #pragma unroll
                for (int i = 0; i < 2; ++i) {
                    acc[i][j] = __builtin_amdgcn_mfma_f32_16x16x32_f16(ah[i], bh, acc[i][j], 0, 0, 0);
                    acc[i][j] = __builtin_amdgcn_mfma_f32_16x16x32_f16(al[i], bh, acc[i][j], 0, 0, 0);
                    acc[i][j] = __builtin_amdgcn_mfma_f32_16x16x32_f16(ah[i], bl, acc[i][j], 0, 0, 0);
                }
            }
        }
    }
    const float* Hb = Hf + (size_t)bt * 32 * N_;
    _Float16* R_h = Rh + (size_t)bt * 32 * N_;
    _Float16* R_l = Rl + (size_t)bt * 32 * N_;
    #pragma unroll
    for (int i = 0; i < 2; ++i)
        #pragma unroll
        for (int j = 0; j < 2; ++j)
            #pragma unroll
            for (int r = 0; r < 4; ++r) {
                size_t idx = (size_t)(i * 16 + lk * 4 + r) * N_ + n0 + j * 16 + l15;
                float v = acc[i][j][r] + Hb[idx];
                _Float16 h = (_Float16)v;
                R_h[idx] = h;
                R_l[idx] = (_Float16)(v - (float)h);
            }
}

// ---------------- K6: y2 = tanh(b2 + Y2a + R(t-1)@S(t)); readout -> out -----
__global__ void k_chainY2(const _Float16* __restrict__ Rh, const _Float16* __restrict__ Rl,
                          const _Float16* __restrict__ STh, const _Float16* __restrict__ STl,
                          const float* __restrict__ Y2a, const float* __restrict__ b2,
                          const float* __restrict__ A1, const float* __restrict__ c1,
                          const float* __restrict__ A2, const float* __restrict__ c2,
                          float* __restrict__ out) {
    __shared__ float y2s[32 * 133];   // 17 KB, pad 133 -> conflict-free
    __shared__ float la1[32 * 33];
    int bt = blockIdx.x;
    int t = bt & (T_ - 1);
    int tid = threadIdx.x;
    for (int i = tid; i < 32 * 32; i += 256) la1[(i >> 5) * 33 + (i & 31)] = A1[i];

    int wave = tid >> 6;
    int lane = tid & 63;
    int l15 = lane & 15;
    int lk = lane >> 4;
    int n0 = blockIdx.y * 128 + wave * 32;

    f32x4 acc[2][2];
    #pragma unroll
    for (int i = 0; i < 2; ++i)
        #pragma unroll
        for (int j = 0; j < 2; ++j) acc[i][j] = (f32x4){0.f, 0.f, 0.f, 0.f};

    if (t > 0) {
        const _Float16* A_h = Rh + (size_t)(bt - 1) * 32 * N_;
        const _Float16* A_l = Rl + (size_t)(bt - 1) * 32 * N_;
        const _Float16* B_h = STh + (size_t)bt * N_ * N_;
        const _Float16* B_l = STl + (size_t)bt * N_ * N_;
        #pragma unroll
        for (int kk = 0; kk < 8; ++kk) {
            int kof = kk * 32 + lk * 8;
            half8 ah[2], al[2];
            #pragma unroll
            for (int i = 0; i < 2; ++i) {
                ah[i] = *(const half8*)(A_h + (size_t)(i * 16 + l15) * N_ + kof);
                al[i] = *(const half8*)(A_l + (size_t)(i * 16 + l15) * N_ + kof);
            }
            #pragma unroll
            for (int j = 0; j < 2; ++j) {
                half8 bh = *(const half8*)(B_h + (size_t)(n0 + j * 16 + l15) * N_ + kof);
                half8 bl = *(const half8*)(B_l + (size_t)(n0 + j * 16 + l15) * N_ + kof);
                #pragma unroll
                for (int i = 0; i < 2; ++i) {
                    acc[i][j] = __builtin_amdgcn_mfma_f32_16x16x32_f16(ah[i], bh, acc[i][j], 0, 0, 0);
                    acc[i][j] = __builtin_amdgcn_mfma_f32_16x16x32_f16(al[i], bh, acc[i][j], 0, 0, 0);
                    acc[i][j] = __builtin_amdgcn_mfma_f32_16x16x32_f16(ah[i], bl, acc[i][j], 0, 0, 0);
                }
            }
        }
    }
    const float* Ya = Y2a + (size_t)bt * 32 * N_;
    int colb0 = wave * 32;
    #pragma unroll
    for (int i = 0; i < 2; ++i)
        #pragma unroll
        for (int j = 0; j < 2; ++j)
            #pragma unroll
            for (int r = 0; r < 4; ++r) {
                int row = i * 16 + lk * 4 + r;
                int colb = colb0 + j * 16 + l15;
                int n = blockIdx.y * 128 + colb;
                y2s[row * 133 + colb] = acc[i][j][r] + Ya[(size_t)row * N_ + n] + b2[row];
            }
    __syncthreads();

    if (tid < 128) {
        int colb = tid;
        int n = blockIdx.y * 128 + colb;
        float y2v[32];
        #pragma unroll
        for (int f = 0; f < 32; ++f) y2v[f] = tanh_fast(y2s[f * 133 + colb]);
        float o0 = 0.f, o1 = 0.f;
        #pragma unroll
        for (int j = 0; j < 32; ++j) {
            const float* a1r = la1 + j * 33;
            float s = c1[j];
            #pragma unroll
            for (int f = 0; f < 32; ++f) s += a1r[f] * y2v[f];
            float hj = tanh_fast(s);
            o0 += A2[j] * hj;
            o1 += A2[32 + j] * hj;
        }
        out[((size_t)bt * 2 + 0) * N_ + n] = o0 + c2[0];
        out[((size_t)bt * 2 + 1) * N_ + n] = o1 + c2[1];
    }
}

extern "C" void kernel_launch(void* const* d_in, const int* in_sizes, int n_in,
                              void* d_out, int out_size, void* d_ws, size_t ws_size,
                              hipStream_t stream) {
    const float* x  = (const float*)d_in[0];
    const float* S  = (const float*)d_in[1];
    const float* W1 = (const float*)d_in[2];
    const float* b1 = (const float*)d_in[3];
    const float* W2 = (const float*)d_in[4];
    const float* b2 = (const float*)d_in[5];
    const float* A1 = (const float*)d_in[6];
    const float* c1 = (const float*)d_in[7];
    const float* A2 = (const float*)d_in[8];
    const float* c2 = (const float*)d_in[9];
    float* out = (float*)d_out;

    char* ws = (char*)d_ws;
    const size_t SZ_ST  = (size_t)BT_ * N_ * N_ * 2;   // 67,108,864 per plane
    const size_t SZ_Y1T = (size_t)BT_ * N_ * 64 * 2;   // 16,777,216 per plane
    const size_t SZ_G   = (size_t)BT_ * 32 * N_ * 2;   //  8,388,608 per plane
    const size_t SZ_H   = (size_t)BT_ * 32 * N_ * 4;   // 16,777,216 (f32)
    const size_t SZ_T16 = (size_t)BT_ * N_ * 16 * 2;   //  4,194,304 (16-row plane)
    size_t off = 0;
    _Float16* STh  = (_Float16*)(ws + off); off += SZ_ST;
    _Float16* STl  = (_Float16*)(ws + off); off += SZ_ST;
    _Float16* Y1Th = (_Float16*)(ws + off); off += SZ_Y1T;
    _Float16* Y1Tl = (_Float16*)(ws + off); off += SZ_Y1T;
    _Float16* Gh   = (_Float16*)(ws + off); off += SZ_G;
    _Float16* Gl   = (_Float16*)(ws + off); off += SZ_G;
    float*    Hf   = (float*)(ws + off); off += SZ_H;
    float*    Y2a  = (float*)(ws + off); off += SZ_H;
    _Float16* Rh   = (_Float16*)(ws + off); off += SZ_G;
    _Float16* Rl   = (_Float16*)(ws + off); off += SZ_G;
    if (ws_size < off) return;  // insufficient scratch -> clean failure

    // overlays (lifetime-disjoint):
    //   XT  (written K0b, read K3)  lives in Hf  region (Hf written later by k_proj)
    //   U1T (written K1,  read K3)  lives in Y2a region first half
    //   V1T (written K2,  read K3)  lives in Y2a region second half
    //   U1 row-major (written K1, read K2) lives in R region (R written by k_chainR)
    _Float16* XTh  = (_Float16*)Hf;
    _Float16* XTl  = XTh + SZ_T16 / 2;
    _Float16* U1Th = (_Float16*)Y2a;
    _Float16* U1Tl = U1Th + SZ_T16 / 2;
    _Float16* V1Th = U1Tl + SZ_T16 / 2;
    _Float16* V1Tl = V1Th + SZ_T16 / 2;
    _Float16* U1h  = Rh;
    _Float16* U1l  = Rl;

    k_transpose_s<<<dim3(BT_, 4), 512, 0, stream>>>(S, STh, STl);
    k_transpose_x<<<BT_, 256, 0, stream>>>(x, XTh, XTl);
    k_chain1x<<<dim3(BT_, 2), 256, 0, stream>>>(x, STh, STl, U1h, U1l, U1Th, U1Tl);
    k_chainV1<<<dim3(BT_, 2), 256, 0, stream>>>(U1h, U1l, STh, STl, V1Th, V1Tl);
    k_combine1<<<BT_, 256, 0, stream>>>(XTh, XTl, U1Th, U1Tl, V1Th, V1Tl, W1, b1, Y1Th, Y1Tl);
    k_proj<<<BT_, 256, 0, stream>>>(Y1Th, Y1Tl, W2, Gh, Gl, Hf, Y2a);
    k_chainR<<<dim3(BT_, 2), 256, 0, stream>>>(Gh, Gl, STh, STl, Hf, Rh, Rl);
    k_chainY2<<<dim3(BT_, 2), 256, 0, stream>>>(Rh, Rl, STh, STl, Y2a, b2,
                                                A1, c1, A2, c2, out);
}

// Round 11
// 247.355 us; speedup vs baseline: 2.5547x; 1.0500x over previous
//
#include <hip/hip_runtime.h>
#include <hip/hip_fp16.h>

typedef _Float16 half8 __attribute__((ext_vector_type(8)));
typedef _Float16 half4v __attribute__((ext_vector_type(4)));
typedef float f32x4 __attribute__((ext_vector_type(4)));

static constexpr int B_ = 8, T_ = 64, N_ = 256;
static constexpr int F0 = 12, F1 = 64, F2 = 32;
static constexpr int BT_ = B_ * T_;

__device__ inline float tanh_fast(float x) {
    x = fminf(20.f, fmaxf(-20.f, x));
    float e = __expf(2.f * x);
    return (e - 1.f) / (e + 1.f);
}

// ---------------- K0: S (BT,256,256) f32 -> S^T hi/lo fp16 planes ----------
// grid (BT,4): block owns 64 output rows (n), 2 m-tiles of 128.
// LDS [n][m] stride 129 (odd): load writes transposed scalar (2-way, free);
// store reads 32B-contiguous per lane, 8rows x 8chunks/wave -> 2-way (free).
// S loads are non-temporal: S is single-use; keep L3 for the ST planes.
__global__ __launch_bounds__(512) void k_transpose_s(const float* __restrict__ S,
                              _Float16* __restrict__ STh, _Float16* __restrict__ STl) {
    __shared__ float tile[64][129];   // 33 KB
    int bt = blockIdx.x;
    int n0 = blockIdx.y * 64;
    const float* s = S + (size_t)bt * N_ * N_;
    _Float16* sth = STh + (size_t)bt * N_ * N_;
    _Float16* stl = STl + (size_t)bt * N_ * N_;
    int q = threadIdx.x & 15;        // n-quad (load)
    int r0 = threadIdx.x >> 4;       // 0..31   (load rows)
    int q2 = threadIdx.x & 7;        // m-chunk (store)
    int nr = threadIdx.x >> 3;       // 0..63   (store rows)
    for (int m0 = 0; m0 < N_; m0 += 128) {
        #pragma unroll
        for (int rr = r0; rr < 128; rr += 32) {
            f32x4 v = __builtin_nontemporal_load(
                (const f32x4*)(s + (size_t)(m0 + rr) * N_ + n0 + q * 4));
            tile[q * 4 + 0][rr] = v[0];
            tile[q * 4 + 1][rr] = v[1];
            tile[q * 4 + 2][rr] = v[2];
            tile[q * 4 + 3][rr] = v[3];
        }
        __syncthreads();
        #pragma unroll
        for (int ci = 0; ci < 2; ++ci) {
            int mc = ci * 8 + q2;            // m-chunk 0..15
            half8 h, l;
            #pragma unroll
            for (int e = 0; e < 8; ++e) {
                float v = tile[nr][mc * 8 + e];
                _Float16 hh = (_Float16)v;
                h[e] = hh;
                l[e] = (_Float16)(v - (float)hh);
            }
            size_t o = (size_t)(n0 + nr) * N_ + m0 + mc * 8;
            *(half8*)(sth + o) = h;
            *(half8*)(stl + o) = l;
        }
        __syncthreads();
    }
}

// ---------------- K0b: x -> xT[bt][n][16] hi/lo (rows 12..15 zero) ----------
__global__ void k_transpose_x(const float* __restrict__ x,
                              _Float16* __restrict__ XTh, _Float16* __restrict__ XTl) {
    int bt = blockIdx.x;
    int n = threadIdx.x;
    const float* xc = x + (size_t)bt * F0 * N_;
    half8 hb[2] = {}, lb[2] = {};
    #pragma unroll
    for (int g = 0; g < F0; ++g) {
        float v = xc[(size_t)g * N_ + n];
        _Float16 hh = (_Float16)v;
        hb[g >> 3][g & 7] = hh;
        lb[g >> 3][g & 7] = (_Float16)(v - (float)hh);
    }
    size_t o = ((size_t)bt * N_ + n) * 16;
    *(half8*)(XTh + o) = hb[0];
    *(half8*)(XTh + o + 8) = hb[1];
    *(half8*)(XTl + o) = lb[0];
    *(half8*)(XTl + o + 8) = lb[1];
}

// ---------------- K1: U1(b,t) = x(b,t-1) @ S(b,t); grid (BT,2) --------------
// Writes U1 row-major (A-operand for chainV1) AND col-major U1T (for combine1).
__global__ void k_chain1x(const float* __restrict__ x,
                          const _Float16* __restrict__ STh, const _Float16* __restrict__ STl,
                          _Float16* __restrict__ Oh, _Float16* __restrict__ Ol,
                          _Float16* __restrict__ OTh, _Float16* __restrict__ OTl) {
    int bt = blockIdx.x;
    int t = bt & (T_ - 1);
    int wave = threadIdx.x >> 6;
    int lane = threadIdx.x & 63;
    int l15 = lane & 15;
    int lk = lane >> 4;
    int n0 = blockIdx.y * 128 + wave * 32;

    f32x4 acc[2];
    #pragma unroll
    for (int j = 0; j < 2; ++j) acc[j] = (f32x4){0.f, 0.f, 0.f, 0.f};

    if (t > 0) {
        const float* A = x + (size_t)(bt - 1) * F0 * N_;
        const _Float16* B_h = STh + (size_t)bt * N_ * N_;
        const _Float16* B_l = STl + (size_t)bt * N_ * N_;
        #pragma unroll
        for (int kk = 0; kk < 8; ++kk) {
            int kof = kk * 32 + lk * 8;
            half8 ah = {}, al = {};
            if (l15 < F0) {
                const float* ar = A + (size_t)l15 * N_ + kof;
                float4 v0 = *(const float4*)(ar);
                float4 v1 = *(const float4*)(ar + 4);
                float vv[8] = {v0.x, v0.y, v0.z, v0.w, v1.x, v1.y, v1.z, v1.w};
                #pragma unroll
                for (int c = 0; c < 8; ++c) {
                    _Float16 hh = (_Float16)vv[c];
                    ah[c] = hh;
                    al[c] = (_Float16)(vv[c] - (float)hh);
                }
            }
            #pragma unroll
            for (int j = 0; j < 2; ++j) {
                half8 bh = *(const half8*)(B_h + (size_t)(n0 + j * 16 + l15) * N_ + kof);
                half8 bl = *(const half8*)(B_l + (size_t)(n0 + j * 16 + l15) * N_ + kof);
                acc[j] = __builtin_amdgcn_mfma_f32_16x16x32_f16(ah, bh, acc[j], 0, 0, 0);
                acc[j] = __builtin_amdgcn_mfma_f32_16x16x32_f16(al, bh, acc[j], 0, 0, 0);
                acc[j] = __builtin_amdgcn_mfma_f32_16x16x32_f16(ah, bl, acc[j], 0, 0, 0);
            }
        }
    }
    _Float16* O_h = Oh + (size_t)bt * 16 * N_;
    _Float16* O_l = Ol + (size_t)bt * 16 * N_;
    #pragma unroll
    for (int j = 0; j < 2; ++j) {
        half4v th, tl;
        #pragma unroll
        for (int r = 0; r < 4; ++r) {
            float v = acc[j][r];
            _Float16 h = (_Float16)v;
            size_t idx = (size_t)(lk * 4 + r) * N_ + n0 + j * 16 + l15;
            O_h[idx] = h;
            O_l[idx] = (_Float16)(v - (float)h);
            th[r] = h;
            tl[r] = (_Float16)(v - (float)h);
        }
        size_t to = ((size_t)bt * N_ + n0 + j * 16 + l15) * 16 + lk * 4;
        *(half4v*)(OTh + to) = th;
        *(half4v*)(OTl + to) = tl;
    }
}

// ---------------- K2: V1(b,t) = U1(b,t-1) @ S(b,t) -> col-major hi/lo -------
__global__ void k_chainV1(const _Float16* __restrict__ Ah, const _Float16* __restrict__ Al,
                          const _Float16* __restrict__ STh, const _Float16* __restrict__ STl,
                          _Float16* __restrict__ OTh, _Float16* __restrict__ OTl) {
    int bt = blockIdx.x;
    int t = bt & (T_ - 1);
    int wave = threadIdx.x >> 6;
    int lane = threadIdx.x & 63;
    int l15 = lane & 15;
    int lk = lane >> 4;
    int n0 = blockIdx.y * 128 + wave * 32;

    f32x4 acc[2];
    #pragma unroll
    for (int j = 0; j < 2; ++j) acc[j] = (f32x4){0.f, 0.f, 0.f, 0.f};

    if (t > 0) {
        const _Float16* A_h = Ah + (size_t)(bt - 1) * 16 * N_;
        const _Float16* A_l = Al + (size_t)(bt - 1) * 16 * N_;
        const _Float16* B_h = STh + (size_t)bt * N_ * N_;
        const _Float16* B_l = STl + (size_t)bt * N_ * N_;
        #pragma unroll
        for (int kk = 0; kk < 8; ++kk) {
            int kof = kk * 32 + lk * 8;
            half8 ah = *(const half8*)(A_h + (size_t)l15 * N_ + kof);
            half8 al = *(const half8*)(A_l + (size_t)l15 * N_ + kof);
            #pragma unroll
            for (int j = 0; j < 2; ++j) {
                half8 bh = *(const half8*)(B_h + (size_t)(n0 + j * 16 + l15) * N_ + kof);
                half8 bl = *(const half8*)(B_l + (size_t)(n0 + j * 16 + l15) * N_ + kof);
                acc[j] = __builtin_amdgcn_mfma_f32_16x16x32_f16(ah, bh, acc[j], 0, 0, 0);
                acc[j] = __builtin_amdgcn_mfma_f32_16x16x32_f16(al, bh, acc[j], 0, 0, 0);
                acc[j] = __builtin_amdgcn_mfma_f32_16x16x32_f16(ah, bl, acc[j], 0, 0, 0);
            }
        }
    }
    #pragma unroll
    for (int j = 0; j < 2; ++j) {
        half4v th, tl;
        #pragma unroll
        for (int r = 0; r < 4; ++r) {
            float v = acc[j][r];
            _Float16 h = (_Float16)v;
            th[r] = h;
            tl[r] = (_Float16)(v - (float)h);
        }
        size_t to = ((size_t)bt * N_ + n0 + j * 16 + l15) * 16 + lk * 4;
        *(half4v*)(OTh + to) = th;
        *(half4v*)(OTl + to) = tl;
    }
}

// ---------------- K3: y1 = tanh(W1cat @ Zcat + b1) -> Y1T hi/lo -------------
// Zcat^T[col] = [xT(16) | U1T(16) | V1T(16) | 0(16)]; W1cat (64x64) in LDS.
__global__ void k_combine1(const _Float16* __restrict__ XTh, const _Float16* __restrict__ XTl,
                           const _Float16* __restrict__ U1Th, const _Float16* __restrict__ U1Tl,
                           const _Float16* __restrict__ V1Th, const _Float16* __restrict__ V1Tl,
                           const float* __restrict__ W1, const float* __restrict__ b1,
                           _Float16* __restrict__ Y1Th, _Float16* __restrict__ Y1Tl) {
    __shared__ _Float16 wh[64 * 72], wl[64 * 72];
    int bt = blockIdx.x;
    int tid = threadIdx.x;
    for (int i = tid; i < 64 * 72; i += 256) {
        int f = i / 72, k = i % 72;
        float v = 0.f;
        if (k < 12) v = W1[f * 36 + k];
        else if (k >= 16 && k < 28) v = W1[f * 36 + 12 + (k - 16)];
        else if (k >= 32 && k < 44) v = W1[f * 36 + 24 + (k - 32)];
        _Float16 hh = (_Float16)v;
        wh[i] = hh;
        wl[i] = (_Float16)(v - (float)hh);
    }
    __syncthreads();

    int wv = tid >> 6, lane = tid & 63, l15 = lane & 15, lk = lane >> 4;
    int n0 = wv * 64;
    f32x4 acc[4][4];
    #pragma unroll
    for (int i = 0; i < 4; ++i)
        #pragma unroll
        for (int j = 0; j < 4; ++j) acc[i][j] = (f32x4){0.f, 0.f, 0.f, 0.f};

    #pragma unroll
    for (int kk = 0; kk < 2; ++kk) {
        half8 bh[4], bl[4];
        #pragma unroll
        for (int j = 0; j < 4; ++j) {
            size_t base16 = ((size_t)bt * N_ + n0 + j * 16 + l15) * 16;
            if (kk == 0) {
                if (lk < 2) {
                    bh[j] = *(const half8*)(XTh + base16 + lk * 8);
                    bl[j] = *(const half8*)(XTl + base16 + lk * 8);
                } else {
                    bh[j] = *(const half8*)(U1Th + base16 + (lk - 2) * 8);
                    bl[j] = *(const half8*)(U1Tl + base16 + (lk - 2) * 8);
                }
            } else {
                if (lk < 2) {
                    bh[j] = *(const half8*)(V1Th + base16 + lk * 8);
                    bl[j] = *(const half8*)(V1Tl + base16 + lk * 8);
                } else {
                    bh[j] = half8{};
                    bl[j] = half8{};
                }
            }
        }
        #pragma unroll
        for (int i = 0; i < 4; ++i) {
            half8 ah = *(const half8*)(wh + (i * 16 + l15) * 72 + kk * 32 + lk * 8);
            half8 al = *(const half8*)(wl + (i * 16 + l15) * 72 + kk * 32 + lk * 8);
            #pragma unroll
            for (int j = 0; j < 4; ++j) {
                acc[i][j] = __builtin_amdgcn_mfma_f32_16x16x32_f16(ah, bh[j], acc[i][j], 0, 0, 0);
                acc[i][j] = __builtin_amdgcn_mfma_f32_16x16x32_f16(al, bh[j], acc[i][j], 0, 0, 0);
                acc[i][j] = __builtin_amdgcn_mfma_f32_16x16x32_f16(ah, bl[j], acc[i][j], 0, 0, 0);
            }
        }
    }
    #pragma unroll
    for (int i = 0; i < 4; ++i) {
        float bb[4];
        #pragma unroll
        for (int r = 0; r < 4; ++r) bb[r] = b1[i * 16 + lk * 4 + r];
        #pragma unroll
        for (int j = 0; j < 4; ++j) {
            half4v th, tl;
            #pragma unroll
            for (int r = 0; r < 4; ++r) {
                float yv = tanh_fast(acc[i][j][r] + bb[r]);
                _Float16 h = (_Float16)yv;
                th[r] = h;
                tl[r] = (_Float16)(yv - (float)h);
            }
            size_t to = ((size_t)bt * N_ + n0 + j * 16 + l15) * 64 + i * 16 + lk * 4;
            *(half4v*)(Y1Th + to) = th;
            *(half4v*)(Y1Tl + to) = tl;
        }
    }
}

// ---------------- K4: projections G=W2v@Y1, H=W2u@Y1, Y2a=W2y@Y1 ------------
__global__ void k_proj(const _Float16* __restrict__ Y1Th, const _Float16* __restrict__ Y1Tl,
                       const float* __restrict__ W2,
                       _Float16* __restrict__ Gh, _Float16* __restrict__ Gl,
                       float* __restrict__ Hf, float* __restrict__ Y2a) {
    __shared__ _Float16 wh[96 * 72], wl[96 * 72];
    int bt = blockIdx.x;
    int tid = threadIdx.x;
    for (int i = tid; i < 96 * 64; i += 256) {
        int r = i >> 6, g = i & 63;
        int f, off;
        if (r < 32)      { f = r;      off = 128; }   // W2v -> G
        else if (r < 64) { f = r - 32; off = 64;  }   // W2u -> H
        else             { f = r - 64; off = 0;   }   // W2y -> Y2a
        float v = W2[f * 192 + off + g];
        _Float16 hh = (_Float16)v;
        wh[r * 72 + g] = hh;
        wl[r * 72 + g] = (_Float16)(v - (float)hh);
    }
    __syncthreads();

    int wv = tid >> 6, lane = tid & 63, l15 = lane & 15, lk = lane >> 4;
    int n0 = wv * 64;
    f32x4 acc[6][4];
    #pragma unroll
    for (int i = 0; i < 6; ++i)
        #pragma unroll
        for (int j = 0; j < 4; ++j) acc[i][j] = (f32x4){0.f, 0.f, 0.f, 0.f};

    const _Float16* Bh = Y1Th + (size_t)bt * N_ * 64;
    const _Float16* Bl = Y1Tl + (size_t)bt * N_ * 64;
    #pragma unroll
    for (int kk = 0; kk < 2; ++kk) {
        int kof = kk * 32 + lk * 8;
        half8 bh[4], bl[4];
        #pragma unroll
        for (int j = 0; j < 4; ++j) {
            bh[j] = *(const half8*)(Bh + (size_t)(n0 + j * 16 + l15) * 64 + kof);
            bl[j] = *(const half8*)(Bl + (size_t)(n0 + j * 16 + l15) * 64 + kof);
        }
        #pragma unroll
        for (int i = 0; i < 6; ++i) {
            half8 ah = *(const half8*)(wh + (i * 16 + l15) * 72 + kof);
            half8 al = *(const half8*)(wl + (i * 16 + l15) * 72 + kof);
            #pragma unroll
            for (int j = 0; j < 4; ++j) {
                acc[i][j] = __builtin_amdgcn_mfma_f32_16x16x32_f16(ah, bh[j], acc[i][j], 0, 0, 0);
                acc[i][j] = __builtin_amdgcn_mfma_f32_16x16x32_f16(al, bh[j], acc[i][j], 0, 0, 0);
                acc[i][j] = __builtin_amdgcn_mfma_f32_16x16x32_f16(ah, bl[j], acc[i][j], 0, 0, 0);
            }
        }
    }
    #pragma unroll
    for (int i = 0; i < 6; ++i)
        #pragma unroll
        for (int j = 0; j < 4; ++j)
            #pragma unroll
            for (int r = 0; r < 4; ++r) {
                int row = i * 16 + lk * 4 + r;   // 0..95
                int col = n0 + j * 16 + l15;
                float v = acc[i][j][r];
                if (row < 32) {
                    _Float16 hh = (_Float16)v;
                    size_t o = ((size_t)bt * 32 + row) * N_ + col;
                    Gh[o] = hh;
                    Gl[o] = (_Float16)(v - (float)hh);
                } else if (row < 64) {
                    Hf[((size_t)bt * 32 + row - 32) * N_ + col] = v;
                } else {
                    Y2a[((size_t)bt * 32 + row - 64) * N_ + col] = v;
                }
            }
}

// ---------------- K5: R(b,t) = H(b,t) + G(b,t-1)@S(b,t), hi/lo out ----------
__global__ void k_chainR(const _Float16* __restrict__ Gh, const _Float16* __restrict__ Gl,
                         const _Float16* __restrict__ STh, const _Float16* __restrict__ STl,
                         const float* __restrict__ Hf,
                         _Float16* __restrict__ Rh, _Float16* __restrict__ Rl) {
    int bt = blockIdx.x;
    int t = bt & (T_ - 1);
    int wave = threadIdx.x >> 6;
    int lane = threadIdx.x & 63;
    int l15 = lane & 15;
    int lk = lane >> 4;
    int n0 = blockIdx.y * 128 + wave * 32;

    f32x4 acc[2][2];
    #pragma unroll
    for (int i = 0; i < 2; ++i)
        #pragma unroll
        for (int j = 0; j < 2; ++j) acc[i][j] = (f32x4){0.f, 0.f, 0.f, 0.f};

    if (t > 0) {
        const _Float16* A_h = Gh + (size_t)(bt - 1) * 32 * N_;
        const _Float16* A_l = Gl + (size_t)(bt - 1) * 32 * N_;
        const _Float16* B_h = STh + (size_t)bt * N_ * N_;
        const _Float16* B_l = STl + (size_t)bt * N_ * N_;
        #pragma unroll
        for (int kk = 0; kk < 8; ++kk) {
            int kof = kk * 32 + lk * 8;
            half8 ah[2], al[2];
            #pragma unroll
            for (int i = 0; i < 2; ++i) {
                ah[i] = *(const half8*)(A_h + (size_t)(i * 16 + l15) * N_ + kof);
                al[i] = *(const half8*)(A_l + (size_t)(i * 16 + l15) * N_ + kof);
            }
            #pragma unroll
            for (int j = 0; j < 2; ++j) {
                half8 bh = *(const half8*)(B_h + (size_t)(n0 + j * 16 + l15) * N_ + kof);
                half8 bl = *(const half8*)(B_l + (size_t)(n0 + j * 16 + l15) * N_ + kof);
                #pragma unroll
                for (int i = 0; i < 2; ++i) {
                    acc[i][j] = __builtin_amdgcn_mfma_f32_16x16x32_f16(ah[i], bh, acc[i][j], 0, 0, 0);
                    acc[i][j] = __builtin_amdgcn_mfma_f32_16x16x32_f16(al[i], bh, acc[i][j], 0, 0, 0);
                    acc[i][j] = __builtin_amdgcn_mfma_f32_16x16x32_f16(ah[i], bl, acc[i][j], 0, 0, 0);
                }
            }
        }
    }
    const float* Hb = Hf + (size_t)bt * 32 * N_;
    _Float16* R_h = Rh + (size_t)bt * 32 * N_;
    _Float16* R_l = Rl + (size_t)bt * 32 * N_;
    #pragma unroll
    for (int i = 0; i < 2; ++i)
        #pragma unroll
        for (int j = 0; j < 2; ++j)
            #pragma unroll
            for (int r = 0; r < 4; ++r) {
                size_t idx = (size_t)(i * 16 + lk * 4 + r) * N_ + n0 + j * 16 + l15;
                float v = acc[i][j][r] + Hb[idx];
                _Float16 h = (_Float16)v;
                R_h[idx] = h;
                R_l[idx] = (_Float16)(v - (float)h);
            }
}

// ---------------- K6: y2 = tanh(b2 + Y2a + R(t-1)@S(t)); readout -> out -----
__global__ void k_chainY2(const _Float16* __restrict__ Rh, const _Float16* __restrict__ Rl,
                          const _Float16* __restrict__ STh, const _Float16* __restrict__ STl,
                          const float* __restrict__ Y2a, const float* __restrict__ b2,
                          const float* __restrict__ A1, const float* __restrict__ c1,
                          const float* __restrict__ A2, const float* __restrict__ c2,
                          float* __restrict__ out) {
    __shared__ float y2s[32 * 133];   // 17 KB, pad 133 -> conflict-free
    __shared__ float la1[32 * 33];
    int bt = blockIdx.x;
    int t = bt & (T_ - 1);
    int tid = threadIdx.x;
    for (int i = tid; i < 32 * 32; i += 256) la1[(i >> 5) * 33 + (i & 31)] = A1[i];

    int wave = tid >> 6;
    int lane = tid & 63;
    int l15 = lane & 15;
    int lk = lane >> 4;
    int n0 = blockIdx.y * 128 + wave * 32;

    f32x4 acc[2][2];
    #pragma unroll
    for (int i = 0; i < 2; ++i)
        #pragma unroll
        for (int j = 0; j < 2; ++j) acc[i][j] = (f32x4){0.f, 0.f, 0.f, 0.f};

    if (t > 0) {
        const _Float16* A_h = Rh + (size_t)(bt - 1) * 32 * N_;
        const _Float16* A_l = Rl + (size_t)(bt - 1) * 32 * N_;
        const _Float16* B_h = STh + (size_t)bt * N_ * N_;
        const _Float16* B_l = STl + (size_t)bt * N_ * N_;
        #pragma unroll
        for (int kk = 0; kk < 8; ++kk) {
            int kof = kk * 32 + lk * 8;
            half8 ah[2], al[2];
            #pragma unroll
            for (int i = 0; i < 2; ++i) {
                ah[i] = *(const half8*)(A_h + (size_t)(i * 16 + l15) * N_ + kof);
                al[i] = *(const half8*)(A_l + (size_t)(i * 16 + l15) * N_ + kof);
            }
            #pragma unroll
            for (int j = 0; j < 2; ++j) {
                half8 bh = *(const half8*)(B_h + (size_t)(n0 + j * 16 + l15) * N_ + kof);
                half8 bl = *(const half8*)(B_l + (size_t)(n0 + j * 16 + l15) * N_ + kof);
                #pragma unroll
                for (int i = 0; i < 2; ++i) {
                    acc[i][j] = __builtin_amdgcn_mfma_f32_16x16x32_f16(ah[i], bh, acc[i][j], 0, 0, 0);
                    acc[i][j] = __builtin_amdgcn_mfma_f32_16x16x32_f16(al[i], bh, acc[i][j], 0, 0, 0);
                    acc[i][j] = __builtin_amdgcn_mfma_f32_16x16x32_f16(ah[i], bl, acc[i][j], 0, 0, 0);
                }
            }
        }
    }
    const float* Ya = Y2a + (size_t)bt * 32 * N_;
    int colb0 = wave * 32;
    #pragma unroll
    for (int i = 0; i < 2; ++i)
        #pragma unroll
        for (int j = 0; j < 2; ++j)
            #pragma unroll
            for (int r = 0; r < 4; ++r) {
                int row = i * 16 + lk * 4 + r;
                int colb = colb0 + j * 16 + l15;
                int n = blockIdx.y * 128 + colb;
                y2s[row * 133 + colb] = acc[i][j][r] + Ya[(size_t)row * N_ + n] + b2[row];
            }
    __syncthreads();

    if (tid < 128) {
        int colb = tid;
        int n = blockIdx.y * 128 + colb;
        float y2v[32];
        #pragma unroll
        for (int f = 0; f < 32; ++f) y2v[f] = tanh_fast(y2s[f * 133 + colb]);
        float o0 = 0.f, o1 = 0.f;
        #pragma unroll
        for (int j = 0; j < 32; ++j) {
            const float* a1r = la1 + j * 33;
            float s = c1[j];
            #pragma unroll
            for (int f = 0; f < 32; ++f) s += a1r[f] * y2v[f];
            float hj = tanh_fast(s);
            o0 += A2[j] * hj;
            o1 += A2[32 + j] * hj;
        }
        out[((size_t)bt * 2 + 0) * N_ + n] = o0 + c2[0];
        out[((size_t)bt * 2 + 1) * N_ + n] = o1 + c2[1];
    }
}

extern "C" void kernel_launch(void* const* d_in, const int* in_sizes, int n_in,
                              void* d_out, int out_size, void* d_ws, size_t ws_size,
                              hipStream_t stream) {
    const float* x  = (const float*)d_in[0];
    const float* S  = (const float*)d_in[1];
    const float* W1 = (const float*)d_in[2];
    const float* b1 = (const float*)d_in[3];
    const float* W2 = (const float*)d_in[4];
    const float* b2 = (const float*)d_in[5];
    const float* A1 = (const float*)d_in[6];
    const float* c1 = (const float*)d_in[7];
    const float* A2 = (const float*)d_in[8];
    const float* c2 = (const float*)d_in[9];
    float* out = (float*)d_out;

    char* ws = (char*)d_ws;
    const size_t SZ_ST  = (size_t)BT_ * N_ * N_ * 2;   // 67,108,864 per plane
    const size_t SZ_Y1T = (size_t)BT_ * N_ * 64 * 2;   // 16,777,216 per plane
    const size_t SZ_G   = (size_t)BT_ * 32 * N_ * 2;   //  8,388,608 per plane
    const size_t SZ_H   = (size_t)BT_ * 32 * N_ * 4;   // 16,777,216 (f32)
    const size_t SZ_T16 = (size_t)BT_ * N_ * 16 * 2;   //  4,194,304 (16-row plane)
    size_t off = 0;
    _Float16* STh  = (_Float16*)(ws + off); off += SZ_ST;
    _Float16* STl  = (_Float16*)(ws + off); off += SZ_ST;
    _Float16* Y1Th = (_Float16*)(ws + off); off += SZ_Y1T;
    _Float16* Y1Tl = (_Float16*)(ws + off); off += SZ_Y1T;
    _Float16* Gh   = (_Float16*)(ws + off); off += SZ_G;
    _Float16* Gl   = (_Float16*)(ws + off); off += SZ_G;
    float*    Hf   = (float*)(ws + off); off += SZ_H;
    float*    Y2a  = (float*)(ws + off); off += SZ_H;
    _Float16* Rh   = (_Float16*)(ws + off); off += SZ_G;
    _Float16* Rl   = (_Float16*)(ws + off); off += SZ_G;
    if (ws_size < off) return;  // insufficient scratch -> clean failure

    // overlays (lifetime-disjoint):
    //   XT  (written K0b, read K3)  lives in Hf  region (Hf written later by k_proj)
    //   U1T (written K1,  read K3)  lives in Y2a region first half
    //   V1T (written K2,  read K3)  lives in Y2a region second half
    //   U1 row-major (written K1, read K2) lives in R region (R written by k_chainR)
    _Float16* XTh  = (_Float16*)Hf;
    _Float16* XTl  = XTh + SZ_T16 / 2;
    _Float16* U1Th = (_Float16*)Y2a;
    _Float16* U1Tl = U1Th + SZ_T16 / 2;
    _Float16* V1Th = U1Tl + SZ_T16 / 2;
    _Float16* V1Tl = V1Th + SZ_T16 / 2;
    _Float16* U1h  = Rh;
    _Float16* U1l  = Rl;

    k_transpose_s<<<dim3(BT_, 4), 512, 0, stream>>>(S, STh, STl);
    k_transpose_x<<<BT_, 256, 0, stream>>>(x, XTh, XTl);
    k_chain1x<<<dim3(BT_, 2), 256, 0, stream>>>(x, STh, STl, U1h, U1l, U1Th, U1Tl);
    k_chainV1<<<dim3(BT_, 2), 256, 0, stream>>>(U1h, U1l, STh, STl, V1Th, V1Tl);
    k_combine1<<<BT_, 256, 0, stream>>>(XTh, XTl, U1Th, U1Tl, V1Th, V1Tl, W1, b1, Y1Th, Y1Tl);
    k_proj<<<BT_, 256, 0, stream>>>(Y1Th, Y1Tl, W2, Gh, Gl, Hf, Y2a);
    k_chainR<<<dim3(BT_, 2), 256, 0, stream>>>(Gh, Gl, STh, STl, Hf, Rh, Rl);
    k_chainY2<<<dim3(BT_, 2), 256, 0, stream>>>(Rh, Rl, STh, STl, Y2a, b2,
                                                A1, c1, A2, c2, out);
}

// Round 12
// 228.917 us; speedup vs baseline: 2.7605x; 1.0805x over previous
//
#include <hip/hip_runtime.h>
#include <hip/hip_fp16.h>

typedef _Float16 half8 __attribute__((ext_vector_type(8)));
typedef _Float16 half4v __attribute__((ext_vector_type(4)));
typedef float f32x4 __attribute__((ext_vector_type(4)));

static constexpr int B_ = 8, T_ = 64, N_ = 256;
static constexpr int F0 = 12, F1 = 64, F2 = 32;
static constexpr int BT_ = B_ * T_;

__device__ inline float tanh_fast(float x) {
    x = fminf(20.f, fmaxf(-20.f, x));
    float e = __expf(2.f * x);
    return (e - 1.f) / (e + 1.f);
}

// ---------------- K0: fused S-transpose + U1 = x(t-1)@S(t) ------------------
// grid (BT,4): block owns 64 output rows (n = S columns), 2 m-tiles of 128.
// Per m-tile: load S[m0:+128][n0:+64] (non-temporal) -> LDS [n][m] stride 129;
// store hi/lo fp16 ST chunks (128B-contiguous); build B-fragments from LDS
// (2-way banks, free) and accumulate U1's 16x16 fragment per wave.
__global__ __launch_bounds__(256) void k_transpose_u1(
    const float* __restrict__ S, const float* __restrict__ x,
    _Float16* __restrict__ STh, _Float16* __restrict__ STl,
    _Float16* __restrict__ U1h, _Float16* __restrict__ U1l,
    _Float16* __restrict__ U1Th, _Float16* __restrict__ U1Tl) {
    __shared__ float tile[64][129];   // 33 KB
    int bt = blockIdx.x;
    int t  = bt & (T_ - 1);
    int n0 = blockIdx.y * 64;
    const float* s = S + (size_t)bt * N_ * N_;
    _Float16* sth = STh + (size_t)bt * N_ * N_;
    _Float16* stl = STl + (size_t)bt * N_ * N_;
    int tid = threadIdx.x;
    int q  = tid & 15, r0  = tid >> 4;   // load mapping
    int q2 = tid & 7,  nr0 = tid >> 3;   // ST-store mapping
    int lane = tid & 63, wv = tid >> 6;  // MFMA mapping
    int l15 = lane & 15, lk = lane >> 4;
    const float* A = x + (size_t)(bt - 1) * F0 * N_;  // valid only when t>0
    f32x4 acc = (f32x4){0.f, 0.f, 0.f, 0.f};

    for (int m0 = 0; m0 < N_; m0 += 128) {
        #pragma unroll
        for (int rr = r0; rr < 128; rr += 16) {
            f32x4 v = __builtin_nontemporal_load(
                (const f32x4*)(s + (size_t)(m0 + rr) * N_ + n0 + q * 4));
            tile[q * 4 + 0][rr] = v[0];
            tile[q * 4 + 1][rr] = v[1];
            tile[q * 4 + 2][rr] = v[2];
            tile[q * 4 + 3][rr] = v[3];
        }
        __syncthreads();
        // ST store phase
        #pragma unroll
        for (int nn = nr0; nn < 64; nn += 32) {
            #pragma unroll
            for (int ci = 0; ci < 2; ++ci) {
                int mc = ci * 8 + q2;
                half8 h, l;
                #pragma unroll
                for (int e = 0; e < 8; ++e) {
                    float v = tile[nn][mc * 8 + e];
                    _Float16 hh = (_Float16)v;
                    h[e] = hh;
                    l[e] = (_Float16)(v - (float)hh);
                }
                size_t o = (size_t)(n0 + nn) * N_ + m0 + mc * 8;
                *(half8*)(sth + o) = h;
                *(half8*)(stl + o) = l;
            }
        }
        // MFMA phase: accumulate U1 fragment for this m-range
        if (t > 0) {
            #pragma unroll
            for (int kkl = 0; kkl < 4; ++kkl) {
                int ml = kkl * 32 + lk * 8;
                half8 ah = {}, al = {};
                if (l15 < F0) {
                    const float* ar = A + (size_t)l15 * N_ + m0 + ml;
                    float4 v0 = *(const float4*)(ar);
                    float4 v1 = *(const float4*)(ar + 4);
                    float vv[8] = {v0.x, v0.y, v0.z, v0.w, v1.x, v1.y, v1.z, v1.w};
                    #pragma unroll
                    for (int c = 0; c < 8; ++c) {
                        _Float16 hh = (_Float16)vv[c];
                        ah[c] = hh;
                        al[c] = (_Float16)(vv[c] - (float)hh);
                    }
                }
                half8 bh, bl;
                const float* tr = &tile[wv * 16 + l15][ml];
                #pragma unroll
                for (int e = 0; e < 8; ++e) {
                    float v = tr[e];
                    _Float16 hh = (_Float16)v;
                    bh[e] = hh;
                    bl[e] = (_Float16)(v - (float)hh);
                }
                acc = __builtin_amdgcn_mfma_f32_16x16x32_f16(ah, bh, acc, 0, 0, 0);
                acc = __builtin_amdgcn_mfma_f32_16x16x32_f16(al, bh, acc, 0, 0, 0);
                acc = __builtin_amdgcn_mfma_f32_16x16x32_f16(ah, bl, acc, 0, 0, 0);
            }
        }
        __syncthreads();
    }
    // U1 writes (zeros when t==0): row-major + col-major hi/lo
    {
        int n = n0 + wv * 16 + l15;
        _Float16* O_h = U1h + (size_t)bt * 16 * N_;
        _Float16* O_l = U1l + (size_t)bt * 16 * N_;
        half4v th, tl;
        #pragma unroll
        for (int r = 0; r < 4; ++r) {
            float v = acc[r];
            _Float16 h = (_Float16)v;
            _Float16 lo = (_Float16)(v - (float)h);
            O_h[(size_t)(lk * 4 + r) * N_ + n] = h;
            O_l[(size_t)(lk * 4 + r) * N_ + n] = lo;
            th[r] = h;
            tl[r] = lo;
        }
        size_t to = ((size_t)bt * N_ + n) * 16 + lk * 4;
        *(half4v*)(U1Th + to) = th;
        *(half4v*)(U1Tl + to) = tl;
    }
}

// ---------------- K0b: x -> xT[bt][n][16] hi/lo (rows 12..15 zero) ----------
__global__ void k_transpose_x(const float* __restrict__ x,
                              _Float16* __restrict__ XTh, _Float16* __restrict__ XTl) {
    int bt = blockIdx.x;
    int n = threadIdx.x;
    const float* xc = x + (size_t)bt * F0 * N_;
    half8 hb[2] = {}, lb[2] = {};
    #pragma unroll
    for (int g = 0; g < F0; ++g) {
        float v = xc[(size_t)g * N_ + n];
        _Float16 hh = (_Float16)v;
        hb[g >> 3][g & 7] = hh;
        lb[g >> 3][g & 7] = (_Float16)(v - (float)hh);
    }
    size_t o = ((size_t)bt * N_ + n) * 16;
    *(half8*)(XTh + o) = hb[0];
    *(half8*)(XTh + o + 8) = hb[1];
    *(half8*)(XTl + o) = lb[0];
    *(half8*)(XTl + o + 8) = lb[1];
}

// ---------------- K2: V1(b,t) = U1(b,t-1) @ S(b,t) -> col-major hi/lo -------
__global__ void k_chainV1(const _Float16* __restrict__ Ah, const _Float16* __restrict__ Al,
                          const _Float16* __restrict__ STh, const _Float16* __restrict__ STl,
                          _Float16* __restrict__ OTh, _Float16* __restrict__ OTl) {
    int bt = blockIdx.x;
    int t = bt & (T_ - 1);
    int wave = threadIdx.x >> 6;
    int lane = threadIdx.x & 63;
    int l15 = lane & 15;
    int lk = lane >> 4;
    int n0 = blockIdx.y * 128 + wave * 32;

    f32x4 acc[2];
    #pragma unroll
    for (int j = 0; j < 2; ++j) acc[j] = (f32x4){0.f, 0.f, 0.f, 0.f};

    if (t > 0) {
        const _Float16* A_h = Ah + (size_t)(bt - 1) * 16 * N_;
        const _Float16* A_l = Al + (size_t)(bt - 1) * 16 * N_;
        const _Float16* B_h = STh + (size_t)bt * N_ * N_;
        const _Float16* B_l = STl + (size_t)bt * N_ * N_;
        #pragma unroll
        for (int kk = 0; kk < 8; ++kk) {
            int kof = kk * 32 + lk * 8;
            half8 ah = *(const half8*)(A_h + (size_t)l15 * N_ + kof);
            half8 al = *(const half8*)(A_l + (size_t)l15 * N_ + kof);
            #pragma unroll
            for (int j = 0; j < 2; ++j) {
                half8 bh = *(const half8*)(B_h + (size_t)(n0 + j * 16 + l15) * N_ + kof);
                half8 bl = *(const half8*)(B_l + (size_t)(n0 + j * 16 + l15) * N_ + kof);
                acc[j] = __builtin_amdgcn_mfma_f32_16x16x32_f16(ah, bh, acc[j], 0, 0, 0);
                acc[j] = __builtin_amdgcn_mfma_f32_16x16x32_f16(al, bh, acc[j], 0, 0, 0);
                acc[j] = __builtin_amdgcn_mfma_f32_16x16x32_f16(ah, bl, acc[j], 0, 0, 0);
            }
        }
    }
    #pragma unroll
    for (int j = 0; j < 2; ++j) {
        half4v th, tl;
        #pragma unroll
        for (int r = 0; r < 4; ++r) {
            float v = acc[j][r];
            _Float16 h = (_Float16)v;
            th[r] = h;
            tl[r] = (_Float16)(v - (float)h);
        }
        size_t to = ((size_t)bt * N_ + n0 + j * 16 + l15) * 16 + lk * 4;
        *(half4v*)(OTh + to) = th;
        *(half4v*)(OTl + to) = tl;
    }
}

// ---------------- K3: y1 = tanh(W1cat @ Zcat + b1) -> Y1T hi/lo -------------
__global__ void k_combine1(const _Float16* __restrict__ XTh, const _Float16* __restrict__ XTl,
                           const _Float16* __restrict__ U1Th, const _Float16* __restrict__ U1Tl,
                           const _Float16* __restrict__ V1Th, const _Float16* __restrict__ V1Tl,
                           const float* __restrict__ W1, const float* __restrict__ b1,
                           _Float16* __restrict__ Y1Th, _Float16* __restrict__ Y1Tl) {
    __shared__ _Float16 wh[64 * 72], wl[64 * 72];
    int bt = blockIdx.x;
    int tid = threadIdx.x;
    for (int i = tid; i < 64 * 72; i += 256) {
        int f = i / 72, k = i % 72;
        float v = 0.f;
        if (k < 12) v = W1[f * 36 + k];
        else if (k >= 16 && k < 28) v = W1[f * 36 + 12 + (k - 16)];
        else if (k >= 32 && k < 44) v = W1[f * 36 + 24 + (k - 32)];
        _Float16 hh = (_Float16)v;
        wh[i] = hh;
        wl[i] = (_Float16)(v - (float)hh);
    }
    __syncthreads();

    int wv = tid >> 6, lane = tid & 63, l15 = lane & 15, lk = lane >> 4;
    int n0 = wv * 64;
    f32x4 acc[4][4];
    #pragma unroll
    for (int i = 0; i < 4; ++i)
        #pragma unroll
        for (int j = 0; j < 4; ++j) acc[i][j] = (f32x4){0.f, 0.f, 0.f, 0.f};

    #pragma unroll
    for (int kk = 0; kk < 2; ++kk) {
        half8 bh[4], bl[4];
        #pragma unroll
        for (int j = 0; j < 4; ++j) {
            size_t base16 = ((size_t)bt * N_ + n0 + j * 16 + l15) * 16;
            if (kk == 0) {
                if (lk < 2) {
                    bh[j] = *(const half8*)(XTh + base16 + lk * 8);
                    bl[j] = *(const half8*)(XTl + base16 + lk * 8);
                } else {
                    bh[j] = *(const half8*)(U1Th + base16 + (lk - 2) * 8);
                    bl[j] = *(const half8*)(U1Tl + base16 + (lk - 2) * 8);
                }
            } else {
                if (lk < 2) {
                    bh[j] = *(const half8*)(V1Th + base16 + lk * 8);
                    bl[j] = *(const half8*)(V1Tl + base16 + lk * 8);
                } else {
                    bh[j] = half8{};
                    bl[j] = half8{};
                }
            }
        }
        #pragma unroll
        for (int i = 0; i < 4; ++i) {
            half8 ah = *(const half8*)(wh + (i * 16 + l15) * 72 + kk * 32 + lk * 8);
            half8 al = *(const half8*)(wl + (i * 16 + l15) * 72 + kk * 32 + lk * 8);
            #pragma unroll
            for (int j = 0; j < 4; ++j) {
                acc[i][j] = __builtin_amdgcn_mfma_f32_16x16x32_f16(ah, bh[j], acc[i][j], 0, 0, 0);
                acc[i][j] = __builtin_amdgcn_mfma_f32_16x16x32_f16(al, bh[j], acc[i][j], 0, 0, 0);
                acc[i][j] = __builtin_amdgcn_mfma_f32_16x16x32_f16(ah, bl[j], acc[i][j], 0, 0, 0);
            }
        }
    }
    #pragma unroll
    for (int i = 0; i < 4; ++i) {
        float bb[4];
        #pragma unroll
        for (int r = 0; r < 4; ++r) bb[r] = b1[i * 16 + lk * 4 + r];
        #pragma unroll
        for (int j = 0; j < 4; ++j) {
            half4v th, tl;
            #pragma unroll
            for (int r = 0; r < 4; ++r) {
                float yv = tanh_fast(acc[i][j][r] + bb[r]);
                _Float16 h = (_Float16)yv;
                th[r] = h;
                tl[r] = (_Float16)(yv - (float)h);
            }
            size_t to = ((size_t)bt * N_ + n0 + j * 16 + l15) * 64 + i * 16 + lk * 4;
            *(half4v*)(Y1Th + to) = th;
            *(half4v*)(Y1Tl + to) = tl;
        }
    }
}

// ---------------- K4: projections G=W2v@Y1, H=W2u@Y1, Y2a=W2y@Y1 ------------
__global__ void k_proj(const _Float16* __restrict__ Y1Th, const _Float16* __restrict__ Y1Tl,
                       const float* __restrict__ W2,
                       _Float16* __restrict__ Gh, _Float16* __restrict__ Gl,
                       float* __restrict__ Hf, float* __restrict__ Y2a) {
    __shared__ _Float16 wh[96 * 72], wl[96 * 72];
    int bt = blockIdx.x;
    int tid = threadIdx.x;
    for (int i = tid; i < 96 * 64; i += 256) {
        int r = i >> 6, g = i & 63;
        int f, off;
        if (r < 32)      { f = r;      off = 128; }   // W2v -> G
        else if (r < 64) { f = r - 32; off = 64;  }   // W2u -> H
        else             { f = r - 64; off = 0;   }   // W2y -> Y2a
        float v = W2[f * 192 + off + g];
        _Float16 hh = (_Float16)v;
        wh[r * 72 + g] = hh;
        wl[r * 72 + g] = (_Float16)(v - (float)hh);
    }
    __syncthreads();

    int wv = tid >> 6, lane = tid & 63, l15 = lane & 15, lk = lane >> 4;
    int n0 = wv * 64;
    f32x4 acc[6][4];
    #pragma unroll
    for (int i = 0; i < 6; ++i)
        #pragma unroll
        for (int j = 0; j < 4; ++j) acc[i][j] = (f32x4){0.f, 0.f, 0.f, 0.f};

    const _Float16* Bh = Y1Th + (size_t)bt * N_ * 64;
    const _Float16* Bl = Y1Tl + (size_t)bt * N_ * 64;
    #pragma unroll
    for (int kk = 0; kk < 2; ++kk) {
        int kof = kk * 32 + lk * 8;
        half8 bh[4], bl[4];
        #pragma unroll
        for (int j = 0; j < 4; ++j) {
            bh[j] = *(const half8*)(Bh + (size_t)(n0 + j * 16 + l15) * 64 + kof);
            bl[j] = *(const half8*)(Bl + (size_t)(n0 + j * 16 + l15) * 64 + kof);
        }
        #pragma unroll
        for (int i = 0; i < 6; ++i) {
            half8 ah = *(const half8*)(wh + (i * 16 + l15) * 72 + kof);
            half8 al = *(const half8*)(wl + (i * 16 + l15) * 72 + kof);
            #pragma unroll
            for (int j = 0; j < 4; ++j) {
                acc[i][j] = __builtin_amdgcn_mfma_f32_16x16x32_f16(ah, bh[j], acc[i][j], 0, 0, 0);
                acc[i][j] = __builtin_amdgcn_mfma_f32_16x16x32_f16(al, bh[j], acc[i][j], 0, 0, 0);
                acc[i][j] = __builtin_amdgcn_mfma_f32_16x16x32_f16(ah, bl[j], acc[i][j], 0, 0, 0);
            }
        }
    }
    #pragma unroll
    for (int i = 0; i < 6; ++i)
        #pragma unroll
        for (int j = 0; j < 4; ++j)
            #pragma unroll
            for (int r = 0; r < 4; ++r) {
                int row = i * 16 + lk * 4 + r;   // 0..95
                int col = n0 + j * 16 + l15;
                float v = acc[i][j][r];
                if (row < 32) {
                    _Float16 hh = (_Float16)v;
                    size_t o = ((size_t)bt * 32 + row) * N_ + col;
                    Gh[o] = hh;
                    Gl[o] = (_Float16)(v - (float)hh);
                } else if (row < 64) {
                    Hf[((size_t)bt * 32 + row - 32) * N_ + col] = v;
                } else {
                    Y2a[((size_t)bt * 32 + row - 64) * N_ + col] = v;
                }
            }
}

// ---------------- K5: R(b,t) = H(b,t) + G(b,t-1)@S(b,t), hi/lo out ----------
__global__ void k_chainR(const _Float16* __restrict__ Gh, const _Float16* __restrict__ Gl,
                         const _Float16* __restrict__ STh, const _Float16* __restrict__ STl,
                         const float* __restrict__ Hf,
                         _Float16* __restrict__ Rh, _Float16* __restrict__ Rl) {
    int bt = blockIdx.x;
    int t = bt & (T_ - 1);
    int wave = threadIdx.x >> 6;
    int lane = threadIdx.x & 63;
    int l15 = lane & 15;
    int lk = lane >> 4;
    int n0 = blockIdx.y * 128 + wave * 32;

    f32x4 acc[2][2];
    #pragma unroll
    for (int i = 0; i < 2; ++i)
        #pragma unroll
        for (int j = 0; j < 2; ++j) acc[i][j] = (f32x4){0.f, 0.f, 0.f, 0.f};

    if (t > 0) {
        const _Float16* A_h = Gh + (size_t)(bt - 1) * 32 * N_;
        const _Float16* A_l = Gl + (size_t)(bt - 1) * 32 * N_;
        const _Float16* B_h = STh + (size_t)bt * N_ * N_;
        const _Float16* B_l = STl + (size_t)bt * N_ * N_;
        #pragma unroll
        for (int kk = 0; kk < 8; ++kk) {
            int kof = kk * 32 + lk * 8;
            half8 ah[2], al[2];
            #pragma unroll
            for (int i = 0; i < 2; ++i) {
                ah[i] = *(const half8*)(A_h + (size_t)(i * 16 + l15) * N_ + kof);
                al[i] = *(const half8*)(A_l + (size_t)(i * 16 + l15) * N_ + kof);
            }
            #pragma unroll
            for (int j = 0; j < 2; ++j) {
                half8 bh = *(const half8*)(B_h + (size_t)(n0 + j * 16 + l15) * N_ + kof);
                half8 bl = *(const half8*)(B_l + (size_t)(n0 + j * 16 + l15) * N_ + kof);
                #pragma unroll
                for (int i = 0; i < 2; ++i) {
                    acc[i][j] = __builtin_amdgcn_mfma_f32_16x16x32_f16(ah[i], bh, acc[i][j], 0, 0, 0);
                    acc[i][j] = __builtin_amdgcn_mfma_f32_16x16x32_f16(al[i], bh, acc[i][j], 0, 0, 0);
                    acc[i][j] = __builtin_amdgcn_mfma_f32_16x16x32_f16(ah[i], bl, acc[i][j], 0, 0, 0);
                }
            }
        }
    }
    const float* Hb = Hf + (size_t)bt * 32 * N_;
    _Float16* R_h = Rh + (size_t)bt * 32 * N_;
    _Float16* R_l = Rl + (size_t)bt * 32 * N_;
    #pragma unroll
    for (int i = 0; i < 2; ++i)
        #pragma unroll
        for (int j = 0; j < 2; ++j)
            #pragma unroll
            for (int r = 0; r < 4; ++r) {
                size_t idx = (size_t)(i * 16 + lk * 4 + r) * N_ + n0 + j * 16 + l15;
                float v = acc[i][j][r] + Hb[idx];
                _Float16 h = (_Float16)v;
                R_h[idx] = h;
                R_l[idx] = (_Float16)(v - (float)h);
            }
}

// ---------------- K6: y2 = tanh(b2 + Y2a + R(t-1)@S(t)); readout -> out -----
__global__ void k_chainY2(const _Float16* __restrict__ Rh, const _Float16* __restrict__ Rl,
                          const _Float16* __restrict__ STh, const _Float16* __restrict__ STl,
                          const float* __restrict__ Y2a, const float* __restrict__ b2,
                          const float* __restrict__ A1, const float* __restrict__ c1,
                          const float* __restrict__ A2, const float* __restrict__ c2,
                          float* __restrict__ out) {
    __shared__ float y2s[32 * 133];   // 17 KB, pad 133 -> conflict-free
    __shared__ float la1[32 * 33];
    int bt = blockIdx.x;
    int t = bt & (T_ - 1);
    int tid = threadIdx.x;
    for (int i = tid; i < 32 * 32; i += 256) la1[(i >> 5) * 33 + (i & 31)] = A1[i];

    int wave = tid >> 6;
    int lane = tid & 63;
    int l15 = lane & 15;
    int lk = lane >> 4;
    int n0 = blockIdx.y * 128 + wave * 32;

    f32x4 acc[2][2];
    #pragma unroll
    for (int i = 0; i < 2; ++i)
        #pragma unroll
        for (int j = 0; j < 2; ++j) acc[i][j] = (f32x4){0.f, 0.f, 0.f, 0.f};

    if (t > 0) {
        const _Float16* A_h = Rh + (size_t)(bt - 1) * 32 * N_;
        const _Float16* A_l = Rl + (size_t)(bt - 1) * 32 * N_;
        const _Float16* B_h = STh + (size_t)bt * N_ * N_;
        const _Float16* B_l = STl + (size_t)bt * N_ * N_;
        #pragma unroll
        for (int kk = 0; kk < 8; ++kk) {
            int kof = kk * 32 + lk * 8;
            half8 ah[2], al[2];
            #pragma unroll
            for (int i = 0; i < 2; ++i) {
                ah[i] = *(const half8*)(A_h + (size_t)(i * 16 + l15) * N_ + kof);
                al[i] = *(const half8*)(A_l + (size_t)(i * 16 + l15) * N_ + kof);
            }
            #pragma unroll
            for (int j = 0; j < 2; ++j) {
                half8 bh = *(const half8*)(B_h + (size_t)(n0 + j * 16 + l15) * N_ + kof);
                half8 bl = *(const half8*)(B_l + (size_t)(n0 + j * 16 + l15) * N_ + kof);
                #pragma unroll
                for (int i = 0; i < 2; ++i) {
                    acc[i][j] = __builtin_amdgcn_mfma_f32_16x16x32_f16(ah[i], bh, acc[i][j], 0, 0, 0);
                    acc[i][j] = __builtin_amdgcn_mfma_f32_16x16x32_f16(al[i], bh, acc[i][j], 0, 0, 0);
                    acc[i][j] = __builtin_amdgcn_mfma_f32_16x16x32_f16(ah[i], bl, acc[i][j], 0, 0, 0);
                }
            }
        }
    }
    const float* Ya = Y2a + (size_t)bt * 32 * N_;
    int colb0 = wave * 32;
    #pragma unroll
    for (int i = 0; i < 2; ++i)
        #pragma unroll
        for (int j = 0; j < 2; ++j)
            #pragma unroll
            for (int r = 0; r < 4; ++r) {
                int row = i * 16 + lk * 4 + r;
                int colb = colb0 + j * 16 + l15;
                int n = blockIdx.y * 128 + colb;
                y2s[row * 133 + colb] = acc[i][j][r] + Ya[(size_t)row * N_ + n] + b2[row];
            }
    __syncthreads();

    if (tid < 128) {
        int colb = tid;
        int n = blockIdx.y * 128 + colb;
        float y2v[32];
        #pragma unroll
        for (int f = 0; f < 32; ++f) y2v[f] = tanh_fast(y2s[f * 133 + colb]);
        float o0 = 0.f, o1 = 0.f;
        #pragma unroll
        for (int j = 0; j < 32; ++j) {
            const float* a1r = la1 + j * 33;
            float s = c1[j];
            #pragma unroll
            for (int f = 0; f < 32; ++f) s += a1r[f] * y2v[f];
            float hj = tanh_fast(s);
            o0 += A2[j] * hj;
            o1 += A2[32 + j] * hj;
        }
        out[((size_t)bt * 2 + 0) * N_ + n] = o0 + c2[0];
        out[((size_t)bt * 2 + 1) * N_ + n] = o1 + c2[1];
    }
}

extern "C" void kernel_launch(void* const* d_in, const int* in_sizes, int n_in,
                              void* d_out, int out_size, void* d_ws, size_t ws_size,
                              hipStream_t stream) {
    const float* x  = (const float*)d_in[0];
    const float* S  = (const float*)d_in[1];
    const float* W1 = (const float*)d_in[2];
    const float* b1 = (const float*)d_in[3];
    const float* W2 = (const float*)d_in[4];
    const float* b2 = (const float*)d_in[5];
    const float* A1 = (const float*)d_in[6];
    const float* c1 = (const float*)d_in[7];
    const float* A2 = (const float*)d_in[8];
    const float* c2 = (const float*)d_in[9];
    float* out = (float*)d_out;

    char* ws = (char*)d_ws;
    const size_t SZ_ST  = (size_t)BT_ * N_ * N_ * 2;   // 67,108,864 per plane
    const size_t SZ_Y1T = (size_t)BT_ * N_ * 64 * 2;   // 16,777,216 per plane
    const size_t SZ_G   = (size_t)BT_ * 32 * N_ * 2;   //  8,388,608 per plane
    const size_t SZ_H   = (size_t)BT_ * 32 * N_ * 4;   // 16,777,216 (f32)
    const size_t SZ_T16 = (size_t)BT_ * N_ * 16 * 2;   //  4,194,304 (16-row plane)
    size_t off = 0;
    _Float16* STh  = (_Float16*)(ws + off); off += SZ_ST;
    _Float16* STl  = (_Float16*)(ws + off); off += SZ_ST;
    _Float16* Y1Th = (_Float16*)(ws + off); off += SZ_Y1T;
    _Float16* Y1Tl = (_Float16*)(ws + off); off += SZ_Y1T;
    _Float16* Gh   = (_Float16*)(ws + off); off += SZ_G;
    _Float16* Gl   = (_Float16*)(ws + off); off += SZ_G;
    float*    Hf   = (float*)(ws + off); off += SZ_H;
    float*    Y2a  = (float*)(ws + off); off += SZ_H;
    _Float16* Rh   = (_Float16*)(ws + off); off += SZ_G;
    _Float16* Rl   = (_Float16*)(ws + off); off += SZ_G;
    if (ws_size < off) return;  // insufficient scratch -> clean failure

    // overlays (lifetime-disjoint):
    //   XT  (written K0b, read K3)  lives in Hf  region (Hf written later by k_proj)
    //   U1T (written K0,  read K3)  lives in Y2a region first half
    //   V1T (written K2,  read K3)  lives in Y2a region second half
    //   U1 row-major (written K0, read K2) lives in R region (R written by k_chainR)
    _Float16* XTh  = (_Float16*)Hf;
    _Float16* XTl  = XTh + SZ_T16 / 2;
    _Float16* U1Th = (_Float16*)Y2a;
    _Float16* U1Tl = U1Th + SZ_T16 / 2;
    _Float16* V1Th = U1Tl + SZ_T16 / 2;
    _Float16* V1Tl = V1Th + SZ_T16 / 2;
    _Float16* U1h  = Rh;
    _Float16* U1l  = Rl;

    k_transpose_u1<<<dim3(BT_, 4), 256, 0, stream>>>(S, x, STh, STl,
                                                     U1h, U1l, U1Th, U1Tl);
    k_transpose_x<<<BT_, 256, 0, stream>>>(x, XTh, XTl);
    k_chainV1<<<dim3(BT_, 2), 256, 0, stream>>>(U1h, U1l, STh, STl, V1Th, V1Tl);
    k_combine1<<<BT_, 256, 0, stream>>>(XTh, XTl, U1Th, U1Tl, V1Th, V1Tl, W1, b1, Y1Th, Y1Tl);
    k_proj<<<BT_, 256, 0, stream>>>(Y1Th, Y1Tl, W2, Gh, Gl, Hf, Y2a);
    k_chainR<<<dim3(BT_, 2), 256, 0, stream>>>(Gh, Gl, STh, STl, Hf, Rh, Rl);
    k_chainY2<<<dim3(BT_, 2), 256, 0, stream>>>(Rh, Rl, STh, STl, Y2a, b2,
                                                A1, c1, A2, c2, out);
}

// Round 14
// 223.166 us; speedup vs baseline: 2.8316x; 1.0258x over previous
//
#include <hip/hip_runtime.h>
#include <hip/hip_fp16.h>

typedef _Float16 half8 __attribute__((ext_vector_type(8)));
typedef _Float16 half4v __attribute__((ext_vector_type(4)));
typedef float f32x4 __attribute__((ext_vector_type(4)));

static constexpr int B_ = 8, T_ = 64, N_ = 256;
static constexpr int F0 = 12, F1 = 64, F2 = 32;
static constexpr int BT_ = B_ * T_;

__device__ inline float tanh_fast(float x) {
    x = fminf(20.f, fmaxf(-20.f, x));
    float e = __expf(2.f * x);
    return (e - 1.f) / (e + 1.f);
}

// ---------------- K0: fused S-transpose + U1 = x(t-1)@S(t) ------------------
// grid (BT,4): block owns 64 output rows (n = S columns), 2 m-tiles of 128.
// Register-staged NT loads (8 deep). [BISECT: only change vs R12]
__global__ __launch_bounds__(256) void k_transpose_u1(
    const float* __restrict__ S, const float* __restrict__ x,
    _Float16* __restrict__ STh, _Float16* __restrict__ STl,
    _Float16* __restrict__ U1h, _Float16* __restrict__ U1l,
    _Float16* __restrict__ U1Th, _Float16* __restrict__ U1Tl) {
    __shared__ float tile[64][129];   // 33 KB
    int bt = blockIdx.x;
    int t  = bt & (T_ - 1);
    int n0 = blockIdx.y * 64;
    const float* s = S + (size_t)bt * N_ * N_;
    _Float16* sth = STh + (size_t)bt * N_ * N_;
    _Float16* stl = STl + (size_t)bt * N_ * N_;
    int tid = threadIdx.x;
    int q  = tid & 15, r0  = tid >> 4;   // load mapping
    int q2 = tid & 7,  nr0 = tid >> 3;   // ST-store mapping
    int lane = tid & 63, wv = tid >> 6;  // MFMA mapping
    int l15 = lane & 15, lk = lane >> 4;
    const float* A = x + (size_t)(bt - 1) * F0 * N_;  // valid only when t>0
    f32x4 acc = (f32x4){0.f, 0.f, 0.f, 0.f};

    for (int m0 = 0; m0 < N_; m0 += 128) {
        // register-staged load: all 8 NT loads issued before any LDS write
        f32x4 vbuf[8];
        #pragma unroll
        for (int ii = 0; ii < 8; ++ii) {
            int rr = r0 + ii * 16;
            vbuf[ii] = __builtin_nontemporal_load(
                (const f32x4*)(s + (size_t)(m0 + rr) * N_ + n0 + q * 4));
        }
        #pragma unroll
        for (int ii = 0; ii < 8; ++ii) {
            int rr = r0 + ii * 16;
            tile[q * 4 + 0][rr] = vbuf[ii][0];
            tile[q * 4 + 1][rr] = vbuf[ii][1];
            tile[q * 4 + 2][rr] = vbuf[ii][2];
            tile[q * 4 + 3][rr] = vbuf[ii][3];
        }
        __syncthreads();
        // ST store phase
        #pragma unroll
        for (int nn = nr0; nn < 64; nn += 32) {
            #pragma unroll
            for (int ci = 0; ci < 2; ++ci) {
                int mc = ci * 8 + q2;
                half8 h, l;
                #pragma unroll
                for (int e = 0; e < 8; ++e) {
                    float v = tile[nn][mc * 8 + e];
                    _Float16 hh = (_Float16)v;
                    h[e] = hh;
                    l[e] = (_Float16)(v - (float)hh);
                }
                size_t o = (size_t)(n0 + nn) * N_ + m0 + mc * 8;
                *(half8*)(sth + o) = h;
                *(half8*)(stl + o) = l;
            }
        }
        // MFMA phase: accumulate U1 fragment for this m-range
        if (t > 0) {
            #pragma unroll
            for (int kkl = 0; kkl < 4; ++kkl) {
                int ml = kkl * 32 + lk * 8;
                half8 ah = {}, al = {};
                if (l15 < F0) {
                    const float* ar = A + (size_t)l15 * N_ + m0 + ml;
                    float4 v0 = *(const float4*)(ar);
                    float4 v1 = *(const float4*)(ar + 4);
                    float vv[8] = {v0.x, v0.y, v0.z, v0.w, v1.x, v1.y, v1.z, v1.w};
                    #pragma unroll
                    for (int c = 0; c < 8; ++c) {
                        _Float16 hh = (_Float16)vv[c];
                        ah[c] = hh;
                        al[c] = (_Float16)(vv[c] - (float)hh);
                    }
                }
                half8 bh, bl;
                const float* tr = &tile[wv * 16 + l15][ml];
                #pragma unroll
                for (int e = 0; e < 8; ++e) {
                    float v = tr[e];
                    _Float16 hh = (_Float16)v;
                    bh[e] = hh;
                    bl[e] = (_Float16)(v - (float)hh);
                }
                acc = __builtin_amdgcn_mfma_f32_16x16x32_f16(ah, bh, acc, 0, 0, 0);
                acc = __builtin_amdgcn_mfma_f32_16x16x32_f16(al, bh, acc, 0, 0, 0);
                acc = __builtin_amdgcn_mfma_f32_16x16x32_f16(ah, bl, acc, 0, 0, 0);
            }
        }
        __syncthreads();
    }
    // U1 writes (zeros when t==0): row-major + col-major hi/lo
    {
        int n = n0 + wv * 16 + l15;
        _Float16* O_h = U1h + (size_t)bt * 16 * N_;
        _Float16* O_l = U1l + (size_t)bt * 16 * N_;
        half4v th, tl;
        #pragma unroll
        for (int r = 0; r < 4; ++r) {
            float v = acc[r];
            _Float16 h = (_Float16)v;
            _Float16 lo = (_Float16)(v - (float)h);
            O_h[(size_t)(lk * 4 + r) * N_ + n] = h;
            O_l[(size_t)(lk * 4 + r) * N_ + n] = lo;
            th[r] = h;
            tl[r] = lo;
        }
        size_t to = ((size_t)bt * N_ + n) * 16 + lk * 4;
        *(half4v*)(U1Th + to) = th;
        *(half4v*)(U1Tl + to) = tl;
    }
}

// ---------------- K0b: x -> xT[bt][n][16] hi/lo (rows 12..15 zero) ----------
__global__ void k_transpose_x(const float* __restrict__ x,
                              _Float16* __restrict__ XTh, _Float16* __restrict__ XTl) {
    int bt = blockIdx.x;
    int n = threadIdx.x;
    const float* xc = x + (size_t)bt * F0 * N_;
    half8 hb[2] = {}, lb[2] = {};
    #pragma unroll
    for (int g = 0; g < F0; ++g) {
        float v = xc[(size_t)g * N_ + n];
        _Float16 hh = (_Float16)v;
        hb[g >> 3][g & 7] = hh;
        lb[g >> 3][g & 7] = (_Float16)(v - (float)hh);
    }
    size_t o = ((size_t)bt * N_ + n) * 16;
    *(half8*)(XTh + o) = hb[0];
    *(half8*)(XTh + o + 8) = hb[1];
    *(half8*)(XTl + o) = lb[0];
    *(half8*)(XTl + o + 8) = lb[1];
}

// ---------------- K2: V1(b,t) = U1(b,t-1) @ S(b,t) -> col-major hi/lo -------
// grid (BT,2), wave=32 cols  [R12-proven version]
__global__ void k_chainV1(const _Float16* __restrict__ Ah, const _Float16* __restrict__ Al,
                          const _Float16* __restrict__ STh, const _Float16* __restrict__ STl,
                          _Float16* __restrict__ OTh, _Float16* __restrict__ OTl) {
    int bt = blockIdx.x;
    int t = bt & (T_ - 1);
    int wave = threadIdx.x >> 6;
    int lane = threadIdx.x & 63;
    int l15 = lane & 15;
    int lk = lane >> 4;
    int n0 = blockIdx.y * 128 + wave * 32;

    f32x4 acc[2];
    #pragma unroll
    for (int j = 0; j < 2; ++j) acc[j] = (f32x4){0.f, 0.f, 0.f, 0.f};

    if (t > 0) {
        const _Float16* A_h = Ah + (size_t)(bt - 1) * 16 * N_;
        const _Float16* A_l = Al + (size_t)(bt - 1) * 16 * N_;
        const _Float16* B_h = STh + (size_t)bt * N_ * N_;
        const _Float16* B_l = STl + (size_t)bt * N_ * N_;
        #pragma unroll
        for (int kk = 0; kk < 8; ++kk) {
            int kof = kk * 32 + lk * 8;
            half8 ah = *(const half8*)(A_h + (size_t)l15 * N_ + kof);
            half8 al = *(const half8*)(A_l + (size_t)l15 * N_ + kof);
            #pragma unroll
            for (int j = 0; j < 2; ++j) {
                half8 bh = *(const half8*)(B_h + (size_t)(n0 + j * 16 + l15) * N_ + kof);
                half8 bl = *(const half8*)(B_l + (size_t)(n0 + j * 16 + l15) * N_ + kof);
                acc[j] = __builtin_amdgcn_mfma_f32_16x16x32_f16(ah, bh, acc[j], 0, 0, 0);
                acc[j] = __builtin_amdgcn_mfma_f32_16x16x32_f16(al, bh, acc[j], 0, 0, 0);
                acc[j] = __builtin_amdgcn_mfma_f32_16x16x32_f16(ah, bl, acc[j], 0, 0, 0);
            }
        }
    }
    #pragma unroll
    for (int j = 0; j < 2; ++j) {
        half4v th, tl;
        #pragma unroll
        for (int r = 0; r < 4; ++r) {
            float v = acc[j][r];
            _Float16 h = (_Float16)v;
            th[r] = h;
            tl[r] = (_Float16)(v - (float)h);
        }
        size_t to = ((size_t)bt * N_ + n0 + j * 16 + l15) * 16 + lk * 4;
        *(half4v*)(OTh + to) = th;
        *(half4v*)(OTl + to) = tl;
    }
}

// ---------------- K3: y1 = tanh(W1cat @ Zcat + b1) -> Y1T hi/lo -------------
__global__ void k_combine1(const _Float16* __restrict__ XTh, const _Float16* __restrict__ XTl,
                           const _Float16* __restrict__ U1Th, const _Float16* __restrict__ U1Tl,
                           const _Float16* __restrict__ V1Th, const _Float16* __restrict__ V1Tl,
                           const float* __restrict__ W1, const float* __restrict__ b1,
                           _Float16* __restrict__ Y1Th, _Float16* __restrict__ Y1Tl) {
    __shared__ _Float16 wh[64 * 72], wl[64 * 72];
    int bt = blockIdx.x;
    int tid = threadIdx.x;
    for (int i = tid; i < 64 * 72; i += 256) {
        int f = i / 72, k = i % 72;
        float v = 0.f;
        if (k < 12) v = W1[f * 36 + k];
        else if (k >= 16 && k < 28) v = W1[f * 36 + 12 + (k - 16)];
        else if (k >= 32 && k < 44) v = W1[f * 36 + 24 + (k - 32)];
        _Float16 hh = (_Float16)v;
        wh[i] = hh;
        wl[i] = (_Float16)(v - (float)hh);
    }
    __syncthreads();

    int wv = tid >> 6, lane = tid & 63, l15 = lane & 15, lk = lane >> 4;
    int n0 = wv * 64;
    f32x4 acc[4][4];
    #pragma unroll
    for (int i = 0; i < 4; ++i)
        #pragma unroll
        for (int j = 0; j < 4; ++j) acc[i][j] = (f32x4){0.f, 0.f, 0.f, 0.f};

    #pragma unroll
    for (int kk = 0; kk < 2; ++kk) {
        half8 bh[4], bl[4];
        #pragma unroll
        for (int j = 0; j < 4; ++j) {
            size_t base16 = ((size_t)bt * N_ + n0 + j * 16 + l15) * 16;
            if (kk == 0) {
                if (lk < 2) {
                    bh[j] = *(const half8*)(XTh + base16 + lk * 8);
                    bl[j] = *(const half8*)(XTl + base16 + lk * 8);
                } else {
                    bh[j] = *(const half8*)(U1Th + base16 + (lk - 2) * 8);
                    bl[j] = *(const half8*)(U1Tl + base16 + (lk - 2) * 8);
                }
            } else {
                if (lk < 2) {
                    bh[j] = *(const half8*)(V1Th + base16 + lk * 8);
                    bl[j] = *(const half8*)(V1Tl + base16 + lk * 8);
                } else {
                    bh[j] = half8{};
                    bl[j] = half8{};
                }
            }
        }
        #pragma unroll
        for (int i = 0; i < 4; ++i) {
            half8 ah = *(const half8*)(wh + (i * 16 + l15) * 72 + kk * 32 + lk * 8);
            half8 al = *(const half8*)(wl + (i * 16 + l15) * 72 + kk * 32 + lk * 8);
            #pragma unroll
            for (int j = 0; j < 4; ++j) {
                acc[i][j] = __builtin_amdgcn_mfma_f32_16x16x32_f16(ah, bh[j], acc[i][j], 0, 0, 0);
                acc[i][j] = __builtin_amdgcn_mfma_f32_16x16x32_f16(al, bh[j], acc[i][j], 0, 0, 0);
                acc[i][j] = __builtin_amdgcn_mfma_f32_16x16x32_f16(ah, bl[j], acc[i][j], 0, 0, 0);
            }
        }
    }
    #pragma unroll
    for (int i = 0; i < 4; ++i) {
        float bb[4];
        #pragma unroll
        for (int r = 0; r < 4; ++r) bb[r] = b1[i * 16 + lk * 4 + r];
        #pragma unroll
        for (int j = 0; j < 4; ++j) {
            half4v th, tl;
            #pragma unroll
            for (int r = 0; r < 4; ++r) {
                float yv = tanh_fast(acc[i][j][r] + bb[r]);
                _Float16 h = (_Float16)yv;
                th[r] = h;
                tl[r] = (_Float16)(yv - (float)h);
            }
            size_t to = ((size_t)bt * N_ + n0 + j * 16 + l15) * 64 + i * 16 + lk * 4;
            *(half4v*)(Y1Th + to) = th;
            *(half4v*)(Y1Tl + to) = tl;
        }
    }
}

// ---------------- K4: projections G=W2v@Y1, H=W2u@Y1, Y2a=W2y@Y1 ------------
__global__ void k_proj(const _Float16* __restrict__ Y1Th, const _Float16* __restrict__ Y1Tl,
                       const float* __restrict__ W2,
                       _Float16* __restrict__ Gh, _Float16* __restrict__ Gl,
                       float* __restrict__ Hf, float* __restrict__ Y2a) {
    __shared__ _Float16 wh[96 * 72], wl[96 * 72];
    int bt = blockIdx.x;
    int tid = threadIdx.x;
    for (int i = tid; i < 96 * 64; i += 256) {
        int r = i >> 6, g = i & 63;
        int f, off;
        if (r < 32)      { f = r;      off = 128; }   // W2v -> G
        else if (r < 64) { f = r - 32; off = 64;  }   // W2u -> H
        else             { f = r - 64; off = 0;   }   // W2y -> Y2a
        float v = W2[f * 192 + off + g];
        _Float16 hh = (_Float16)v;
        wh[r * 72 + g] = hh;
        wl[r * 72 + g] = (_Float16)(v - (float)hh);
    }
    __syncthreads();

    int wv = tid >> 6, lane = tid & 63, l15 = lane & 15, lk = lane >> 4;
    int n0 = wv * 64;
    f32x4 acc[6][4];
    #pragma unroll
    for (int i = 0; i < 6; ++i)
        #pragma unroll
        for (int j = 0; j < 4; ++j) acc[i][j] = (f32x4){0.f, 0.f, 0.f, 0.f};

    const _Float16* Bh = Y1Th + (size_t)bt * N_ * 64;
    const _Float16* Bl = Y1Tl + (size_t)bt * N_ * 64;
    #pragma unroll
    for (int kk = 0; kk < 2; ++kk) {
        int kof = kk * 32 + lk * 8;
        half8 bh[4], bl[4];
        #pragma unroll
        for (int j = 0; j < 4; ++j) {
            bh[j] = *(const half8*)(Bh + (size_t)(n0 + j * 16 + l15) * 64 + kof);
            bl[j] = *(const half8*)(Bl + (size_t)(n0 + j * 16 + l15) * 64 + kof);
        }
        #pragma unroll
        for (int i = 0; i < 6; ++i) {
            half8 ah = *(const half8*)(wh + (i * 16 + l15) * 72 + kof);
            half8 al = *(const half8*)(wl + (i * 16 + l15) * 72 + kof);
            #pragma unroll
            for (int j = 0; j < 4; ++j) {
                acc[i][j] = __builtin_amdgcn_mfma_f32_16x16x32_f16(ah, bh[j], acc[i][j], 0, 0, 0);
                acc[i][j] = __builtin_amdgcn_mfma_f32_16x16x32_f16(al, bh[j], acc[i][j], 0, 0, 0);
                acc[i][j] = __builtin_amdgcn_mfma_f32_16x16x32_f16(ah, bl[j], acc[i][j], 0, 0, 0);
            }
        }
    }
    #pragma unroll
    for (int i = 0; i < 6; ++i)
        #pragma unroll
        for (int j = 0; j < 4; ++j)
            #pragma unroll
            for (int r = 0; r < 4; ++r) {
                int row = i * 16 + lk * 4 + r;   // 0..95
                int col = n0 + j * 16 + l15;
                float v = acc[i][j][r];
                if (row < 32) {
                    _Float16 hh = (_Float16)v;
                    size_t o = ((size_t)bt * 32 + row) * N_ + col;
                    Gh[o] = hh;
                    Gl[o] = (_Float16)(v - (float)hh);
                } else if (row < 64) {
                    Hf[((size_t)bt * 32 + row - 32) * N_ + col] = v;
                } else {
                    Y2a[((size_t)bt * 32 + row - 64) * N_ + col] = v;
                }
            }
}

// ---------------- K5: R(b,t) = H(b,t) + G(b,t-1)@S(b,t), hi/lo out ----------
// grid (BT,2), wave=32 cols  [R12-proven version]
__global__ void k_chainR(const _Float16* __restrict__ Gh, const _Float16* __restrict__ Gl,
                         const _Float16* __restrict__ STh, const _Float16* __restrict__ STl,
                         const float* __restrict__ Hf,
                         _Float16* __restrict__ Rh, _Float16* __restrict__ Rl) {
    int bt = blockIdx.x;
    int t = bt & (T_ - 1);
    int wave = threadIdx.x >> 6;
    int lane = threadIdx.x & 63;
    int l15 = lane & 15;
    int lk = lane >> 4;
    int n0 = blockIdx.y * 128 + wave * 32;

    f32x4 acc[2][2];
    #pragma unroll
    for (int i = 0; i < 2; ++i)
        #pragma unroll
        for (int j = 0; j < 2; ++j) acc[i][j] = (f32x4){0.f, 0.f, 0.f, 0.f};

    if (t > 0) {
        const _Float16* A_h = Gh + (size_t)(bt - 1) * 32 * N_;
        const _Float16* A_l = Gl + (size_t)(bt - 1) * 32 * N_;
        const _Float16* B_h = STh + (size_t)bt * N_ * N_;
        const _Float16* B_l = STl + (size_t)bt * N_ * N_;
        #pragma unroll
        for (int kk = 0; kk < 8; ++kk) {
            int kof = kk * 32 + lk * 8;
            half8 ah[2], al[2];
            #pragma unroll
            for (int i = 0; i < 2; ++i) {
                ah[i] = *(const half8*)(A_h + (size_t)(i * 16 + l15) * N_ + kof);
                al[i] = *(const half8*)(A_l + (size_t)(i * 16 + l15) * N_ + kof);
            }
            #pragma unroll
            for (int j = 0; j < 2; ++j) {
                half8 bh = *(const half8*)(B_h + (size_t)(n0 + j * 16 + l15) * N_ + kof);
                half8 bl = *(const half8*)(B_l + (size_t)(n0 + j * 16 + l15) * N_ + kof);
                #pragma unroll
                for (int i = 0; i < 2; ++i) {
                    acc[i][j] = __builtin_amdgcn_mfma_f32_16x16x32_f16(ah[i], bh, acc[i][j], 0, 0, 0);
                    acc[i][j] = __builtin_amdgcn_mfma_f32_16x16x32_f16(al[i], bh, acc[i][j], 0, 0, 0);
                    acc[i][j] = __builtin_amdgcn_mfma_f32_16x16x32_f16(ah[i], bl, acc[i][j], 0, 0, 0);
                }
            }
        }
    }
    const float* Hb = Hf + (size_t)bt * 32 * N_;
    _Float16* R_h = Rh + (size_t)bt * 32 * N_;
    _Float16* R_l = Rl + (size_t)bt * 32 * N_;
    #pragma unroll
    for (int i = 0; i < 2; ++i)
        #pragma unroll
        for (int j = 0; j < 2; ++j)
            #pragma unroll
            for (int r = 0; r < 4; ++r) {
                size_t idx = (size_t)(i * 16 + lk * 4 + r) * N_ + n0 + j * 16 + l15;
                float v = acc[i][j][r] + Hb[idx];
                _Float16 h = (_Float16)v;
                R_h[idx] = h;
                R_l[idx] = (_Float16)(v - (float)h);
            }
}

// ---------------- K6: y2 = tanh(b2 + Y2a + R(t-1)@S(t)); readout -> out -----
// grid (BT,2)  [R12-proven version]
__global__ void k_chainY2(const _Float16* __restrict__ Rh, const _Float16* __restrict__ Rl,
                          const _Float16* __restrict__ STh, const _Float16* __restrict__ STl,
                          const float* __restrict__ Y2a, const float* __restrict__ b2,
                          const float* __restrict__ A1, const float* __restrict__ c1,
                          const float* __restrict__ A2, const float* __restrict__ c2,
                          float* __restrict__ out) {
    __shared__ float y2s[32 * 133];   // 17 KB, pad 133 -> conflict-free
    __shared__ float la1[32 * 33];
    int bt = blockIdx.x;
    int t = bt & (T_ - 1);
    int tid = threadIdx.x;
    for (int i = tid; i < 32 * 32; i += 256) la1[(i >> 5) * 33 + (i & 31)] = A1[i];

    int wave = tid >> 6;
    int lane = tid & 63;
    int l15 = lane & 15;
    int lk = lane >> 4;
    int n0 = blockIdx.y * 128 + wave * 32;

    f32x4 acc[2][2];
    #pragma unroll
    for (int i = 0; i < 2; ++i)
        #pragma unroll
        for (int j = 0; j < 2; ++j) acc[i][j] = (f32x4){0.f, 0.f, 0.f, 0.f};

    if (t > 0) {
        const _Float16* A_h = Rh + (size_t)(bt - 1) * 32 * N_;
        const _Float16* A_l = Rl + (size_t)(bt - 1) * 32 * N_;
        const _Float16* B_h = STh + (size_t)bt * N_ * N_;
        const _Float16* B_l = STl + (size_t)bt * N_ * N_;
        #pragma unroll
        for (int kk = 0; kk < 8; ++kk) {
            int kof = kk * 32 + lk * 8;
            half8 ah[2], al[2];
            #pragma unroll
            for (int i = 0; i < 2; ++i) {
                ah[i] = *(const half8*)(A_h + (size_t)(i * 16 + l15) * N_ + kof);
                al[i] = *(const half8*)(A_l + (size_t)(i * 16 + l15) * N_ + kof);
            }
            #pragma unroll
            for (int j = 0; j < 2; ++j) {
                half8 bh = *(const half8*)(B_h + (size_t)(n0 + j * 16 + l15) * N_ + kof);
                half8 bl = *(const half8*)(B_l + (size_t)(n0 + j * 16 + l15) * N_ + kof);
                #pragma unroll
                for (int i = 0; i < 2; ++i) {
                    acc[i][j] = __builtin_amdgcn_mfma_f32_16x16x32_f16(ah[i], bh, acc[i][j], 0, 0, 0);
                    acc[i][j] = __builtin_amdgcn_mfma_f32_16x16x32_f16(al[i], bh, acc[i][j], 0, 0, 0);
                    acc[i][j] = __builtin_amdgcn_mfma_f32_16x16x32_f16(ah[i], bl, acc[i][j], 0, 0, 0);
                }
            }
        }
    }
    const float* Ya = Y2a + (size_t)bt * 32 * N_;
    int colb0 = wave * 32;
    #pragma unroll
    for (int i = 0; i < 2; ++i)
        #pragma unroll
        for (int j = 0; j < 2; ++j)
            #pragma unroll
            for (int r = 0; r < 4; ++r) {
                int row = i * 16 + lk * 4 + r;
                int colb = colb0 + j * 16 + l15;
                int n = blockIdx.y * 128 + colb;
                y2s[row * 133 + colb] = acc[i][j][r] + Ya[(size_t)row * N_ + n] + b2[row];
            }
    __syncthreads();

    if (tid < 128) {
        int colb = tid;
        int n = blockIdx.y * 128 + colb;
        float y2v[32];
        #pragma unroll
        for (int f = 0; f < 32; ++f) y2v[f] = tanh_fast(y2s[f * 133 + colb]);
        float o0 = 0.f, o1 = 0.f;
        #pragma unroll
        for (int j = 0; j < 32; ++j) {
            const float* a1r = la1 + j * 33;
            float s = c1[j];
            #pragma unroll
            for (int f = 0; f < 32; ++f) s += a1r[f] * y2v[f];
            float hj = tanh_fast(s);
            o0 += A2[j] * hj;
            o1 += A2[32 + j] * hj;
        }
        out[((size_t)bt * 2 + 0) * N_ + n] = o0 + c2[0];
        out[((size_t)bt * 2 + 1) * N_ + n] = o1 + c2[1];
    }
}

extern "C" void kernel_launch(void* const* d_in, const int* in_sizes, int n_in,
                              void* d_out, int out_size, void* d_ws, size_t ws_size,
                              hipStream_t stream) {
    const float* x  = (const float*)d_in[0];
    const float* S  = (const float*)d_in[1];
    const float* W1 = (const float*)d_in[2];
    const float* b1 = (const float*)d_in[3];
    const float* W2 = (const float*)d_in[4];
    const float* b2 = (const float*)d_in[5];
    const float* A1 = (const float*)d_in[6];
    const float* c1 = (const float*)d_in[7];
    const float* A2 = (const float*)d_in[8];
    const float* c2 = (const float*)d_in[9];
    float* out = (float*)d_out;

    char* ws = (char*)d_ws;
    const size_t SZ_ST  = (size_t)BT_ * N_ * N_ * 2;   // 67,108,864 per plane
    const size_t SZ_Y1T = (size_t)BT_ * N_ * 64 * 2;   // 16,777,216 per plane
    const size_t SZ_G   = (size_t)BT_ * 32 * N_ * 2;   //  8,388,608 per plane
    const size_t SZ_H   = (size_t)BT_ * 32 * N_ * 4;   // 16,777,216 (f32)
    const size_t SZ_T16 = (size_t)BT_ * N_ * 16 * 2;   //  4,194,304 (16-row plane)
    size_t off = 0;
    _Float16* STh  = (_Float16*)(ws + off); off += SZ_ST;
    _Float16* STl  = (_Float16*)(ws + off); off += SZ_ST;
    _Float16* Y1Th = (_Float16*)(ws + off); off += SZ_Y1T;
    _Float16* Y1Tl = (_Float16*)(ws + off); off += SZ_Y1T;
    _Float16* Gh   = (_Float16*)(ws + off); off += SZ_G;
    _Float16* Gl   = (_Float16*)(ws + off); off += SZ_G;
    float*    Hf   = (float*)(ws + off); off += SZ_H;
    float*    Y2a  = (float*)(ws + off); off += SZ_H;
    _Float16* Rh   = (_Float16*)(ws + off); off += SZ_G;
    _Float16* Rl   = (_Float16*)(ws + off); off += SZ_G;
    if (ws_size < off) return;  // insufficient scratch -> clean failure

    // overlays (lifetime-disjoint):
    //   XT  (written K0b, read K3)  lives in Hf  region (Hf written later by k_proj)
    //   U1T (written K0,  read K3)  lives in Y2a region first half
    //   V1T (written K2,  read K3)  lives in Y2a region second half
    //   U1 row-major (written K0, read K2) lives in R region (R written by k_chainR)
    _Float16* XTh  = (_Float16*)Hf;
    _Float16* XTl  = XTh + SZ_T16 / 2;
    _Float16* U1Th = (_Float16*)Y2a;
    _Float16* U1Tl = U1Th + SZ_T16 / 2;
    _Float16* V1Th = U1Tl + SZ_T16 / 2;
    _Float16* V1Tl = V1Th + SZ_T16 / 2;
    _Float16* U1h  = Rh;
    _Float16* U1l  = Rl;

    k_transpose_u1<<<dim3(BT_, 4), 256, 0, stream>>>(S, x, STh, STl,
                                                     U1h, U1l, U1Th, U1Tl);
    k_transpose_x<<<BT_, 256, 0, stream>>>(x, XTh, XTl);
    k_chainV1<<<dim3(BT_, 2), 256, 0, stream>>>(U1h, U1l, STh, STl, V1Th, V1Tl);
    k_combine1<<<BT_, 256, 0, stream>>>(XTh, XTl, U1Th, U1Tl, V1Th, V1Tl, W1, b1, Y1Th, Y1Tl);
    k_proj<<<BT_, 256, 0, stream>>>(Y1Th, Y1Tl, W2, Gh, Gl, Hf, Y2a);
    k_chainR<<<dim3(BT_, 2), 256, 0, stream>>>(Gh, Gl, STh, STl, Hf, Rh, Rl);
    k_chainY2<<<dim3(BT_, 2), 256, 0, stream>>>(Rh, Rl, STh, STl, Y2a, b2,
                                                A1, c1, A2, c2, out);
}